// Round 6
// baseline (938.444 us; speedup 1.0000x reference)
//
#include <hip/hip_runtime.h>
#include <math.h>

#define BB 4
#define NN 4096
#define KK 20

typedef __bf16 bf16x8 __attribute__((ext_vector_type(8)));
typedef float  f32x4  __attribute__((ext_vector_type(4)));

__device__ __forceinline__ float lrelu(float x){ return x > 0.f ? x : 0.2f*x; }

// order-preserving f32 -> u32 (monotone), and inverse
__device__ __forceinline__ unsigned ordf(float v){
  unsigned u = __float_as_uint(v);
  return u ^ (((unsigned)((int)u >> 31)) | 0x80000000u);
}
__device__ __forceinline__ float iordf(unsigned o){
  unsigned u = (o & 0x80000000u) ? (o ^ 0x80000000u) : ~o;
  return __uint_as_float(u);
}

// ---------------------------------------------------------------------------
// Exact top-20 of 4096 keys per wave, register-resident, value-only top-3.
// Slot ownership: lane L owns j = s*64 + L, s in [0,64). getv(s,L) must be
// DETERMINISTIC and bit-identical across call sites (pin arithmetic w/ fmaf).
// Priority = (value desc, global index asc) == lax.top_k tie-break.
// Per round: 32-bit wave max + cooperative slot-recovery rescan of the winner
// lane (eligibility excludes already-popped slots); rebuild top-3 on exhaustion.
template<typename GetV>
__device__ __forceinline__ int topk20_v2(int lane, GetV getv){
  unsigned b0 = 0u, b1 = 0u, b2 = 0u;
  for (int s = 0; s < 64; ++s){
    unsigned v = getv(s, lane);
    unsigned nb0 = b0 > v ? b0 : v;
    unsigned mx1 = b1 > v ? b1 : v;
    unsigned nb1 = mx1 < b0 ? mx1 : b0;   // min(b0, max(b1,v))
    unsigned mx2 = b2 > v ? b2 : v;
    unsigned nb2 = mx2 < b1 ? mx2 : b1;   // min(b1, max(b2,v))
    b0 = nb0; b1 = nb1; b2 = nb2;
  }
  unsigned lastv = 0xFFFFFFFFu; int lasts = -1;   // per-lane last-popped (value, slot)
  int myj = 0;
  for (int r = 0; r < 20; ++r){
    unsigned m = b0;
    #pragma unroll
    for (int off = 32; off; off >>= 1){ unsigned o = __shfl_xor(m, off); if (o > m) m = o; }
    unsigned long long msk = __ballot(b0 == m);
    int wl, ss;
    if (__popcll(msk) == 1){
      wl = __ffsll(msk) - 1;
      unsigned lw = __shfl(lastv, wl); int ls = __shfl(lasts, wl);
      unsigned cv = getv(lane, wl);               // slot s=lane of lane wl
      bool elig = (cv < lw) || (cv == lw && lane > ls);
      unsigned long long mk2 = __ballot(elig && cv == m);
      ss = __ffsll(mk2) - 1;                      // lowest eligible slot
    } else {
      // value tie across lanes (rare): min global index j = s*64+L
      int best = 0x7fffffff;
      unsigned long long tmp = msk;
      while (tmp){
        int wl2 = __ffsll(tmp) - 1; tmp &= tmp - 1;
        unsigned lw = __shfl(lastv, wl2); int ls = __shfl(lasts, wl2);
        unsigned cv = getv(lane, wl2);
        bool elig = (cv < lw) || (cv == lw && lane > ls);
        unsigned long long mk2 = __ballot(elig && cv == m);
        int s2 = __ffsll(mk2) - 1;
        int cand = (s2 << 6) | wl2;
        if (cand < best) best = cand;
      }
      ss = best >> 6; wl = best & 63;
    }
    if (lane == r) myj = (ss << 6) | wl;
    bool empty = false;
    if (lane == wl){
      lastv = m; lasts = ss;
      b0 = b1; b1 = b2; b2 = 0u;
      empty = (b0 == 0u);
    }
    if (__any(empty)){
      // cooperative rebuild of winner lane's top-3 among eligible slots
      unsigned cv = getv(lane, wl);
      bool elig2 = (cv < m) || (cv == m && lane > ss);
      if (!elig2) cv = 0u;
      unsigned nv0 = 0u, nv1 = 0u, nv2 = 0u;
      #pragma unroll
      for (int t = 0; t < 3; ++t){
        unsigned mm = cv;
        #pragma unroll
        for (int off = 32; off; off >>= 1){ unsigned o = __shfl_xor(mm, off); if (o > mm) mm = o; }
        unsigned long long mk = __ballot(cv == mm && mm != 0u);
        if (mk){
          int src = __ffsll(mk) - 1;
          if (lane == src) cv = 0u;               // remove one instance
        }
        if (t == 0) nv0 = mm; else if (t == 1) nv1 = mm; else nv2 = mm;
      }
      if (lane == wl){ b0 = nv0; b1 = nv1; b2 = nv2; }
    }
  }
  return myj;
}

// ---------------------------------------------------------------------------
// SoA + norm precompute: pts[g] = (x, y, z, x^2+y^2+z^2), g over B*N points.
__global__ __launch_bounds__(256) void soa_xyz(const float* __restrict__ xyz, float4* __restrict__ pts){
  int g = blockIdx.x*256 + threadIdx.x;
  const float* p = xyz + (size_t)g*3;
  float a0 = p[0], a1 = p[1], a2 = p[2];
  float xx = fmaf(a0, a0, fmaf(a1, a1, a2*a2));
  pts[g] = make_float4(a0, a1, a2, xx);
}

// kNN on xyz. One wave per row; 1 float4 load + ~13 VALU per pair.
__global__ __launch_bounds__(256) void knn_xyz(const float4* __restrict__ pts, int* __restrict__ idx_out){
  int tid = threadIdx.x, wv = tid >> 6, lane = tid & 63;
  int row = blockIdx.x * 4 + wv;
  int b = row >> 12, i = row & 4095;
  const float4* pb = pts + ((size_t)b << 12);
  float4 pi = pb[i];
  float xi0 = pi.x, xi1 = pi.y, xi2 = pi.z, xxi = pi.w;
  auto getv = [=](int s, int L)->unsigned{
    float4 p = pb[(s << 6) + L];
    float inner = fmaf(xi0, p.x, fmaf(xi1, p.y, xi2*p.z));
    float d = fmaf(2.f, inner, -xxi) - p.w;
    return ordf(d);
  };
  int myj = topk20_v2(lane, getv);
  if (lane < 20) idx_out[(size_t)row*20 + lane] = myj;
}

__global__ __launch_bounds__(256) void topk_rows(const unsigned* __restrict__ dg, int* __restrict__ idx_out){
  int tid = threadIdx.x, wv = tid >> 6, lane = tid & 63;
  int i = blockIdx.x * 4 + wv;
  const unsigned* drow = dg + (size_t)i * 4096;
  auto getv = [=](int s, int L)->unsigned{ return drow[(s << 6) + L]; };
  int myj = topk20_v2(lane, getv);
  if (lane < 20) idx_out[(size_t)i*20 + lane] = myj;
}

// ---------------------------------------------------------------------------
// Gram + negative-sq-distance (ord u32) for one batch. Exact f32 (knn path).
__global__ __launch_bounds__(256) void gram_dist(const float* __restrict__ x1, const float* __restrict__ xx,
                                                 unsigned* __restrict__ dg){
  int it = blockIdx.y, jt = blockIdx.x;
  if (jt < it) return;
  __shared__ __align__(16) float Atl[128*32];
  __shared__ __align__(16) float Btl[128*32];
  int tid = threadIdx.x;
  int wv = tid >> 6, lane = tid & 63;
  int wy = wv >> 1, wx = wv & 1, ly = lane >> 3, lx = lane & 7;
  int ib = wy*64 + ly*8, jb = wx*64 + lx*8;
  float acc[8][8] = {};
  for (int kc = 0; kc < 2; ++kc){
    __syncthreads();
    for (int q = 0; q < 4; ++q){
      int e4 = q*256 + tid;
      int r = e4 >> 3, c4 = e4 & 7;
      int cs = (c4 ^ ((r >> 3) & 7)) << 2;
      *(float4*)&Atl[r*32 + cs] = *(const float4*)&x1[(size_t)(it*128 + r)*128 + kc*32 + c4*4];
      *(float4*)&Btl[r*32 + cs] = *(const float4*)&x1[(size_t)(jt*128 + r)*128 + kc*32 + c4*4];
    }
    __syncthreads();
    for (int k4 = 0; k4 < 8; ++k4){
      float a[8][4], bb[8][4];
      #pragma unroll
      for (int p = 0; p < 8; ++p){
        float4 v = *(const float4*)&Atl[(ib + p)*32 + ((k4 ^ ly) << 2)];
        a[p][0]=v.x; a[p][1]=v.y; a[p][2]=v.z; a[p][3]=v.w;
        float4 u = *(const float4*)&Btl[(jb + p)*32 + ((k4 ^ lx) << 2)];
        bb[p][0]=u.x; bb[p][1]=u.y; bb[p][2]=u.z; bb[p][3]=u.w;
      }
      #pragma unroll
      for (int kk = 0; kk < 4; ++kk)
        #pragma unroll
        for (int p = 0; p < 8; ++p)
          #pragma unroll
          for (int q = 0; q < 8; ++q)
            acc[p][q] += a[p][kk] * bb[q][kk];
    }
  }
  float xxi[8], xxj[8];
  #pragma unroll
  for (int p = 0; p < 8; ++p){ xxi[p] = xx[it*128 + ib + p]; xxj[p] = xx[jt*128 + jb + p]; }
  #pragma unroll
  for (int p = 0; p < 8; ++p){
    unsigned ow[8];
    #pragma unroll
    for (int q = 0; q < 8; ++q){ float d = -xxi[p] + 2.f*acc[p][q] - xxj[q]; ow[q] = ordf(d); }
    size_t o = (size_t)(it*128 + ib + p)*4096 + jt*128 + jb;
    *(uint4*)&dg[o]   = make_uint4(ow[0],ow[1],ow[2],ow[3]);
    *(uint4*)&dg[o+4] = make_uint4(ow[4],ow[5],ow[6],ow[7]);
  }
  if (jt > it){
    #pragma unroll
    for (int q = 0; q < 8; ++q){
      unsigned ow[8];
      #pragma unroll
      for (int p = 0; p < 8; ++p){ float d = -xxi[p] + 2.f*acc[p][q] - xxj[q]; ow[p] = ordf(d); }
      size_t o = (size_t)(jt*128 + jb + q)*4096 + it*128 + ib;
      *(uint4*)&dg[o]   = make_uint4(ow[0],ow[1],ow[2],ow[3]);
      *(uint4*)&dg[o+4] = make_uint4(ow[4],ow[5],ow[6],ow[7]);
    }
  }
}

__global__ __launch_bounds__(256) void row_norms(const float* __restrict__ xper, float* __restrict__ xx){
  int wv = threadIdx.x >> 6, lane = threadIdx.x & 63;
  int row = blockIdx.x * 4 + wv;
  float v = xper[(size_t)row*128 + lane];
  float s = v*v;
  #pragma unroll
  for (int off = 32; off; off >>= 1) s += __shfl_xor(s, off);
  if (lane == 0) xx[row] = s;
}

// ---------------------------------------------------------------------------
// stats of z1a = graph_feature(xyz) @ w1a^T, no materialization.
__global__ __launch_bounds__(256) void stats1a(const float* __restrict__ xyz, const int* __restrict__ idx,
                                               const float* __restrict__ w1a,
                                               float* __restrict__ part1, float* __restrict__ part2){
  int tid = threadIdx.x, wv = tid >> 6, lane = tid & 63;
  float w[6];
  #pragma unroll
  for (int c = 0; c < 6; ++c) w[c] = w1a[lane*6 + c];
  float s1 = 0.f, s2 = 0.f;
  int p0 = blockIdx.x*16 + wv*4;
  for (int pp = 0; pp < 4; ++pp){
    int bn = p0 + pp; int b = bn >> 12, i = bn & 4095;
    const float* xb = xyz + (size_t)b * NN * 3;
    float i0 = xb[i*3+0], i1 = xb[i*3+1], i2 = xb[i*3+2];
    for (int k = 0; k < 20; ++k){
      int j = idx[bn*20 + k];
      float a0 = xb[j*3+0], a1 = xb[j*3+1], a2 = xb[j*3+2];
      float z = w[0]*(a0-i0) + w[1]*(a1-i1) + w[2]*(a2-i2) + w[3]*i0 + w[4]*i1 + w[5]*i2;
      s1 += z; s2 += z*z;
    }
  }
  __shared__ float red[2][4][64];
  red[0][wv][lane] = s1; red[1][wv][lane] = s2;
  __syncthreads();
  if (tid < 64)
    part1[(size_t)blockIdx.x*64 + tid] = red[0][0][tid]+red[0][1][tid]+red[0][2][tid]+red[0][3][tid];
  else if (tid < 128){
    int c = tid - 64;
    part2[(size_t)blockIdx.x*64 + c] = red[1][0][c]+red[1][1][c]+red[1][2][c]+red[1][3][c];
  }
}

// ---------------------------------------------------------------------------
// Fused block-1: recompute z1a, h = lrelu(bn(z1a)) in LDS, gemm w1b. (exact f32)
// MODE 0: z1b channel stats only.  MODE 1: BN(st_b)+lrelu, per-point k-max -> xper cols 0..63.
// k4 MAC loop NOT unrolled (r3 post-mortem: full unroll -> 256 VGPR + scratch spill).
template<int MODE>
__global__ __launch_bounds__(128) void fused1(const float* __restrict__ xyz, const int* __restrict__ idx,
                                              const float* __restrict__ w1a, const float* __restrict__ w1b,
                                              const float* __restrict__ st_a, const float* __restrict__ st_b,
                                              float* __restrict__ part1, float* __restrict__ part2,
                                              float* __restrict__ xper){
  __shared__ __align__(16) float h[80*68];
  __shared__ __align__(16) float wl[64*68];
  __shared__ float pr[2][2][64];
  int tid = threadIdx.x, wv = tid >> 6, lane = tid & 63;
  int p0 = blockIdx.x * 4;
  {
    int c = tid >> 1, kh = tid & 1;
    for (int u = 0; u < 8; ++u)
      *(float4*)&wl[c*68 + kh*32 + u*4] = *(const float4*)&w1b[c*64 + kh*32 + u*4];
  }
  {
    float w[6];
    #pragma unroll
    for (int c = 0; c < 6; ++c) w[c] = w1a[lane*6 + c];
    float ma = st_a[lane], ra = st_a[64 + lane];
    for (int g = 0; g < 2; ++g){
      int pt = wv*2 + g; int bn = p0 + pt; int b = bn >> 12, i = bn & 4095;
      const float* xb = xyz + (size_t)b * NN * 3;
      float i0 = xb[i*3+0], i1 = xb[i*3+1], i2 = xb[i*3+2];
      for (int kk = 0; kk < 20; ++kk){
        int j = idx[bn*20 + kk];
        float a0 = xb[j*3+0], a1 = xb[j*3+1], a2 = xb[j*3+2];
        float z = w[0]*(a0-i0) + w[1]*(a1-i1) + w[2]*(a2-i2) + w[3]*i0 + w[4]*i1 + w[5]*i2;
        h[(pt*20 + kk)*68 + lane] = lrelu((z - ma)*ra);
      }
    }
  }
  __syncthreads();
  int ly = lane >> 3, lx = lane & 7;
  float acc[5][8] = {};
  for (int k4 = 0; k4 < 16; ++k4){          // NOT unrolled
    float a[5][4], bb[8][4];
    #pragma unroll
    for (int p = 0; p < 5; ++p){
      float4 v = *(const float4*)&h[(wv*40 + ly + 8*p)*68 + k4*4];
      a[p][0]=v.x; a[p][1]=v.y; a[p][2]=v.z; a[p][3]=v.w;
    }
    #pragma unroll
    for (int q = 0; q < 8; ++q){
      float4 u = *(const float4*)&wl[(lx + 8*q)*68 + k4*4];
      bb[q][0]=u.x; bb[q][1]=u.y; bb[q][2]=u.z; bb[q][3]=u.w;
    }
    #pragma unroll
    for (int kk = 0; kk < 4; ++kk)
      #pragma unroll
      for (int p = 0; p < 5; ++p)
        #pragma unroll
        for (int q = 0; q < 8; ++q)
          acc[p][q] += a[p][kk] * bb[q][kk];
  }
  if (MODE == 0){
    #pragma unroll
    for (int q = 0; q < 8; ++q){
      float s1 = 0.f, s2 = 0.f;
      #pragma unroll
      for (int p = 0; p < 5; ++p){ float v = acc[p][q]; s1 += v; s2 += v*v; }
      #pragma unroll
      for (int off = 8; off < 64; off <<= 1){ s1 += __shfl_xor(s1, off); s2 += __shfl_xor(s2, off); }
      if (ly == 0){ pr[wv][0][lx + 8*q] = s1; pr[wv][1][lx + 8*q] = s2; }
    }
    __syncthreads();
    if (tid < 64) part1[(size_t)blockIdx.x*64 + tid] = pr[0][0][tid] + pr[1][0][tid];
    else if (tid < 128){ int c = tid - 64; part2[(size_t)blockIdx.x*64 + c] = pr[0][1][c] + pr[1][1][c]; }
  } else {
    float mb[8], rb[8];
    #pragma unroll
    for (int q = 0; q < 8; ++q){ int col = lx + 8*q; mb[q] = st_b[col]; rb[q] = st_b[64 + col]; }
    #pragma unroll
    for (int p = 0; p < 5; ++p)
      #pragma unroll
      for (int q = 0; q < 8; ++q)
        h[(wv*40 + ly + 8*p)*68 + (lx + 8*q)] = lrelu((acc[p][q] - mb[q])*rb[q]);
    __syncthreads();
    int ch = tid & 63, pb = tid >> 6;
    for (int g = 0; g < 2; ++g){
      int pt = pb + g*2;
      float mx = -INFINITY;
      for (int kk = 0; kk < 20; ++kk) mx = fmaxf(mx, h[(pt*20 + kk)*68 + ch]);
      xper[(size_t)(p0 + pt)*128 + ch] = mx;
    }
  }
}

// ---------------------------------------------------------------------------
// MFMA rows-GEMM (bf16 inputs, f32 accum). See r5 notes; unchanged.
template<int CIN, int VAR, int OUT>
__global__ __launch_bounds__(256) void gemm_mfma(const float* A, const float* __restrict__ W,
                                                 float* out, int ostride,
                                                 float* __restrict__ part1, float* __restrict__ part2,
                                                 const float* __restrict__ statsIn,
                                                 const int* __restrict__ idx, float oscale,
                                                 const float* __restrict__ statsIn2,
                                                 unsigned* __restrict__ xglob){
  constexpr int ROWB = CIN*2;
  constexpr int CH8  = CIN/8;
  constexpr int SH   = (CIN == 128) ? 4 : 3;
  __shared__ __align__(16) char Al[128*ROWB];
  __shared__ __align__(16) char Bl[64*ROWB];
  __shared__ float pls[4][2][64];
  int tid = threadIdx.x, wv = tid >> 6, lane = tid & 63;
  int rowbase = blockIdx.x*128, chb = blockIdx.y;

  for (int q = 0; q < (128*CH8)/256; ++q){
    int e = q*256 + tid;
    int r = e >> SH, c8 = e & (CH8-1);
    int k0 = c8*8;
    float f[8];
    if (VAR == 2){
      int row = rowbase + r;
      int bn = row / 20; int b = bn >> 12;
      int j = idx[row];
      const float* xi = A + (size_t)bn*128;
      const float* xj = A + ((size_t)(b << 12) + j)*128;
      if (k0 < 64){
        float4 a1 = *(const float4*)&xj[k0];  float4 a2 = *(const float4*)&xj[k0+4];
        float4 b1 = *(const float4*)&xi[k0];  float4 b2 = *(const float4*)&xi[k0+4];
        f[0]=a1.x-b1.x; f[1]=a1.y-b1.y; f[2]=a1.z-b1.z; f[3]=a1.w-b1.w;
        f[4]=a2.x-b2.x; f[5]=a2.y-b2.y; f[6]=a2.z-b2.z; f[7]=a2.w-b2.w;
      } else {
        float4 b1 = *(const float4*)&xi[k0-64]; float4 b2 = *(const float4*)&xi[k0-60];
        f[0]=b1.x; f[1]=b1.y; f[2]=b1.z; f[3]=b1.w;
        f[4]=b2.x; f[5]=b2.y; f[6]=b2.z; f[7]=b2.w;
      }
    } else {
      const float* src = &A[(size_t)(rowbase + r)*CIN + k0];
      float4 v1 = *(const float4*)src; float4 v2 = *(const float4*)(src+4);
      f[0]=v1.x; f[1]=v1.y; f[2]=v1.z; f[3]=v1.w;
      f[4]=v2.x; f[5]=v2.y; f[6]=v2.z; f[7]=v2.w;
      if (VAR == 1){
        float4 m1 = *(const float4*)&statsIn[k0];     float4 m2 = *(const float4*)&statsIn[k0+4];
        float4 r1 = *(const float4*)&statsIn[CIN+k0]; float4 r2 = *(const float4*)&statsIn[CIN+k0+4];
        f[0]=lrelu((f[0]-m1.x)*r1.x); f[1]=lrelu((f[1]-m1.y)*r1.y);
        f[2]=lrelu((f[2]-m1.z)*r1.z); f[3]=lrelu((f[3]-m1.w)*r1.w);
        f[4]=lrelu((f[4]-m2.x)*r2.x); f[5]=lrelu((f[5]-m2.y)*r2.y);
        f[6]=lrelu((f[6]-m2.z)*r2.z); f[7]=lrelu((f[7]-m2.w)*r2.w);
      }
    }
    bf16x8 hv;
    #pragma unroll
    for (int i2 = 0; i2 < 8; ++i2) hv[i2] = (__bf16)f[i2];
    *(bf16x8*)&Al[r*ROWB + ((k0*2) ^ ((r & 7) << 4))] = hv;
  }
  for (int q = 0; q < (64*CH8)/256; ++q){
    int e = q*256 + tid;
    int r = e >> SH, c8 = e & (CH8-1);
    int k0 = c8*8;
    const float* src = &W[(size_t)(chb*64 + r)*CIN + k0];
    float4 v1 = *(const float4*)src; float4 v2 = *(const float4*)(src+4);
    float f[8] = {v1.x,v1.y,v1.z,v1.w,v2.x,v2.y,v2.z,v2.w};
    bf16x8 hv;
    #pragma unroll
    for (int i2 = 0; i2 < 8; ++i2) hv[i2] = (__bf16)f[i2];
    *(bf16x8*)&Bl[r*ROWB + ((k0*2) ^ ((r & 7) << 4))] = hv;
  }
  __syncthreads();

  int lr = lane & 15, hi = lane >> 4;
  f32x4 acc[2][4];
  #pragma unroll
  for (int a_ = 0; a_ < 2; ++a_)
    #pragma unroll
    for (int b_ = 0; b_ < 4; ++b_){ acc[a_][b_][0]=0.f; acc[a_][b_][1]=0.f; acc[a_][b_][2]=0.f; acc[a_][b_][3]=0.f; }
  int wrow = wv*32;
  for (int ks = 0; ks < CIN/32; ++ks){
    int kb = ks*64 + hi*16;
    bf16x8 af[2], bfr[4];
    #pragma unroll
    for (int rf = 0; rf < 2; ++rf){
      int row = wrow + rf*16 + lr;
      af[rf] = *(const bf16x8*)&Al[row*ROWB + (kb ^ ((row & 7) << 4))];
    }
    #pragma unroll
    for (int cf = 0; cf < 4; ++cf){
      int cr = cf*16 + lr;
      bfr[cf] = *(const bf16x8*)&Bl[cr*ROWB + (kb ^ ((cr & 7) << 4))];
    }
    #pragma unroll
    for (int rf = 0; rf < 2; ++rf)
      #pragma unroll
      for (int cf = 0; cf < 4; ++cf)
        acc[rf][cf] = __builtin_amdgcn_mfma_f32_16x16x32_bf16(af[rf], bfr[cf], acc[rf][cf], 0, 0, 0);
  }

  if (OUT == 0){
    #pragma unroll
    for (int rf = 0; rf < 2; ++rf)
      #pragma unroll
      for (int cf = 0; cf < 4; ++cf)
        #pragma unroll
        for (int r4 = 0; r4 < 4; ++r4){
          int row = rowbase + wrow + rf*16 + hi*4 + r4;
          out[(size_t)row*ostride + chb*64 + cf*16 + lr] = acc[rf][cf][r4] * oscale;
        }
  }
  if (OUT != 2 && part1){
    #pragma unroll
    for (int cf = 0; cf < 4; ++cf){
      float s1 = 0.f, s2 = 0.f;
      #pragma unroll
      for (int rf = 0; rf < 2; ++rf)
        #pragma unroll
        for (int r4 = 0; r4 < 4; ++r4){ float v = acc[rf][cf][r4]; s1 += v; s2 += v*v; }
      s1 += __shfl_xor(s1, 16); s1 += __shfl_xor(s1, 32);
      s2 += __shfl_xor(s2, 16); s2 += __shfl_xor(s2, 32);
      if (hi == 0){ pls[wv][0][cf*16 + lr] = s1; pls[wv][1][cf*16 + lr] = s2; }
    }
    __syncthreads();
    int nchTot = gridDim.y * 64;
    if (tid < 64)
      part1[(size_t)blockIdx.x*nchTot + chb*64 + tid] = pls[0][0][tid]+pls[1][0][tid]+pls[2][0][tid]+pls[3][0][tid];
    else if (tid < 128){
      int c = tid - 64;
      part2[(size_t)blockIdx.x*nchTot + chb*64 + c] = pls[0][1][c]+pls[1][1][c]+pls[2][1][c]+pls[3][1][c];
    }
  }
  if (OUT == 2){
    int nchTot = gridDim.y * 64;
    int b = rowbase >> 12;
    #pragma unroll
    for (int cf = 0; cf < 4; ++cf){
      int col = chb*64 + cf*16 + lr;
      float m2 = statsIn2[col], rs2 = statsIn2[nchTot + col];
      float mv = -INFINITY;
      #pragma unroll
      for (int rf = 0; rf < 2; ++rf)
        #pragma unroll
        for (int r4 = 0; r4 < 4; ++r4) mv = fmaxf(mv, lrelu((acc[rf][cf][r4] - m2)*rs2));
      mv = fmaxf(mv, __shfl_xor(mv, 16));
      mv = fmaxf(mv, __shfl_xor(mv, 32));
      if (hi == 0) pls[wv][0][cf*16 + lr] = mv;
    }
    __syncthreads();
    if (tid < 64)
      atomicMax(&xglob[b*nchTot + chb*64 + tid],
                ordf(fmaxf(fmaxf(pls[0][0][tid], pls[1][0][tid]), fmaxf(pls[2][0][tid], pls[3][0][tid]))));
  }
}

// deterministic partial -> (mean, rstd) per channel
__global__ __launch_bounds__(256) void stats_reduce(const float* __restrict__ p1, const float* __restrict__ p2,
                                                    float* __restrict__ statsOut, int nblk, int nch, float count){
  int ch = blockIdx.x, tid = threadIdx.x;
  float s1 = 0.f, s2 = 0.f;
  for (int i = tid; i < nblk; i += 256){ s1 += p1[(size_t)i*nch + ch]; s2 += p2[(size_t)i*nch + ch]; }
  __shared__ float r1[256], r2[256];
  r1[tid] = s1; r2[tid] = s2;
  __syncthreads();
  for (int off = 128; off; off >>= 1){
    if (tid < off){ r1[tid] += r1[tid+off]; r2[tid] += r2[tid+off]; }
    __syncthreads();
  }
  if (tid == 0){
    float m = r1[0] / count;
    float var = r2[0] / count - m*m;
    if (var < 0.f) var = 0.f;
    statsOut[ch] = m;
    statsOut[nch + ch] = rsqrtf(var + 1e-5f);
  }
}

// bn+lrelu then max over k=20 -> xper[:, off..off+63]
__global__ __launch_bounds__(256) void colmax(const float* __restrict__ buf, const float* __restrict__ st,
                                              float* __restrict__ xper, int off){
  int wv = threadIdx.x >> 6, lane = threadIdx.x & 63;
  int bn = blockIdx.x*4 + wv;
  float m = st[lane], rs = st[64 + lane];
  float mx = -INFINITY;
  for (int k = 0; k < 20; ++k){
    float z = buf[((size_t)bn*20 + k)*64 + lane];
    mx = fmaxf(mx, lrelu((z - m)*rs));
  }
  xper[(size_t)bn*128 + off + lane] = mx;
}

__global__ __launch_bounds__(256) void head(const unsigned* __restrict__ xglob,
                                            const float* __restrict__ mu_w, const float* __restrict__ mu_b,
                                            const float* __restrict__ var_w, const float* __restrict__ var_b,
                                            const float* __restrict__ eps_z, float* __restrict__ dout,
                                            float* __restrict__ zv){
  __shared__ __align__(16) float xg[1024];
  int b = blockIdx.x, t = threadIdx.x;
  for (int q = 0; q < 4; ++q) xg[q*256 + t] = iordf(xglob[b*1024 + q*256 + t]);
  __syncthreads();
  if (t < 128){
    float s1 = 0.f, s2 = 0.f;
    for (int c = 0; c < 1024; c += 4){
      float4 xv = *(const float4*)&xg[c];
      float4 wa = *(const float4*)&mu_w[(size_t)t*1024 + c];
      float4 wb = *(const float4*)&var_w[(size_t)t*1024 + c];
      s1 += wa.x*xv.x + wa.y*xv.y + wa.z*xv.z + wa.w*xv.w;
      s2 += wb.x*xv.x + wb.y*xv.y + wb.z*xv.z + wb.w*xv.w;
    }
    float mu = s1 + mu_b[t];
    float lv = s2 + var_b[t];
    dout[458816 + b*128 + t] = mu;
    dout[459328 + b*128 + t] = lv;
    zv[b*128 + t] = eps_z[b*128 + t] * expf(0.5f*lv) + mu;
  }
}

// cuboid MLP + Para_pred per (b,m)
__global__ __launch_bounds__(256) void cuboid(const float* __restrict__ zv, const float* __restrict__ enc_w,
                                              const float* __restrict__ w1, const float* __restrict__ w2,
                                              const float* __restrict__ rot_w, const float* __restrict__ rot_b,
                                              const float* __restrict__ trans_w, const float* __restrict__ trans_b,
                                              const float* __restrict__ ext_w1, const float* __restrict__ ext_b1,
                                              const float* __restrict__ ext_w2, const float* __restrict__ ext_b2,
                                              const float* __restrict__ k_w, float* __restrict__ Km,
                                              float* __restrict__ rot, float* __restrict__ trs,
                                              float* __restrict__ dout){
  int bm = blockIdx.x; int b = bm >> 4, m = bm & 15; int t = threadIdx.x;
  __shared__ __align__(16) float xc[192];
  __shared__ __align__(16) float h1[256];
  __shared__ __align__(16) float xcu[128];
  __shared__ float qv[4]; __shared__ float ev[30];
  if (t < 192) xc[t] = (t < 128) ? zv[b*128 + t] : lrelu(enc_w[(t-128)*16 + m]);
  __syncthreads();
  {
    float s = 0.f; const float* wr = w1 + (size_t)t*192;
    for (int c = 0; c < 192; c += 4){
      float4 w4 = *(const float4*)&wr[c]; float4 x4 = *(const float4*)&xc[c];
      s += w4.x*x4.x + w4.y*x4.y + w4.z*x4.z + w4.w*x4.w;
    }
    h1[t] = lrelu(s);
  }
  __syncthreads();
  if (t < 128){
    float s = 0.f; const float* wr = w2 + (size_t)t*256;
    for (int c = 0; c < 256; c += 4){
      float4 w4 = *(const float4*)&wr[c]; float4 x4 = *(const float4*)&h1[c];
      s += w4.x*x4.x + w4.y*x4.y + w4.z*x4.z + w4.w*x4.w;
    }
    xcu[t] = lrelu(s);
  }
  __syncthreads();
  if (t < 64){
    float s = 0.f;
    for (int c = 0; c < 128; ++c) s += xcu[c]*k_w[(size_t)t*128 + c];
    Km[(size_t)(b*16 + m)*64 + t] = s;
  } else if (t < 68){
    int o = t - 64; float s = rot_b[o];
    for (int c = 0; c < 128; ++c) s += xcu[c]*rot_w[(size_t)o*128 + c];
    qv[o] = s;
  } else if (t < 71){
    int o = t - 68; float s = trans_b[o];
    for (int c = 0; c < 128; ++c) s += xcu[c]*trans_w[(size_t)o*128 + c];
    trs[(size_t)(b*16 + m)*3 + o] = tanhf(s);
  } else if (t < 101){
    int o = t - 71; float s = ext_b1[o];
    for (int c = 0; c < 128; ++c) s += xcu[c]*ext_w1[(size_t)o*128 + c];
    ev[o] = lrelu(s);
  }
  __syncthreads();
  if (t == 0){
    float w = qv[0], x = qv[1], y = qv[2], z = qv[3];
    float nrm = sqrtf(w*w + x*x + y*y + z*z);
    float inv = 1.f / fmaxf(nrm, 1e-12f);
    w *= inv; x *= inv; y *= inv; z *= inv;
    float xx2 = x*x, yy = y*y, zz = z*z;
    float* r = rot + (size_t)(b*16 + m)*9;
    r[0] = 1.f - 2.f*(yy + zz); r[1] = 2.f*(x*y - w*z); r[2] = 2.f*(x*z + w*y);
    r[3] = 2.f*(x*y + w*z); r[4] = 1.f - 2.f*(xx2 + zz); r[5] = 2.f*(y*z - w*x);
    r[6] = 2.f*(x*z - w*y); r[7] = 2.f*(y*z + w*x); r[8] = 1.f - 2.f*(xx2 + yy);
  }
  if (t == 1){
    float s = ext_b2[0];
    for (int o = 0; o < 30; ++o) s += ev[o]*ext_w2[o];
    dout[458752 + b*16 + m] = s;
  }
}

// attention epilogue
__global__ __launch_bounds__(256) void attn(const float* __restrict__ Qbuf, const float* __restrict__ Km,
                                            const float* __restrict__ rot, const float* __restrict__ trs,
                                            float* __restrict__ dout){
  __shared__ float kml[16*64];
  __shared__ float rl[144], tl[48];
  __shared__ float Ql[4][64];
  __shared__ float al[4][16];
  int tid = threadIdx.x, wv = tid >> 6, lane = tid & 63;
  int bn0 = blockIdx.x*4; int b = bn0 >> 12;
  for (int e = tid; e < 1024; e += 256){
    int m = e >> 6, d = e & 63;
    kml[m*64 + (d ^ ((m & 15) << 2))] = Km[(size_t)b*1024 + e];
  }
  if (tid < 144) rl[tid] = rot[(size_t)b*144 + tid];
  if (tid < 48)  tl[tid] = trs[(size_t)b*48 + tid];
  __syncthreads();
  int bn = bn0 + wv;
  Ql[wv][lane] = Qbuf[(size_t)bn*64 + lane];
  if (lane < 16){
    float sc = 0.f;
    for (int d = 0; d < 64; ++d) sc += Ql[wv][d] * kml[lane*64 + (d ^ ((lane & 15) << 2))];
    float mx = sc;
    #pragma unroll
    for (int off = 8; off; off >>= 1) mx = fmaxf(mx, __shfl_xor(mx, off));
    float e = expf(sc - mx);
    float sm = e;
    #pragma unroll
    for (int off = 8; off; off >>= 1) sm += __shfl_xor(sm, off);
    float a = e / sm;
    dout[(size_t)bn*16 + lane] = a;
    al[wv][lane] = a;
  }
  if (lane < 9){
    float s = 0.f;
    for (int m = 0; m < 16; ++m) s += al[wv][m] * rl[m*9 + lane];
    dout[262144 + (size_t)bn*9 + lane] = s;
  }
  if (lane >= 16 && lane < 19){
    int d = lane - 16;
    float s = 0.f;
    for (int m = 0; m < 16; ++m) s += al[wv][m] * tl[m*3 + d];
    dout[409600 + (size_t)bn*3 + d] = s;
  }
}

// ---------------------------------------------------------------------------
extern "C" void kernel_launch(void* const* d_in, const int* in_sizes, int n_in,
                              void* d_out, int out_size, void* d_ws, size_t ws_size,
                              hipStream_t stream){
  (void)in_sizes; (void)n_in; (void)out_size; (void)ws_size;
  const float* xyz     = (const float*)d_in[0];
  const float* eps_z   = (const float*)d_in[2];
  const float* w1a     = (const float*)d_in[3];
  const float* w1b     = (const float*)d_in[4];
  const float* w2a     = (const float*)d_in[5];
  const float* w2b     = (const float*)d_in[6];
  const float* w3      = (const float*)d_in[7];
  const float* mu_w    = (const float*)d_in[8];
  const float* mu_b    = (const float*)d_in[9];
  const float* var_w   = (const float*)d_in[10];
  const float* var_b   = (const float*)d_in[11];
  const float* enc_w   = (const float*)d_in[12];
  const float* cw1     = (const float*)d_in[13];
  const float* cw2     = (const float*)d_in[14];
  const float* q_w     = (const float*)d_in[15];
  const float* k_w     = (const float*)d_in[16];
  const float* rot_w   = (const float*)d_in[19];
  const float* rot_b   = (const float*)d_in[20];
  const float* trans_w = (const float*)d_in[21];
  const float* trans_b = (const float*)d_in[22];
  const float* ext_w1  = (const float*)d_in[23];
  const float* ext_b1  = (const float*)d_in[24];
  const float* ext_w2  = (const float*)d_in[25];
  const float* ext_b2  = (const float*)d_in[26];
  float* dout = (float*)d_out;

  char* wsb = (char*)d_ws;
  size_t off = 0;
  float* buf   = (float*)(wsb + off); off += 83886080;      // z2a/z2b [B,N,K,64] f32; reused as dist (64MB)
  int*   idx0  = (int*)(wsb + off);   off += 1310720;
  int*   idx1  = (int*)(wsb + off);   off += 1310720;
  float* xper  = (float*)(wsb + off); off += 8388608;       // [B,N,128] = [x1|x2]
  float* xx    = (float*)(wsb + off); off += 65536;
  float* part1 = (float*)(wsb + off); off += 4194304;       // reused as Qbuf
  float* part2 = (float*)(wsb + off); off += 4194304;
  float* st1a  = (float*)(wsb + off); off += 512;
  float* st1b  = (float*)(wsb + off); off += 512;
  float* st2a  = (float*)(wsb + off); off += 512;
  float* st2b  = (float*)(wsb + off); off += 512;
  float* st3   = (float*)(wsb + off); off += 8192;
  unsigned* xglob = (unsigned*)(wsb + off); off += 16384;
  float* zv    = (float*)(wsb + off); off += 2048;
  float* Kmb   = (float*)(wsb + off); off += 16384;
  float* rotb  = (float*)(wsb + off); off += 2304;
  float* trsb  = (float*)(wsb + off); off += 768;
  float4* pts  = (float4*)(wsb + off); off += 262144;       // [B*N] (x,y,z,|x|^2)

  // --- Feature_extract, block 1 (fully fused, exact f32 -> x1/idx1 unchanged) ---
  soa_xyz<<<64, 256, 0, stream>>>(xyz, pts);
  knn_xyz<<<4096, 256, 0, stream>>>(pts, idx0);
  stats1a<<<1024, 256, 0, stream>>>(xyz, idx0, w1a, part1, part2);
  stats_reduce<<<64, 256, 0, stream>>>(part1, part2, st1a, 1024, 64, 327680.f);
  fused1<0><<<4096, 128, 0, stream>>>(xyz, idx0, w1a, w1b, st1a, nullptr, part1, part2, nullptr);
  stats_reduce<<<64, 256, 0, stream>>>(part1, part2, st1b, 4096, 64, 327680.f);
  fused1<1><<<4096, 128, 0, stream>>>(xyz, idx0, w1a, w1b, st1a, st1b, nullptr, nullptr, xper);

  // --- knn on x1 (Gram -> ord-dist -> topk), per batch, exact f32 ---
  row_norms<<<4096, 256, 0, stream>>>(xper, xx);
  for (int b = 0; b < 4; ++b){
    gram_dist<<<dim3(32,32), 256, 0, stream>>>(xper + (size_t)b*NN*128, xx + (size_t)b*NN, (unsigned*)buf);
    topk_rows<<<1024, 256, 0, stream>>>((unsigned*)buf, idx1 + (size_t)b*NN*KK);
  }

  // --- Feature_extract, block 2 (bf16 MFMA) ---
  gemm_mfma<128,2,0><<<dim3(2560,1), 256, 0, stream>>>(xper, w2a, buf, 64, part1, part2, nullptr, idx1, 1.f, nullptr, nullptr);
  stats_reduce<<<64, 256, 0, stream>>>(part1, part2, st2a, 2560, 64, 327680.f);
  gemm_mfma<64,1,0><<<dim3(2560,1), 256, 0, stream>>>(buf, w2b, buf, 64, part1, part2, st2a, nullptr, 1.f, nullptr, nullptr);
  stats_reduce<<<64, 256, 0, stream>>>(part1, part2, st2b, 2560, 64, 327680.f);
  colmax<<<4096, 256, 0, stream>>>(buf, st2b, xper, 64);    // x2

  // --- global embedding (bf16 MFMA stats pass + fused BN/lrelu/max pass, no z3) ---
  gemm_mfma<128,0,1><<<dim3(128,16), 256, 0, stream>>>(xper, w3, nullptr, 1024, part1, part2, nullptr, nullptr, 1.f, nullptr, nullptr);
  stats_reduce<<<1024, 256, 0, stream>>>(part1, part2, st3, 128, 1024, 16384.f);
  hipMemsetAsync(xglob, 0, 4096*sizeof(unsigned), stream);
  gemm_mfma<128,0,2><<<dim3(128,16), 256, 0, stream>>>(xper, w3, nullptr, 1024, nullptr, nullptr, nullptr, nullptr, 1.f, st3, xglob);

  // --- heads ---
  head<<<4, 256, 0, stream>>>(xglob, mu_w, mu_b, var_w, var_b, eps_z, dout, zv);
  cuboid<<<64, 256, 0, stream>>>(zv, enc_w, cw1, cw2, rot_w, rot_b, trans_w, trans_b,
                                 ext_w1, ext_b1, ext_w2, ext_b2, k_w, Kmb, rotb, trsb, dout);
  gemm_mfma<128,0,0><<<dim3(128,1), 256, 0, stream>>>(xper, q_w, part1, 64, nullptr, nullptr, nullptr, nullptr, 0.125f, nullptr, nullptr);
  attn<<<4096, 256, 0, stream>>>(part1, Kmb, rotb, trsb, dout);
}

// Round 7
// 735.324 us; speedup vs baseline: 1.2762x; 1.2762x over previous
//
#include <hip/hip_runtime.h>
#include <math.h>

#define BB 4
#define NN 4096
#define KK 20

typedef __bf16 bf16x8 __attribute__((ext_vector_type(8)));
typedef float  f32x4  __attribute__((ext_vector_type(4)));

__device__ __forceinline__ float lrelu(float x){ return x > 0.f ? x : 0.2f*x; }

// order-preserving f32 -> u32 (monotone), and inverse
__device__ __forceinline__ unsigned ordf(float v){
  unsigned u = __float_as_uint(v);
  return u ^ (((unsigned)((int)u >> 31)) | 0x80000000u);
}
__device__ __forceinline__ float iordf(unsigned o){
  unsigned u = (o & 0x80000000u) ? (o ^ 0x80000000u) : ~o;
  return __uint_as_float(u);
}

// ---------------------------------------------------------------------------
// Exact top-20 of 4096 keys per wave (hybrid r5/r6 structure).
// Lane L owns slots j = s*64 + L. Scan keeps top-3 (value, slot) in registers
// (r5 — no per-round global re-reads). Selection per round: 32-bit value
// max-reduce + ballot + shfl of the stored slot (r6 mechanics). Cooperative
// getv rescan happens ONLY on rare lane exhaustion (~0.2x/row).
// Priority = (value desc, global index asc) == lax.top_k tie-break.
template<typename GetV>
__device__ __forceinline__ int topk20_v3(int lane, GetV getv){
  unsigned b0v = 0u, b1v = 0u, b2v = 0u;
  int b0s = 63, b1s = 63, b2s = 63;
  for (int s = 0; s < 64; ++s){
    unsigned v = getv(s, lane);
    if (v > b0v){ b2v=b1v; b2s=b1s; b1v=b0v; b1s=b0s; b0v=v; b0s=s; }
    else if (v > b1v){ b2v=b1v; b2s=b1s; b1v=v; b1s=s; }
    else if (v > b2v){ b2v=v; b2s=s; }
  }
  unsigned lastv = 0u; int lasts = 0;
  int myj = 0;
  for (int r = 0; r < 20; ++r){
    unsigned m = b0v;
    #pragma unroll
    for (int off = 32; off; off >>= 1){ unsigned o = __shfl_xor(m, off); if (o > m) m = o; }
    unsigned long long msk = __ballot(b0v == m);
    int wl, ss;
    if (__popcll(msk) == 1){
      wl = __ffsll(msk) - 1;
      ss = __shfl(b0s, wl);
    } else {
      // value tie across lanes (rare): min global index j = (slot<<6)|lane
      int kk = (b0v == m) ? ((b0s << 6) | lane) : 0x7fffffff;
      #pragma unroll
      for (int off = 32; off; off >>= 1){ int o = __shfl_xor(kk, off); if (o < kk) kk = o; }
      wl = kk & 63; ss = kk >> 6;
    }
    if (lane == r) myj = (ss << 6) | wl;
    bool empty = false;
    if (lane == wl){
      lastv = m; lasts = ss;
      b0v = b1v; b0s = b1s; b1v = b2v; b1s = b2s; b2v = 0u; b2s = 63;
      empty = (b0v == 0u);
    }
    if (__any(empty)){
      // cooperative rebuild of winner lane's top-3 among still-eligible slots
      unsigned lw = __shfl(lastv, wl); int ls = __shfl(lasts, wl);
      unsigned cv = getv(lane, wl);              // slot s=lane of chunk wl
      bool keep = (cv < lw) || (cv == lw && lane > ls);
      if (!keep) cv = 0u;
      unsigned nv0, nv1, nv2; int ns0, ns1, ns2;
      #pragma unroll
      for (int t = 0; t < 3; ++t){
        unsigned mm = cv;
        #pragma unroll
        for (int off = 32; off; off >>= 1){ unsigned o = __shfl_xor(mm, off); if (o > mm) mm = o; }
        unsigned long long mk = __ballot(cv == mm && mm != 0u);
        int src = mk ? (__ffsll(mk) - 1) : 63;   // lowest lane == lowest slot
        if (t == 0){ nv0 = mm; ns0 = src; }
        else if (t == 1){ nv1 = mm; ns1 = src; }
        else { nv2 = mm; ns2 = src; }
        if (mk && lane == src) cv = 0u;
      }
      if (lane == wl){ b0v=nv0; b0s=ns0; b1v=nv1; b1s=ns1; b2v=nv2; b2s=ns2; }
    }
  }
  return myj;
}

// ---------------------------------------------------------------------------
// SoA + norm precompute: pts[g] = (x, y, z, x^2+y^2+z^2), g over B*N points.
__global__ __launch_bounds__(256) void soa_xyz(const float* __restrict__ xyz, float4* __restrict__ pts){
  int g = blockIdx.x*256 + threadIdx.x;
  const float* p = xyz + (size_t)g*3;
  float a0 = p[0], a1 = p[1], a2 = p[2];
  float xx = fmaf(a0, a0, fmaf(a1, a1, a2*a2));
  pts[g] = make_float4(a0, a1, a2, xx);
}

// kNN on xyz. One wave per row; 1 float4 load + ~8 VALU per pair (scan).
__global__ __launch_bounds__(256) void knn_xyz(const float4* __restrict__ pts, int* __restrict__ idx_out){
  int tid = threadIdx.x, wv = tid >> 6, lane = tid & 63;
  int row = blockIdx.x * 4 + wv;
  int b = row >> 12, i = row & 4095;
  const float4* pb = pts + ((size_t)b << 12);
  float4 pi = pb[i];
  float xi0 = pi.x, xi1 = pi.y, xi2 = pi.z, xxi = pi.w;
  auto getv = [=](int s, int L)->unsigned{
    float4 p = pb[(s << 6) + L];
    float inner = fmaf(xi0, p.x, fmaf(xi1, p.y, xi2*p.z));
    float d = fmaf(2.f, inner, -xxi) - p.w;
    return ordf(d);
  };
  int myj = topk20_v3(lane, getv);
  if (lane < 20) idx_out[(size_t)row*20 + lane] = myj;
}

__global__ __launch_bounds__(256) void topk_rows(const unsigned* __restrict__ dg, int* __restrict__ idx_out){
  int tid = threadIdx.x, wv = tid >> 6, lane = tid & 63;
  int i = blockIdx.x * 4 + wv;
  const unsigned* drow = dg + (size_t)i * 4096;
  auto getv = [=](int s, int L)->unsigned{ return drow[(s << 6) + L]; };
  int myj = topk20_v3(lane, getv);
  if (lane < 20) idx_out[(size_t)i*20 + lane] = myj;
}

// ---------------------------------------------------------------------------
// Gram + negative-sq-distance (ord u32) for one batch. Exact f32 (knn path).
__global__ __launch_bounds__(256) void gram_dist(const float* __restrict__ x1, const float* __restrict__ xx,
                                                 unsigned* __restrict__ dg){
  int it = blockIdx.y, jt = blockIdx.x;
  if (jt < it) return;
  __shared__ __align__(16) float Atl[128*32];
  __shared__ __align__(16) float Btl[128*32];
  int tid = threadIdx.x;
  int wv = tid >> 6, lane = tid & 63;
  int wy = wv >> 1, wx = wv & 1, ly = lane >> 3, lx = lane & 7;
  int ib = wy*64 + ly*8, jb = wx*64 + lx*8;
  float acc[8][8] = {};
  for (int kc = 0; kc < 2; ++kc){
    __syncthreads();
    for (int q = 0; q < 4; ++q){
      int e4 = q*256 + tid;
      int r = e4 >> 3, c4 = e4 & 7;
      int cs = (c4 ^ ((r >> 3) & 7)) << 2;
      *(float4*)&Atl[r*32 + cs] = *(const float4*)&x1[(size_t)(it*128 + r)*128 + kc*32 + c4*4];
      *(float4*)&Btl[r*32 + cs] = *(const float4*)&x1[(size_t)(jt*128 + r)*128 + kc*32 + c4*4];
    }
    __syncthreads();
    for (int k4 = 0; k4 < 8; ++k4){
      float a[8][4], bb[8][4];
      #pragma unroll
      for (int p = 0; p < 8; ++p){
        float4 v = *(const float4*)&Atl[(ib + p)*32 + ((k4 ^ ly) << 2)];
        a[p][0]=v.x; a[p][1]=v.y; a[p][2]=v.z; a[p][3]=v.w;
        float4 u = *(const float4*)&Btl[(jb + p)*32 + ((k4 ^ lx) << 2)];
        bb[p][0]=u.x; bb[p][1]=u.y; bb[p][2]=u.z; bb[p][3]=u.w;
      }
      #pragma unroll
      for (int kk = 0; kk < 4; ++kk)
        #pragma unroll
        for (int p = 0; p < 8; ++p)
          #pragma unroll
          for (int q = 0; q < 8; ++q)
            acc[p][q] += a[p][kk] * bb[q][kk];
    }
  }
  float xxi[8], xxj[8];
  #pragma unroll
  for (int p = 0; p < 8; ++p){ xxi[p] = xx[it*128 + ib + p]; xxj[p] = xx[jt*128 + jb + p]; }
  #pragma unroll
  for (int p = 0; p < 8; ++p){
    unsigned ow[8];
    #pragma unroll
    for (int q = 0; q < 8; ++q){ float d = -xxi[p] + 2.f*acc[p][q] - xxj[q]; ow[q] = ordf(d); }
    size_t o = (size_t)(it*128 + ib + p)*4096 + jt*128 + jb;
    *(uint4*)&dg[o]   = make_uint4(ow[0],ow[1],ow[2],ow[3]);
    *(uint4*)&dg[o+4] = make_uint4(ow[4],ow[5],ow[6],ow[7]);
  }
  if (jt > it){
    #pragma unroll
    for (int q = 0; q < 8; ++q){
      unsigned ow[8];
      #pragma unroll
      for (int p = 0; p < 8; ++p){ float d = -xxi[p] + 2.f*acc[p][q] - xxj[q]; ow[p] = ordf(d); }
      size_t o = (size_t)(jt*128 + jb + q)*4096 + it*128 + ib;
      *(uint4*)&dg[o]   = make_uint4(ow[0],ow[1],ow[2],ow[3]);
      *(uint4*)&dg[o+4] = make_uint4(ow[4],ow[5],ow[6],ow[7]);
    }
  }
}

__global__ __launch_bounds__(256) void row_norms(const float* __restrict__ xper, float* __restrict__ xx){
  int wv = threadIdx.x >> 6, lane = threadIdx.x & 63;
  int row = blockIdx.x * 4 + wv;
  float v = xper[(size_t)row*128 + lane];
  float s = v*v;
  #pragma unroll
  for (int off = 32; off; off >>= 1) s += __shfl_xor(s, off);
  if (lane == 0) xx[row] = s;
}

// ---------------------------------------------------------------------------
// stats of z1a = graph_feature(xyz) @ w1a^T, no materialization.
__global__ __launch_bounds__(256) void stats1a(const float* __restrict__ xyz, const int* __restrict__ idx,
                                               const float* __restrict__ w1a,
                                               float* __restrict__ part1, float* __restrict__ part2){
  int tid = threadIdx.x, wv = tid >> 6, lane = tid & 63;
  float w[6];
  #pragma unroll
  for (int c = 0; c < 6; ++c) w[c] = w1a[lane*6 + c];
  float s1 = 0.f, s2 = 0.f;
  int p0 = blockIdx.x*16 + wv*4;
  for (int pp = 0; pp < 4; ++pp){
    int bn = p0 + pp; int b = bn >> 12, i = bn & 4095;
    const float* xb = xyz + (size_t)b * NN * 3;
    float i0 = xb[i*3+0], i1 = xb[i*3+1], i2 = xb[i*3+2];
    for (int k = 0; k < 20; ++k){
      int j = idx[bn*20 + k];
      float a0 = xb[j*3+0], a1 = xb[j*3+1], a2 = xb[j*3+2];
      float z = w[0]*(a0-i0) + w[1]*(a1-i1) + w[2]*(a2-i2) + w[3]*i0 + w[4]*i1 + w[5]*i2;
      s1 += z; s2 += z*z;
    }
  }
  __shared__ float red[2][4][64];
  red[0][wv][lane] = s1; red[1][wv][lane] = s2;
  __syncthreads();
  if (tid < 64)
    part1[(size_t)blockIdx.x*64 + tid] = red[0][0][tid]+red[0][1][tid]+red[0][2][tid]+red[0][3][tid];
  else if (tid < 128){
    int c = tid - 64;
    part2[(size_t)blockIdx.x*64 + c] = red[1][0][c]+red[1][1][c]+red[1][2][c]+red[1][3][c];
  }
}

// ---------------------------------------------------------------------------
// Fused block-1: recompute z1a, h = lrelu(bn(z1a)) in LDS, gemm w1b. (exact f32)
// MODE 0: z1b channel stats only.  MODE 1: BN(st_b)+lrelu, per-point k-max -> xper cols 0..63.
// k4 MAC loop NOT unrolled (r3 post-mortem: full unroll -> 256 VGPR + scratch spill).
template<int MODE>
__global__ __launch_bounds__(128) void fused1(const float* __restrict__ xyz, const int* __restrict__ idx,
                                              const float* __restrict__ w1a, const float* __restrict__ w1b,
                                              const float* __restrict__ st_a, const float* __restrict__ st_b,
                                              float* __restrict__ part1, float* __restrict__ part2,
                                              float* __restrict__ xper){
  __shared__ __align__(16) float h[80*68];
  __shared__ __align__(16) float wl[64*68];
  __shared__ float pr[2][2][64];
  int tid = threadIdx.x, wv = tid >> 6, lane = tid & 63;
  int p0 = blockIdx.x * 4;
  {
    int c = tid >> 1, kh = tid & 1;
    for (int u = 0; u < 8; ++u)
      *(float4*)&wl[c*68 + kh*32 + u*4] = *(const float4*)&w1b[c*64 + kh*32 + u*4];
  }
  {
    float w[6];
    #pragma unroll
    for (int c = 0; c < 6; ++c) w[c] = w1a[lane*6 + c];
    float ma = st_a[lane], ra = st_a[64 + lane];
    for (int g = 0; g < 2; ++g){
      int pt = wv*2 + g; int bn = p0 + pt; int b = bn >> 12, i = bn & 4095;
      const float* xb = xyz + (size_t)b * NN * 3;
      float i0 = xb[i*3+0], i1 = xb[i*3+1], i2 = xb[i*3+2];
      for (int kk = 0; kk < 20; ++kk){
        int j = idx[bn*20 + kk];
        float a0 = xb[j*3+0], a1 = xb[j*3+1], a2 = xb[j*3+2];
        float z = w[0]*(a0-i0) + w[1]*(a1-i1) + w[2]*(a2-i2) + w[3]*i0 + w[4]*i1 + w[5]*i2;
        h[(pt*20 + kk)*68 + lane] = lrelu((z - ma)*ra);
      }
    }
  }
  __syncthreads();
  int ly = lane >> 3, lx = lane & 7;
  float acc[5][8] = {};
  for (int k4 = 0; k4 < 16; ++k4){          // NOT unrolled
    float a[5][4], bb[8][4];
    #pragma unroll
    for (int p = 0; p < 5; ++p){
      float4 v = *(const float4*)&h[(wv*40 + ly + 8*p)*68 + k4*4];
      a[p][0]=v.x; a[p][1]=v.y; a[p][2]=v.z; a[p][3]=v.w;
    }
    #pragma unroll
    for (int q = 0; q < 8; ++q){
      float4 u = *(const float4*)&wl[(lx + 8*q)*68 + k4*4];
      bb[q][0]=u.x; bb[q][1]=u.y; bb[q][2]=u.z; bb[q][3]=u.w;
    }
    #pragma unroll
    for (int kk = 0; kk < 4; ++kk)
      #pragma unroll
      for (int p = 0; p < 5; ++p)
        #pragma unroll
        for (int q = 0; q < 8; ++q)
          acc[p][q] += a[p][kk] * bb[q][kk];
  }
  if (MODE == 0){
    #pragma unroll
    for (int q = 0; q < 8; ++q){
      float s1 = 0.f, s2 = 0.f;
      #pragma unroll
      for (int p = 0; p < 5; ++p){ float v = acc[p][q]; s1 += v; s2 += v*v; }
      #pragma unroll
      for (int off = 8; off < 64; off <<= 1){ s1 += __shfl_xor(s1, off); s2 += __shfl_xor(s2, off); }
      if (ly == 0){ pr[wv][0][lx + 8*q] = s1; pr[wv][1][lx + 8*q] = s2; }
    }
    __syncthreads();
    if (tid < 64) part1[(size_t)blockIdx.x*64 + tid] = pr[0][0][tid] + pr[1][0][tid];
    else if (tid < 128){ int c = tid - 64; part2[(size_t)blockIdx.x*64 + c] = pr[0][1][c] + pr[1][1][c]; }
  } else {
    float mb[8], rb[8];
    #pragma unroll
    for (int q = 0; q < 8; ++q){ int col = lx + 8*q; mb[q] = st_b[col]; rb[q] = st_b[64 + col]; }
    #pragma unroll
    for (int p = 0; p < 5; ++p)
      #pragma unroll
      for (int q = 0; q < 8; ++q)
        h[(wv*40 + ly + 8*p)*68 + (lx + 8*q)] = lrelu((acc[p][q] - mb[q])*rb[q]);
    __syncthreads();
    int ch = tid & 63, pb = tid >> 6;
    for (int g = 0; g < 2; ++g){
      int pt = pb + g*2;
      float mx = -INFINITY;
      for (int kk = 0; kk < 20; ++kk) mx = fmaxf(mx, h[(pt*20 + kk)*68 + ch]);
      xper[(size_t)(p0 + pt)*128 + ch] = mx;
    }
  }
}

// ---------------------------------------------------------------------------
// MFMA rows-GEMM (bf16 inputs, f32 accum). See r5 notes; unchanged.
template<int CIN, int VAR, int OUT>
__global__ __launch_bounds__(256) void gemm_mfma(const float* A, const float* __restrict__ W,
                                                 float* out, int ostride,
                                                 float* __restrict__ part1, float* __restrict__ part2,
                                                 const float* __restrict__ statsIn,
                                                 const int* __restrict__ idx, float oscale,
                                                 const float* __restrict__ statsIn2,
                                                 unsigned* __restrict__ xglob){
  constexpr int ROWB = CIN*2;
  constexpr int CH8  = CIN/8;
  constexpr int SH   = (CIN == 128) ? 4 : 3;
  __shared__ __align__(16) char Al[128*ROWB];
  __shared__ __align__(16) char Bl[64*ROWB];
  __shared__ float pls[4][2][64];
  int tid = threadIdx.x, wv = tid >> 6, lane = tid & 63;
  int rowbase = blockIdx.x*128, chb = blockIdx.y;

  for (int q = 0; q < (128*CH8)/256; ++q){
    int e = q*256 + tid;
    int r = e >> SH, c8 = e & (CH8-1);
    int k0 = c8*8;
    float f[8];
    if (VAR == 2){
      int row = rowbase + r;
      int bn = row / 20; int b = bn >> 12;
      int j = idx[row];
      const float* xi = A + (size_t)bn*128;
      const float* xj = A + ((size_t)(b << 12) + j)*128;
      if (k0 < 64){
        float4 a1 = *(const float4*)&xj[k0];  float4 a2 = *(const float4*)&xj[k0+4];
        float4 b1 = *(const float4*)&xi[k0];  float4 b2 = *(const float4*)&xi[k0+4];
        f[0]=a1.x-b1.x; f[1]=a1.y-b1.y; f[2]=a1.z-b1.z; f[3]=a1.w-b1.w;
        f[4]=a2.x-b2.x; f[5]=a2.y-b2.y; f[6]=a2.z-b2.z; f[7]=a2.w-b2.w;
      } else {
        float4 b1 = *(const float4*)&xi[k0-64]; float4 b2 = *(const float4*)&xi[k0-60];
        f[0]=b1.x; f[1]=b1.y; f[2]=b1.z; f[3]=b1.w;
        f[4]=b2.x; f[5]=b2.y; f[6]=b2.z; f[7]=b2.w;
      }
    } else {
      const float* src = &A[(size_t)(rowbase + r)*CIN + k0];
      float4 v1 = *(const float4*)src; float4 v2 = *(const float4*)(src+4);
      f[0]=v1.x; f[1]=v1.y; f[2]=v1.z; f[3]=v1.w;
      f[4]=v2.x; f[5]=v2.y; f[6]=v2.z; f[7]=v2.w;
      if (VAR == 1){
        float4 m1 = *(const float4*)&statsIn[k0];     float4 m2 = *(const float4*)&statsIn[k0+4];
        float4 r1 = *(const float4*)&statsIn[CIN+k0]; float4 r2 = *(const float4*)&statsIn[CIN+k0+4];
        f[0]=lrelu((f[0]-m1.x)*r1.x); f[1]=lrelu((f[1]-m1.y)*r1.y);
        f[2]=lrelu((f[2]-m1.z)*r1.z); f[3]=lrelu((f[3]-m1.w)*r1.w);
        f[4]=lrelu((f[4]-m2.x)*r2.x); f[5]=lrelu((f[5]-m2.y)*r2.y);
        f[6]=lrelu((f[6]-m2.z)*r2.z); f[7]=lrelu((f[7]-m2.w)*r2.w);
      }
    }
    bf16x8 hv;
    #pragma unroll
    for (int i2 = 0; i2 < 8; ++i2) hv[i2] = (__bf16)f[i2];
    *(bf16x8*)&Al[r*ROWB + ((k0*2) ^ ((r & 7) << 4))] = hv;
  }
  for (int q = 0; q < (64*CH8)/256; ++q){
    int e = q*256 + tid;
    int r = e >> SH, c8 = e & (CH8-1);
    int k0 = c8*8;
    const float* src = &W[(size_t)(chb*64 + r)*CIN + k0];
    float4 v1 = *(const float4*)src; float4 v2 = *(const float4*)(src+4);
    float f[8] = {v1.x,v1.y,v1.z,v1.w,v2.x,v2.y,v2.z,v2.w};
    bf16x8 hv;
    #pragma unroll
    for (int i2 = 0; i2 < 8; ++i2) hv[i2] = (__bf16)f[i2];
    *(bf16x8*)&Bl[r*ROWB + ((k0*2) ^ ((r & 7) << 4))] = hv;
  }
  __syncthreads();

  int lr = lane & 15, hi = lane >> 4;
  f32x4 acc[2][4];
  #pragma unroll
  for (int a_ = 0; a_ < 2; ++a_)
    #pragma unroll
    for (int b_ = 0; b_ < 4; ++b_){ acc[a_][b_][0]=0.f; acc[a_][b_][1]=0.f; acc[a_][b_][2]=0.f; acc[a_][b_][3]=0.f; }
  int wrow = wv*32;
  for (int ks = 0; ks < CIN/32; ++ks){
    int kb = ks*64 + hi*16;
    bf16x8 af[2], bfr[4];
    #pragma unroll
    for (int rf = 0; rf < 2; ++rf){
      int row = wrow + rf*16 + lr;
      af[rf] = *(const bf16x8*)&Al[row*ROWB + (kb ^ ((row & 7) << 4))];
    }
    #pragma unroll
    for (int cf = 0; cf < 4; ++cf){
      int cr = cf*16 + lr;
      bfr[cf] = *(const bf16x8*)&Bl[cr*ROWB + (kb ^ ((cr & 7) << 4))];
    }
    #pragma unroll
    for (int rf = 0; rf < 2; ++rf)
      #pragma unroll
      for (int cf = 0; cf < 4; ++cf)
        acc[rf][cf] = __builtin_amdgcn_mfma_f32_16x16x32_bf16(af[rf], bfr[cf], acc[rf][cf], 0, 0, 0);
  }

  if (OUT == 0){
    #pragma unroll
    for (int rf = 0; rf < 2; ++rf)
      #pragma unroll
      for (int cf = 0; cf < 4; ++cf)
        #pragma unroll
        for (int r4 = 0; r4 < 4; ++r4){
          int row = rowbase + wrow + rf*16 + hi*4 + r4;
          out[(size_t)row*ostride + chb*64 + cf*16 + lr] = acc[rf][cf][r4] * oscale;
        }
  }
  if (OUT != 2 && part1){
    #pragma unroll
    for (int cf = 0; cf < 4; ++cf){
      float s1 = 0.f, s2 = 0.f;
      #pragma unroll
      for (int rf = 0; rf < 2; ++rf)
        #pragma unroll
        for (int r4 = 0; r4 < 4; ++r4){ float v = acc[rf][cf][r4]; s1 += v; s2 += v*v; }
      s1 += __shfl_xor(s1, 16); s1 += __shfl_xor(s1, 32);
      s2 += __shfl_xor(s2, 16); s2 += __shfl_xor(s2, 32);
      if (hi == 0){ pls[wv][0][cf*16 + lr] = s1; pls[wv][1][cf*16 + lr] = s2; }
    }
    __syncthreads();
    int nchTot = gridDim.y * 64;
    if (tid < 64)
      part1[(size_t)blockIdx.x*nchTot + chb*64 + tid] = pls[0][0][tid]+pls[1][0][tid]+pls[2][0][tid]+pls[3][0][tid];
    else if (tid < 128){
      int c = tid - 64;
      part2[(size_t)blockIdx.x*nchTot + chb*64 + c] = pls[0][1][c]+pls[1][1][c]+pls[2][1][c]+pls[3][1][c];
    }
  }
  if (OUT == 2){
    int nchTot = gridDim.y * 64;
    int b = rowbase >> 12;
    #pragma unroll
    for (int cf = 0; cf < 4; ++cf){
      int col = chb*64 + cf*16 + lr;
      float m2 = statsIn2[col], rs2 = statsIn2[nchTot + col];
      float mv = -INFINITY;
      #pragma unroll
      for (int rf = 0; rf < 2; ++rf)
        #pragma unroll
        for (int r4 = 0; r4 < 4; ++r4) mv = fmaxf(mv, lrelu((acc[rf][cf][r4] - m2)*rs2));
      mv = fmaxf(mv, __shfl_xor(mv, 16));
      mv = fmaxf(mv, __shfl_xor(mv, 32));
      if (hi == 0) pls[wv][0][cf*16 + lr] = mv;
    }
    __syncthreads();
    if (tid < 64)
      atomicMax(&xglob[b*nchTot + chb*64 + tid],
                ordf(fmaxf(fmaxf(pls[0][0][tid], pls[1][0][tid]), fmaxf(pls[2][0][tid], pls[3][0][tid]))));
  }
}

// deterministic partial -> (mean, rstd) per channel
__global__ __launch_bounds__(256) void stats_reduce(const float* __restrict__ p1, const float* __restrict__ p2,
                                                    float* __restrict__ statsOut, int nblk, int nch, float count){
  int ch = blockIdx.x, tid = threadIdx.x;
  float s1 = 0.f, s2 = 0.f;
  for (int i = tid; i < nblk; i += 256){ s1 += p1[(size_t)i*nch + ch]; s2 += p2[(size_t)i*nch + ch]; }
  __shared__ float r1[256], r2[256];
  r1[tid] = s1; r2[tid] = s2;
  __syncthreads();
  for (int off = 128; off; off >>= 1){
    if (tid < off){ r1[tid] += r1[tid+off]; r2[tid] += r2[tid+off]; }
    __syncthreads();
  }
  if (tid == 0){
    float m = r1[0] / count;
    float var = r2[0] / count - m*m;
    if (var < 0.f) var = 0.f;
    statsOut[ch] = m;
    statsOut[nch + ch] = rsqrtf(var + 1e-5f);
  }
}

// bn+lrelu then max over k=20 -> xper[:, off..off+63]
__global__ __launch_bounds__(256) void colmax(const float* __restrict__ buf, const float* __restrict__ st,
                                              float* __restrict__ xper, int off){
  int wv = threadIdx.x >> 6, lane = threadIdx.x & 63;
  int bn = blockIdx.x*4 + wv;
  float m = st[lane], rs = st[64 + lane];
  float mx = -INFINITY;
  for (int k = 0; k < 20; ++k){
    float z = buf[((size_t)bn*20 + k)*64 + lane];
    mx = fmaxf(mx, lrelu((z - m)*rs));
  }
  xper[(size_t)bn*128 + off + lane] = mx;
}

__global__ __launch_bounds__(256) void head(const unsigned* __restrict__ xglob,
                                            const float* __restrict__ mu_w, const float* __restrict__ mu_b,
                                            const float* __restrict__ var_w, const float* __restrict__ var_b,
                                            const float* __restrict__ eps_z, float* __restrict__ dout,
                                            float* __restrict__ zv){
  __shared__ __align__(16) float xg[1024];
  int b = blockIdx.x, t = threadIdx.x;
  for (int q = 0; q < 4; ++q) xg[q*256 + t] = iordf(xglob[b*1024 + q*256 + t]);
  __syncthreads();
  if (t < 128){
    float s1 = 0.f, s2 = 0.f;
    for (int c = 0; c < 1024; c += 4){
      float4 xv = *(const float4*)&xg[c];
      float4 wa = *(const float4*)&mu_w[(size_t)t*1024 + c];
      float4 wb = *(const float4*)&var_w[(size_t)t*1024 + c];
      s1 += wa.x*xv.x + wa.y*xv.y + wa.z*xv.z + wa.w*xv.w;
      s2 += wb.x*xv.x + wb.y*xv.y + wb.z*xv.z + wb.w*xv.w;
    }
    float mu = s1 + mu_b[t];
    float lv = s2 + var_b[t];
    dout[458816 + b*128 + t] = mu;
    dout[459328 + b*128 + t] = lv;
    zv[b*128 + t] = eps_z[b*128 + t] * expf(0.5f*lv) + mu;
  }
}

// cuboid MLP + Para_pred per (b,m)
__global__ __launch_bounds__(256) void cuboid(const float* __restrict__ zv, const float* __restrict__ enc_w,
                                              const float* __restrict__ w1, const float* __restrict__ w2,
                                              const float* __restrict__ rot_w, const float* __restrict__ rot_b,
                                              const float* __restrict__ trans_w, const float* __restrict__ trans_b,
                                              const float* __restrict__ ext_w1, const float* __restrict__ ext_b1,
                                              const float* __restrict__ ext_w2, const float* __restrict__ ext_b2,
                                              const float* __restrict__ k_w, float* __restrict__ Km,
                                              float* __restrict__ rot, float* __restrict__ trs,
                                              float* __restrict__ dout){
  int bm = blockIdx.x; int b = bm >> 4, m = bm & 15; int t = threadIdx.x;
  __shared__ __align__(16) float xc[192];
  __shared__ __align__(16) float h1[256];
  __shared__ __align__(16) float xcu[128];
  __shared__ float qv[4]; __shared__ float ev[30];
  if (t < 192) xc[t] = (t < 128) ? zv[b*128 + t] : lrelu(enc_w[(t-128)*16 + m]);
  __syncthreads();
  {
    float s = 0.f; const float* wr = w1 + (size_t)t*192;
    for (int c = 0; c < 192; c += 4){
      float4 w4 = *(const float4*)&wr[c]; float4 x4 = *(const float4*)&xc[c];
      s += w4.x*x4.x + w4.y*x4.y + w4.z*x4.z + w4.w*x4.w;
    }
    h1[t] = lrelu(s);
  }
  __syncthreads();
  if (t < 128){
    float s = 0.f; const float* wr = w2 + (size_t)t*256;
    for (int c = 0; c < 256; c += 4){
      float4 w4 = *(const float4*)&wr[c]; float4 x4 = *(const float4*)&h1[c];
      s += w4.x*x4.x + w4.y*x4.y + w4.z*x4.z + w4.w*x4.w;
    }
    xcu[t] = lrelu(s);
  }
  __syncthreads();
  if (t < 64){
    float s = 0.f;
    for (int c = 0; c < 128; ++c) s += xcu[c]*k_w[(size_t)t*128 + c];
    Km[(size_t)(b*16 + m)*64 + t] = s;
  } else if (t < 68){
    int o = t - 64; float s = rot_b[o];
    for (int c = 0; c < 128; ++c) s += xcu[c]*rot_w[(size_t)o*128 + c];
    qv[o] = s;
  } else if (t < 71){
    int o = t - 68; float s = trans_b[o];
    for (int c = 0; c < 128; ++c) s += xcu[c]*trans_w[(size_t)o*128 + c];
    trs[(size_t)(b*16 + m)*3 + o] = tanhf(s);
  } else if (t < 101){
    int o = t - 71; float s = ext_b1[o];
    for (int c = 0; c < 128; ++c) s += xcu[c]*ext_w1[(size_t)o*128 + c];
    ev[o] = lrelu(s);
  }
  __syncthreads();
  if (t == 0){
    float w = qv[0], x = qv[1], y = qv[2], z = qv[3];
    float nrm = sqrtf(w*w + x*x + y*y + z*z);
    float inv = 1.f / fmaxf(nrm, 1e-12f);
    w *= inv; x *= inv; y *= inv; z *= inv;
    float xx2 = x*x, yy = y*y, zz = z*z;
    float* r = rot + (size_t)(b*16 + m)*9;
    r[0] = 1.f - 2.f*(yy + zz); r[1] = 2.f*(x*y - w*z); r[2] = 2.f*(x*z + w*y);
    r[3] = 2.f*(x*y + w*z); r[4] = 1.f - 2.f*(xx2 + zz); r[5] = 2.f*(y*z - w*x);
    r[6] = 2.f*(x*z - w*y); r[7] = 2.f*(y*z + w*x); r[8] = 1.f - 2.f*(xx2 + yy);
  }
  if (t == 1){
    float s = ext_b2[0];
    for (int o = 0; o < 30; ++o) s += ev[o]*ext_w2[o];
    dout[458752 + b*16 + m] = s;
  }
}

// attention epilogue
__global__ __launch_bounds__(256) void attn(const float* __restrict__ Qbuf, const float* __restrict__ Km,
                                            const float* __restrict__ rot, const float* __restrict__ trs,
                                            float* __restrict__ dout){
  __shared__ float kml[16*64];
  __shared__ float rl[144], tl[48];
  __shared__ float Ql[4][64];
  __shared__ float al[4][16];
  int tid = threadIdx.x, wv = tid >> 6, lane = tid & 63;
  int bn0 = blockIdx.x*4; int b = bn0 >> 12;
  for (int e = tid; e < 1024; e += 256){
    int m = e >> 6, d = e & 63;
    kml[m*64 + (d ^ ((m & 15) << 2))] = Km[(size_t)b*1024 + e];
  }
  if (tid < 144) rl[tid] = rot[(size_t)b*144 + tid];
  if (tid < 48)  tl[tid] = trs[(size_t)b*48 + tid];
  __syncthreads();
  int bn = bn0 + wv;
  Ql[wv][lane] = Qbuf[(size_t)bn*64 + lane];
  if (lane < 16){
    float sc = 0.f;
    for (int d = 0; d < 64; ++d) sc += Ql[wv][d] * kml[lane*64 + (d ^ ((lane & 15) << 2))];
    float mx = sc;
    #pragma unroll
    for (int off = 8; off; off >>= 1) mx = fmaxf(mx, __shfl_xor(mx, off));
    float e = expf(sc - mx);
    float sm = e;
    #pragma unroll
    for (int off = 8; off; off >>= 1) sm += __shfl_xor(sm, off);
    float a = e / sm;
    dout[(size_t)bn*16 + lane] = a;
    al[wv][lane] = a;
  }
  if (lane < 9){
    float s = 0.f;
    for (int m = 0; m < 16; ++m) s += al[wv][m] * rl[m*9 + lane];
    dout[262144 + (size_t)bn*9 + lane] = s;
  }
  if (lane >= 16 && lane < 19){
    int d = lane - 16;
    float s = 0.f;
    for (int m = 0; m < 16; ++m) s += al[wv][m] * tl[m*3 + d];
    dout[409600 + (size_t)bn*3 + d] = s;
  }
}

// ---------------------------------------------------------------------------
extern "C" void kernel_launch(void* const* d_in, const int* in_sizes, int n_in,
                              void* d_out, int out_size, void* d_ws, size_t ws_size,
                              hipStream_t stream){
  (void)in_sizes; (void)n_in; (void)out_size; (void)ws_size;
  const float* xyz     = (const float*)d_in[0];
  const float* eps_z   = (const float*)d_in[2];
  const float* w1a     = (const float*)d_in[3];
  const float* w1b     = (const float*)d_in[4];
  const float* w2a     = (const float*)d_in[5];
  const float* w2b     = (const float*)d_in[6];
  const float* w3      = (const float*)d_in[7];
  const float* mu_w    = (const float*)d_in[8];
  const float* mu_b    = (const float*)d_in[9];
  const float* var_w   = (const float*)d_in[10];
  const float* var_b   = (const float*)d_in[11];
  const float* enc_w   = (const float*)d_in[12];
  const float* cw1     = (const float*)d_in[13];
  const float* cw2     = (const float*)d_in[14];
  const float* q_w     = (const float*)d_in[15];
  const float* k_w     = (const float*)d_in[16];
  const float* rot_w   = (const float*)d_in[19];
  const float* rot_b   = (const float*)d_in[20];
  const float* trans_w = (const float*)d_in[21];
  const float* trans_b = (const float*)d_in[22];
  const float* ext_w1  = (const float*)d_in[23];
  const float* ext_b1  = (const float*)d_in[24];
  const float* ext_w2  = (const float*)d_in[25];
  const float* ext_b2  = (const float*)d_in[26];
  float* dout = (float*)d_out;

  char* wsb = (char*)d_ws;
  size_t off = 0;
  float* buf   = (float*)(wsb + off); off += 83886080;      // z2a/z2b [B,N,K,64] f32; reused as dist (64MB)
  int*   idx0  = (int*)(wsb + off);   off += 1310720;
  int*   idx1  = (int*)(wsb + off);   off += 1310720;
  float* xper  = (float*)(wsb + off); off += 8388608;       // [B,N,128] = [x1|x2]
  float* xx    = (float*)(wsb + off); off += 65536;
  float* part1 = (float*)(wsb + off); off += 4194304;       // reused as Qbuf
  float* part2 = (float*)(wsb + off); off += 4194304;
  float* st1a  = (float*)(wsb + off); off += 512;
  float* st1b  = (float*)(wsb + off); off += 512;
  float* st2a  = (float*)(wsb + off); off += 512;
  float* st2b  = (float*)(wsb + off); off += 512;
  float* st3   = (float*)(wsb + off); off += 8192;
  unsigned* xglob = (unsigned*)(wsb + off); off += 16384;
  float* zv    = (float*)(wsb + off); off += 2048;
  float* Kmb   = (float*)(wsb + off); off += 16384;
  float* rotb  = (float*)(wsb + off); off += 2304;
  float* trsb  = (float*)(wsb + off); off += 768;
  float4* pts  = (float4*)(wsb + off); off += 262144;       // [B*N] (x,y,z,|x|^2)

  // --- Feature_extract, block 1 (fully fused, exact f32 -> x1/idx1 unchanged) ---
  soa_xyz<<<64, 256, 0, stream>>>(xyz, pts);
  knn_xyz<<<4096, 256, 0, stream>>>(pts, idx0);
  stats1a<<<1024, 256, 0, stream>>>(xyz, idx0, w1a, part1, part2);
  stats_reduce<<<64, 256, 0, stream>>>(part1, part2, st1a, 1024, 64, 327680.f);
  fused1<0><<<4096, 128, 0, stream>>>(xyz, idx0, w1a, w1b, st1a, nullptr, part1, part2, nullptr);
  stats_reduce<<<64, 256, 0, stream>>>(part1, part2, st1b, 4096, 64, 327680.f);
  fused1<1><<<4096, 128, 0, stream>>>(xyz, idx0, w1a, w1b, st1a, st1b, nullptr, nullptr, xper);

  // --- knn on x1 (Gram -> ord-dist -> topk), per batch, exact f32 ---
  row_norms<<<4096, 256, 0, stream>>>(xper, xx);
  for (int b = 0; b < 4; ++b){
    gram_dist<<<dim3(32,32), 256, 0, stream>>>(xper + (size_t)b*NN*128, xx + (size_t)b*NN, (unsigned*)buf);
    topk_rows<<<1024, 256, 0, stream>>>((unsigned*)buf, idx1 + (size_t)b*NN*KK);
  }

  // --- Feature_extract, block 2 (bf16 MFMA) ---
  gemm_mfma<128,2,0><<<dim3(2560,1), 256, 0, stream>>>(xper, w2a, buf, 64, part1, part2, nullptr, idx1, 1.f, nullptr, nullptr);
  stats_reduce<<<64, 256, 0, stream>>>(part1, part2, st2a, 2560, 64, 327680.f);
  gemm_mfma<64,1,0><<<dim3(2560,1), 256, 0, stream>>>(buf, w2b, buf, 64, part1, part2, st2a, nullptr, 1.f, nullptr, nullptr);
  stats_reduce<<<64, 256, 0, stream>>>(part1, part2, st2b, 2560, 64, 327680.f);
  colmax<<<4096, 256, 0, stream>>>(buf, st2b, xper, 64);    // x2

  // --- global embedding (bf16 MFMA stats pass + fused BN/lrelu/max pass, no z3) ---
  gemm_mfma<128,0,1><<<dim3(128,16), 256, 0, stream>>>(xper, w3, nullptr, 1024, part1, part2, nullptr, nullptr, 1.f, nullptr, nullptr);
  stats_reduce<<<1024, 256, 0, stream>>>(part1, part2, st3, 128, 1024, 16384.f);
  hipMemsetAsync(xglob, 0, 4096*sizeof(unsigned), stream);
  gemm_mfma<128,0,2><<<dim3(128,16), 256, 0, stream>>>(xper, w3, nullptr, 1024, nullptr, nullptr, nullptr, nullptr, 1.f, st3, xglob);

  // --- heads ---
  head<<<4, 256, 0, stream>>>(xglob, mu_w, mu_b, var_w, var_b, eps_z, dout, zv);
  cuboid<<<64, 256, 0, stream>>>(zv, enc_w, cw1, cw2, rot_w, rot_b, trans_w, trans_b,
                                 ext_w1, ext_b1, ext_w2, ext_b2, k_w, Kmb, rotb, trsb, dout);
  gemm_mfma<128,0,0><<<dim3(128,1), 256, 0, stream>>>(xper, q_w, part1, 64, nullptr, nullptr, nullptr, nullptr, 0.125f, nullptr, nullptr);
  attn<<<4096, 256, 0, stream>>>(part1, Kmb, rotb, trsb, dout);
}

// Round 8
// 669.976 us; speedup vs baseline: 1.4007x; 1.0975x over previous
//
#include <hip/hip_runtime.h>
#include <math.h>

#define BB 4
#define NN 4096
#define KK 20

typedef __bf16 bf16x8 __attribute__((ext_vector_type(8)));
typedef float  f32x4  __attribute__((ext_vector_type(4)));

__device__ __forceinline__ float lrelu(float x){ return x > 0.f ? x : 0.2f*x; }

// order-preserving f32 -> u32 (monotone), and inverse
__device__ __forceinline__ unsigned ordf(float v){
  unsigned u = __float_as_uint(v);
  return u ^ (((unsigned)((int)u >> 31)) | 0x80000000u);
}
__device__ __forceinline__ float iordf(unsigned o){
  unsigned u = (o & 0x80000000u) ? (o ^ 0x80000000u) : ~o;
  return __uint_as_float(u);
}

// ---------------------------------------------------------------------------
// Exact top-20 of 4096 keys per wave, PACKED-KEY variant (r8).
// Lane L owns slots j = s*64 + L. getk(s,L) returns key =
// (ord(value) & ~63) | (63 - s): top-26 value bits + slot tag. Insert is a
// 5-op value-only min/max network (no slot registers). Decode at pop:
// s = 63 - (key&63). Equal keys => equal s, so ffs(ballot) = min lane =
// min global index; ordering among equal 26-bit values is exactly asc-j.
// Cooperative rebuild (rare) rescans the winner's chunk; keys are unique
// within a chunk (slot tag), so eligibility is key < last-popped.
template<typename GetK>
__device__ __forceinline__ int topk20_v4(int lane, GetK getk){
  unsigned b0 = 0u, b1 = 0u, b2 = 0u;
  for (int s = 0; s < 64; ++s){
    unsigned v = getk(s, lane);
    unsigned nb0 = b0 > v ? b0 : v;
    unsigned m1  = b1 > v ? b1 : v;
    unsigned nb1 = m1 < b0 ? m1 : b0;     // min(b0, max(b1,v))
    unsigned m2  = b2 > v ? b2 : v;
    unsigned nb2 = m2 < b1 ? m2 : b1;     // min(b1, max(b2,v))
    b0 = nb0; b1 = nb1; b2 = nb2;
  }
  unsigned lastk = 0xFFFFFFFFu;
  int myj = 0;
  for (int r = 0; r < 20; ++r){
    unsigned m = b0;
    #pragma unroll
    for (int off = 32; off; off >>= 1){ unsigned o = __shfl_xor(m, off); if (o > m) m = o; }
    unsigned long long msk = __ballot(b0 == m);
    int wl = __ffsll(msk) - 1;
    int ss = 63 - (int)(m & 63u);
    if (lane == r) myj = (ss << 6) | wl;
    bool empty = false;
    if (lane == wl){
      lastk = m;
      b0 = b1; b1 = b2; b2 = 0u;
      empty = (b0 == 0u);
    }
    if (__any(empty)){
      // cooperative rebuild of winner lane's top-3 among still-eligible slots
      unsigned lk = __shfl(lastk, wl);
      unsigned cv = getk(lane, wl);            // slot s=lane of chunk wl
      if (cv >= lk) cv = 0u;                   // popped keys are all >= lk
      unsigned nv0 = 0u, nv1 = 0u, nv2 = 0u;
      #pragma unroll
      for (int t = 0; t < 3; ++t){
        unsigned mm = cv;
        #pragma unroll
        for (int off = 32; off; off >>= 1){ unsigned o = __shfl_xor(mm, off); if (o > mm) mm = o; }
        unsigned long long mk = __ballot(cv == mm && mm != 0u);
        if (mk){
          int src = __ffsll(mk) - 1;
          if (lane == src) cv = 0u;
        }
        if (t == 0) nv0 = mm; else if (t == 1) nv1 = mm; else nv2 = mm;
      }
      if (lane == wl){ b0 = nv0; b1 = nv1; b2 = nv2; }
    }
  }
  return myj;
}

// ---------------------------------------------------------------------------
// SoA + norm precompute: pts[g] = (x, y, z, x^2+y^2+z^2), g over B*N points.
__global__ __launch_bounds__(256) void soa_xyz(const float* __restrict__ xyz, float4* __restrict__ pts){
  int g = blockIdx.x*256 + threadIdx.x;
  const float* p = xyz + (size_t)g*3;
  float a0 = p[0], a1 = p[1], a2 = p[2];
  float xx = fmaf(a0, a0, fmaf(a1, a1, a2*a2));
  pts[g] = make_float4(a0, a1, a2, xx);
}

// kNN on xyz. One wave per row; 1 float4 load + ~13 VALU per pair (scan).
__global__ __launch_bounds__(256) void knn_xyz(const float4* __restrict__ pts, int* __restrict__ idx_out){
  int tid = threadIdx.x, wv = tid >> 6, lane = tid & 63;
  int row = blockIdx.x * 4 + wv;
  int b = row >> 12, i = row & 4095;
  const float4* pb = pts + ((size_t)b << 12);
  float4 pi = pb[i];
  float xi0 = pi.x, xi1 = pi.y, xi2 = pi.z, xxi = pi.w;
  auto getk = [=](int s, int L)->unsigned{
    float4 p = pb[(s << 6) + L];
    float inner = fmaf(xi0, p.x, fmaf(xi1, p.y, xi2*p.z));
    float d = fmaf(2.f, inner, -xxi) - p.w;
    return (ordf(d) & 0xFFFFFFC0u) | (unsigned)(63 - s);
  };
  int myj = topk20_v4(lane, getk);
  if (lane < 20) idx_out[(size_t)row*20 + lane] = myj;
}

// top-20 per row from pre-packed key matrix [4096][4096] (gram_dist packs tags)
__global__ __launch_bounds__(256) void topk_rows(const unsigned* __restrict__ dg, int* __restrict__ idx_out){
  int tid = threadIdx.x, wv = tid >> 6, lane = tid & 63;
  int i = blockIdx.x * 4 + wv;
  const unsigned* drow = dg + (size_t)i * 4096;
  auto getk = [=](int s, int L)->unsigned{ return drow[(s << 6) + L]; };
  int myj = topk20_v4(lane, getk);
  if (lane < 20) idx_out[(size_t)i*20 + lane] = myj;
}

// ---------------------------------------------------------------------------
// Gram + negative-sq-distance for one batch, written as PACKED top-k keys:
// key[i][j] = (ordf(d) & ~63) | (63 - (j>>6)). Exact f32 MACs (knn path).
__global__ __launch_bounds__(256) void gram_dist(const float* __restrict__ x1, const float* __restrict__ xx,
                                                 unsigned* __restrict__ dg){
  int it = blockIdx.y, jt = blockIdx.x;
  if (jt < it) return;
  __shared__ __align__(16) float Atl[128*32];
  __shared__ __align__(16) float Btl[128*32];
  int tid = threadIdx.x;
  int wv = tid >> 6, lane = tid & 63;
  int wy = wv >> 1, wx = wv & 1, ly = lane >> 3, lx = lane & 7;
  int ib = wy*64 + ly*8, jb = wx*64 + lx*8;
  float acc[8][8] = {};
  for (int kc = 0; kc < 2; ++kc){
    __syncthreads();
    for (int q = 0; q < 4; ++q){
      int e4 = q*256 + tid;
      int r = e4 >> 3, c4 = e4 & 7;
      int cs = (c4 ^ ((r >> 3) & 7)) << 2;
      *(float4*)&Atl[r*32 + cs] = *(const float4*)&x1[(size_t)(it*128 + r)*128 + kc*32 + c4*4];
      *(float4*)&Btl[r*32 + cs] = *(const float4*)&x1[(size_t)(jt*128 + r)*128 + kc*32 + c4*4];
    }
    __syncthreads();
    for (int k4 = 0; k4 < 8; ++k4){
      float a[8][4], bb[8][4];
      #pragma unroll
      for (int p = 0; p < 8; ++p){
        float4 v = *(const float4*)&Atl[(ib + p)*32 + ((k4 ^ ly) << 2)];
        a[p][0]=v.x; a[p][1]=v.y; a[p][2]=v.z; a[p][3]=v.w;
        float4 u = *(const float4*)&Btl[(jb + p)*32 + ((k4 ^ lx) << 2)];
        bb[p][0]=u.x; bb[p][1]=u.y; bb[p][2]=u.z; bb[p][3]=u.w;
      }
      #pragma unroll
      for (int kk = 0; kk < 4; ++kk)
        #pragma unroll
        for (int p = 0; p < 8; ++p)
          #pragma unroll
          for (int q = 0; q < 8; ++q)
            acc[p][q] += a[p][kk] * bb[q][kk];
    }
  }
  float xxi[8], xxj[8];
  #pragma unroll
  for (int p = 0; p < 8; ++p){ xxi[p] = xx[it*128 + ib + p]; xxj[p] = xx[jt*128 + jb + p]; }
  // slot tags are constant per 8-col span: col>>6 = jt*2+wx (fwd), it*2+wy (mirror)
  unsigned tagF = 63u - (unsigned)(jt*2 + wx);
  #pragma unroll
  for (int p = 0; p < 8; ++p){
    unsigned ow[8];
    #pragma unroll
    for (int q = 0; q < 8; ++q){
      float d = -xxi[p] + 2.f*acc[p][q] - xxj[q];
      ow[q] = (ordf(d) & 0xFFFFFFC0u) | tagF;
    }
    size_t o = (size_t)(it*128 + ib + p)*4096 + jt*128 + jb;
    *(uint4*)&dg[o]   = make_uint4(ow[0],ow[1],ow[2],ow[3]);
    *(uint4*)&dg[o+4] = make_uint4(ow[4],ow[5],ow[6],ow[7]);
  }
  if (jt > it){
    unsigned tagM = 63u - (unsigned)(it*2 + wy);
    #pragma unroll
    for (int q = 0; q < 8; ++q){
      unsigned ow[8];
      #pragma unroll
      for (int p = 0; p < 8; ++p){
        float d = -xxi[p] + 2.f*acc[p][q] - xxj[q];
        ow[p] = (ordf(d) & 0xFFFFFFC0u) | tagM;
      }
      size_t o = (size_t)(jt*128 + jb + q)*4096 + it*128 + ib;
      *(uint4*)&dg[o]   = make_uint4(ow[0],ow[1],ow[2],ow[3]);
      *(uint4*)&dg[o+4] = make_uint4(ow[4],ow[5],ow[6],ow[7]);
    }
  }
}

__global__ __launch_bounds__(256) void row_norms(const float* __restrict__ xper, float* __restrict__ xx){
  int wv = threadIdx.x >> 6, lane = threadIdx.x & 63;
  int row = blockIdx.x * 4 + wv;
  float v = xper[(size_t)row*128 + lane];
  float s = v*v;
  #pragma unroll
  for (int off = 32; off; off >>= 1) s += __shfl_xor(s, off);
  if (lane == 0) xx[row] = s;
}

// ---------------------------------------------------------------------------
// stats of z1a = graph_feature(xyz) @ w1a^T, no materialization. (pts float4 loads)
__global__ __launch_bounds__(256) void stats1a(const float4* __restrict__ pts, const int* __restrict__ idx,
                                               const float* __restrict__ w1a,
                                               float* __restrict__ part1, float* __restrict__ part2){
  int tid = threadIdx.x, wv = tid >> 6, lane = tid & 63;
  float w[6];
  #pragma unroll
  for (int c = 0; c < 6; ++c) w[c] = w1a[lane*6 + c];
  float s1 = 0.f, s2 = 0.f;
  int p0 = blockIdx.x*16 + wv*4;
  for (int pp = 0; pp < 4; ++pp){
    int bn = p0 + pp; int b = bn >> 12, i = bn & 4095;
    const float4* pb = pts + ((size_t)b << 12);
    float4 pi = pb[i];
    float i0 = pi.x, i1 = pi.y, i2 = pi.z;
    for (int k = 0; k < 20; ++k){
      int j = idx[bn*20 + k];
      float4 pj = pb[j];
      float z = w[0]*(pj.x-i0) + w[1]*(pj.y-i1) + w[2]*(pj.z-i2) + w[3]*i0 + w[4]*i1 + w[5]*i2;
      s1 += z; s2 += z*z;
    }
  }
  __shared__ float red[2][4][64];
  red[0][wv][lane] = s1; red[1][wv][lane] = s2;
  __syncthreads();
  if (tid < 64)
    part1[(size_t)blockIdx.x*64 + tid] = red[0][0][tid]+red[0][1][tid]+red[0][2][tid]+red[0][3][tid];
  else if (tid < 128){
    int c = tid - 64;
    part2[(size_t)blockIdx.x*64 + c] = red[1][0][c]+red[1][1][c]+red[1][2][c]+red[1][3][c];
  }
}

// ---------------------------------------------------------------------------
// Fused block-1: recompute z1a, h = lrelu(bn(z1a)) in LDS, gemm w1b. (exact f32)
// MODE 0: z1b channel stats only.  MODE 1: BN(st_b)+lrelu, per-point k-max -> xper cols 0..63.
// k4 MAC loop NOT unrolled (r3 post-mortem: full unroll -> 256 VGPR + scratch spill).
template<int MODE>
__global__ __launch_bounds__(128) void fused1(const float4* __restrict__ pts, const int* __restrict__ idx,
                                              const float* __restrict__ w1a, const float* __restrict__ w1b,
                                              const float* __restrict__ st_a, const float* __restrict__ st_b,
                                              float* __restrict__ part1, float* __restrict__ part2,
                                              float* __restrict__ xper){
  __shared__ __align__(16) float h[80*68];
  __shared__ __align__(16) float wl[64*68];
  __shared__ float pr[2][2][64];
  int tid = threadIdx.x, wv = tid >> 6, lane = tid & 63;
  int p0 = blockIdx.x * 4;
  {
    int c = tid >> 1, kh = tid & 1;
    for (int u = 0; u < 8; ++u)
      *(float4*)&wl[c*68 + kh*32 + u*4] = *(const float4*)&w1b[c*64 + kh*32 + u*4];
  }
  {
    float w[6];
    #pragma unroll
    for (int c = 0; c < 6; ++c) w[c] = w1a[lane*6 + c];
    float ma = st_a[lane], ra = st_a[64 + lane];
    for (int g = 0; g < 2; ++g){
      int pt = wv*2 + g; int bn = p0 + pt; int b = bn >> 12, i = bn & 4095;
      const float4* pb = pts + ((size_t)b << 12);
      float4 pi = pb[i];
      float i0 = pi.x, i1 = pi.y, i2 = pi.z;
      for (int kk = 0; kk < 20; ++kk){
        int j = idx[bn*20 + kk];
        float4 pj = pb[j];
        float z = w[0]*(pj.x-i0) + w[1]*(pj.y-i1) + w[2]*(pj.z-i2) + w[3]*i0 + w[4]*i1 + w[5]*i2;
        h[(pt*20 + kk)*68 + lane] = lrelu((z - ma)*ra);
      }
    }
  }
  __syncthreads();
  int ly = lane >> 3, lx = lane & 7;
  float acc[5][8] = {};
  for (int k4 = 0; k4 < 16; ++k4){          // NOT unrolled
    float a[5][4], bb[8][4];
    #pragma unroll
    for (int p = 0; p < 5; ++p){
      float4 v = *(const float4*)&h[(wv*40 + ly + 8*p)*68 + k4*4];
      a[p][0]=v.x; a[p][1]=v.y; a[p][2]=v.z; a[p][3]=v.w;
    }
    #pragma unroll
    for (int q = 0; q < 8; ++q){
      float4 u = *(const float4*)&wl[(lx + 8*q)*68 + k4*4];
      bb[q][0]=u.x; bb[q][1]=u.y; bb[q][2]=u.z; bb[q][3]=u.w;
    }
    #pragma unroll
    for (int kk = 0; kk < 4; ++kk)
      #pragma unroll
      for (int p = 0; p < 5; ++p)
        #pragma unroll
        for (int q = 0; q < 8; ++q)
          acc[p][q] += a[p][kk] * bb[q][kk];
  }
  if (MODE == 0){
    #pragma unroll
    for (int q = 0; q < 8; ++q){
      float s1 = 0.f, s2 = 0.f;
      #pragma unroll
      for (int p = 0; p < 5; ++p){ float v = acc[p][q]; s1 += v; s2 += v*v; }
      #pragma unroll
      for (int off = 8; off < 64; off <<= 1){ s1 += __shfl_xor(s1, off); s2 += __shfl_xor(s2, off); }
      if (ly == 0){ pr[wv][0][lx + 8*q] = s1; pr[wv][1][lx + 8*q] = s2; }
    }
    __syncthreads();
    if (tid < 64) part1[(size_t)blockIdx.x*64 + tid] = pr[0][0][tid] + pr[1][0][tid];
    else if (tid < 128){ int c = tid - 64; part2[(size_t)blockIdx.x*64 + c] = pr[0][1][c] + pr[1][1][c]; }
  } else {
    float mb[8], rb[8];
    #pragma unroll
    for (int q = 0; q < 8; ++q){ int col = lx + 8*q; mb[q] = st_b[col]; rb[q] = st_b[64 + col]; }
    #pragma unroll
    for (int p = 0; p < 5; ++p)
      #pragma unroll
      for (int q = 0; q < 8; ++q)
        h[(wv*40 + ly + 8*p)*68 + (lx + 8*q)] = lrelu((acc[p][q] - mb[q])*rb[q]);
    __syncthreads();
    int ch = tid & 63, pb2 = tid >> 6;
    for (int g = 0; g < 2; ++g){
      int pt = pb2 + g*2;
      float mx = -INFINITY;
      for (int kk = 0; kk < 20; ++kk) mx = fmaxf(mx, h[(pt*20 + kk)*68 + ch]);
      xper[(size_t)(p0 + pt)*128 + ch] = mx;
    }
  }
}

// ---------------------------------------------------------------------------
// MFMA rows-GEMM (bf16 inputs, f32 accum). See r5 notes; unchanged.
template<int CIN, int VAR, int OUT>
__global__ __launch_bounds__(256) void gemm_mfma(const float* A, const float* __restrict__ W,
                                                 float* out, int ostride,
                                                 float* __restrict__ part1, float* __restrict__ part2,
                                                 const float* __restrict__ statsIn,
                                                 const int* __restrict__ idx, float oscale,
                                                 const float* __restrict__ statsIn2,
                                                 unsigned* __restrict__ xglob){
  constexpr int ROWB = CIN*2;
  constexpr int CH8  = CIN/8;
  constexpr int SH   = (CIN == 128) ? 4 : 3;
  __shared__ __align__(16) char Al[128*ROWB];
  __shared__ __align__(16) char Bl[64*ROWB];
  __shared__ float pls[4][2][64];
  int tid = threadIdx.x, wv = tid >> 6, lane = tid & 63;
  int rowbase = blockIdx.x*128, chb = blockIdx.y;

  for (int q = 0; q < (128*CH8)/256; ++q){
    int e = q*256 + tid;
    int r = e >> SH, c8 = e & (CH8-1);
    int k0 = c8*8;
    float f[8];
    if (VAR == 2){
      int row = rowbase + r;
      int bn = row / 20; int b = bn >> 12;
      int j = idx[row];
      const float* xi = A + (size_t)bn*128;
      const float* xj = A + ((size_t)(b << 12) + j)*128;
      if (k0 < 64){
        float4 a1 = *(const float4*)&xj[k0];  float4 a2 = *(const float4*)&xj[k0+4];
        float4 b1 = *(const float4*)&xi[k0];  float4 b2 = *(const float4*)&xi[k0+4];
        f[0]=a1.x-b1.x; f[1]=a1.y-b1.y; f[2]=a1.z-b1.z; f[3]=a1.w-b1.w;
        f[4]=a2.x-b2.x; f[5]=a2.y-b2.y; f[6]=a2.z-b2.z; f[7]=a2.w-b2.w;
      } else {
        float4 b1 = *(const float4*)&xi[k0-64]; float4 b2 = *(const float4*)&xi[k0-60];
        f[0]=b1.x; f[1]=b1.y; f[2]=b1.z; f[3]=b1.w;
        f[4]=b2.x; f[5]=b2.y; f[6]=b2.z; f[7]=b2.w;
      }
    } else {
      const float* src = &A[(size_t)(rowbase + r)*CIN + k0];
      float4 v1 = *(const float4*)src; float4 v2 = *(const float4*)(src+4);
      f[0]=v1.x; f[1]=v1.y; f[2]=v1.z; f[3]=v1.w;
      f[4]=v2.x; f[5]=v2.y; f[6]=v2.z; f[7]=v2.w;
      if (VAR == 1){
        float4 m1 = *(const float4*)&statsIn[k0];     float4 m2 = *(const float4*)&statsIn[k0+4];
        float4 r1 = *(const float4*)&statsIn[CIN+k0]; float4 r2 = *(const float4*)&statsIn[CIN+k0+4];
        f[0]=lrelu((f[0]-m1.x)*r1.x); f[1]=lrelu((f[1]-m1.y)*r1.y);
        f[2]=lrelu((f[2]-m1.z)*r1.z); f[3]=lrelu((f[3]-m1.w)*r1.w);
        f[4]=lrelu((f[4]-m2.x)*r2.x); f[5]=lrelu((f[5]-m2.y)*r2.y);
        f[6]=lrelu((f[6]-m2.z)*r2.z); f[7]=lrelu((f[7]-m2.w)*r2.w);
      }
    }
    bf16x8 hv;
    #pragma unroll
    for (int i2 = 0; i2 < 8; ++i2) hv[i2] = (__bf16)f[i2];
    *(bf16x8*)&Al[r*ROWB + ((k0*2) ^ ((r & 7) << 4))] = hv;
  }
  for (int q = 0; q < (64*CH8)/256; ++q){
    int e = q*256 + tid;
    int r = e >> SH, c8 = e & (CH8-1);
    int k0 = c8*8;
    const float* src = &W[(size_t)(chb*64 + r)*CIN + k0];
    float4 v1 = *(const float4*)src; float4 v2 = *(const float4*)(src+4);
    float f[8] = {v1.x,v1.y,v1.z,v1.w,v2.x,v2.y,v2.z,v2.w};
    bf16x8 hv;
    #pragma unroll
    for (int i2 = 0; i2 < 8; ++i2) hv[i2] = (__bf16)f[i2];
    *(bf16x8*)&Bl[r*ROWB + ((k0*2) ^ ((r & 7) << 4))] = hv;
  }
  __syncthreads();

  int lr = lane & 15, hi = lane >> 4;
  f32x4 acc[2][4];
  #pragma unroll
  for (int a_ = 0; a_ < 2; ++a_)
    #pragma unroll
    for (int b_ = 0; b_ < 4; ++b_){ acc[a_][b_][0]=0.f; acc[a_][b_][1]=0.f; acc[a_][b_][2]=0.f; acc[a_][b_][3]=0.f; }
  int wrow = wv*32;
  for (int ks = 0; ks < CIN/32; ++ks){
    int kb = ks*64 + hi*16;
    bf16x8 af[2], bfr[4];
    #pragma unroll
    for (int rf = 0; rf < 2; ++rf){
      int row = wrow + rf*16 + lr;
      af[rf] = *(const bf16x8*)&Al[row*ROWB + (kb ^ ((row & 7) << 4))];
    }
    #pragma unroll
    for (int cf = 0; cf < 4; ++cf){
      int cr = cf*16 + lr;
      bfr[cf] = *(const bf16x8*)&Bl[cr*ROWB + (kb ^ ((cr & 7) << 4))];
    }
    #pragma unroll
    for (int rf = 0; rf < 2; ++rf)
      #pragma unroll
      for (int cf = 0; cf < 4; ++cf)
        acc[rf][cf] = __builtin_amdgcn_mfma_f32_16x16x32_bf16(af[rf], bfr[cf], acc[rf][cf], 0, 0, 0);
  }

  if (OUT == 0){
    #pragma unroll
    for (int rf = 0; rf < 2; ++rf)
      #pragma unroll
      for (int cf = 0; cf < 4; ++cf)
        #pragma unroll
        for (int r4 = 0; r4 < 4; ++r4){
          int row = rowbase + wrow + rf*16 + hi*4 + r4;
          out[(size_t)row*ostride + chb*64 + cf*16 + lr] = acc[rf][cf][r4] * oscale;
        }
  }
  if (OUT != 2 && part1){
    #pragma unroll
    for (int cf = 0; cf < 4; ++cf){
      float s1 = 0.f, s2 = 0.f;
      #pragma unroll
      for (int rf = 0; rf < 2; ++rf)
        #pragma unroll
        for (int r4 = 0; r4 < 4; ++r4){ float v = acc[rf][cf][r4]; s1 += v; s2 += v*v; }
      s1 += __shfl_xor(s1, 16); s1 += __shfl_xor(s1, 32);
      s2 += __shfl_xor(s2, 16); s2 += __shfl_xor(s2, 32);
      if (hi == 0){ pls[wv][0][cf*16 + lr] = s1; pls[wv][1][cf*16 + lr] = s2; }
    }
    __syncthreads();
    int nchTot = gridDim.y * 64;
    if (tid < 64)
      part1[(size_t)blockIdx.x*nchTot + chb*64 + tid] = pls[0][0][tid]+pls[1][0][tid]+pls[2][0][tid]+pls[3][0][tid];
    else if (tid < 128){
      int c = tid - 64;
      part2[(size_t)blockIdx.x*nchTot + chb*64 + c] = pls[0][1][c]+pls[1][1][c]+pls[2][1][c]+pls[3][1][c];
    }
  }
  if (OUT == 2){
    int nchTot = gridDim.y * 64;
    int b = rowbase >> 12;
    #pragma unroll
    for (int cf = 0; cf < 4; ++cf){
      int col = chb*64 + cf*16 + lr;
      float m2 = statsIn2[col], rs2 = statsIn2[nchTot + col];
      float mv = -INFINITY;
      #pragma unroll
      for (int rf = 0; rf < 2; ++rf)
        #pragma unroll
        for (int r4 = 0; r4 < 4; ++r4) mv = fmaxf(mv, lrelu((acc[rf][cf][r4] - m2)*rs2));
      mv = fmaxf(mv, __shfl_xor(mv, 16));
      mv = fmaxf(mv, __shfl_xor(mv, 32));
      if (hi == 0) pls[wv][0][cf*16 + lr] = mv;
    }
    __syncthreads();
    if (tid < 64)
      atomicMax(&xglob[b*nchTot + chb*64 + tid],
                ordf(fmaxf(fmaxf(pls[0][0][tid], pls[1][0][tid]), fmaxf(pls[2][0][tid], pls[3][0][tid]))));
  }
}

// deterministic partial -> (mean, rstd) per channel
__global__ __launch_bounds__(256) void stats_reduce(const float* __restrict__ p1, const float* __restrict__ p2,
                                                    float* __restrict__ statsOut, int nblk, int nch, float count){
  int ch = blockIdx.x, tid = threadIdx.x;
  float s1 = 0.f, s2 = 0.f;
  for (int i = tid; i < nblk; i += 256){ s1 += p1[(size_t)i*nch + ch]; s2 += p2[(size_t)i*nch + ch]; }
  __shared__ float r1[256], r2[256];
  r1[tid] = s1; r2[tid] = s2;
  __syncthreads();
  for (int off = 128; off; off >>= 1){
    if (tid < off){ r1[tid] += r1[tid+off]; r2[tid] += r2[tid+off]; }
    __syncthreads();
  }
  if (tid == 0){
    float m = r1[0] / count;
    float var = r2[0] / count - m*m;
    if (var < 0.f) var = 0.f;
    statsOut[ch] = m;
    statsOut[nch + ch] = rsqrtf(var + 1e-5f);
  }
}

// bn+lrelu then max over k=20 -> xper[:, off..off+63]
__global__ __launch_bounds__(256) void colmax(const float* __restrict__ buf, const float* __restrict__ st,
                                              float* __restrict__ xper, int off){
  int wv = threadIdx.x >> 6, lane = threadIdx.x & 63;
  int bn = blockIdx.x*4 + wv;
  float m = st[lane], rs = st[64 + lane];
  float mx = -INFINITY;
  for (int k = 0; k < 20; ++k){
    float z = buf[((size_t)bn*20 + k)*64 + lane];
    mx = fmaxf(mx, lrelu((z - m)*rs));
  }
  xper[(size_t)bn*128 + off + lane] = mx;
}

__global__ __launch_bounds__(256) void head(const unsigned* __restrict__ xglob,
                                            const float* __restrict__ mu_w, const float* __restrict__ mu_b,
                                            const float* __restrict__ var_w, const float* __restrict__ var_b,
                                            const float* __restrict__ eps_z, float* __restrict__ dout,
                                            float* __restrict__ zv){
  __shared__ __align__(16) float xg[1024];
  int b = blockIdx.x, t = threadIdx.x;
  for (int q = 0; q < 4; ++q) xg[q*256 + t] = iordf(xglob[b*1024 + q*256 + t]);
  __syncthreads();
  if (t < 128){
    float s1 = 0.f, s2 = 0.f;
    for (int c = 0; c < 1024; c += 4){
      float4 xv = *(const float4*)&xg[c];
      float4 wa = *(const float4*)&mu_w[(size_t)t*1024 + c];
      float4 wb = *(const float4*)&var_w[(size_t)t*1024 + c];
      s1 += wa.x*xv.x + wa.y*xv.y + wa.z*xv.z + wa.w*xv.w;
      s2 += wb.x*xv.x + wb.y*xv.y + wb.z*xv.z + wb.w*xv.w;
    }
    float mu = s1 + mu_b[t];
    float lv = s2 + var_b[t];
    dout[458816 + b*128 + t] = mu;
    dout[459328 + b*128 + t] = lv;
    zv[b*128 + t] = eps_z[b*128 + t] * expf(0.5f*lv) + mu;
  }
}

// cuboid MLP + Para_pred per (b,m)
__global__ __launch_bounds__(256) void cuboid(const float* __restrict__ zv, const float* __restrict__ enc_w,
                                              const float* __restrict__ w1, const float* __restrict__ w2,
                                              const float* __restrict__ rot_w, const float* __restrict__ rot_b,
                                              const float* __restrict__ trans_w, const float* __restrict__ trans_b,
                                              const float* __restrict__ ext_w1, const float* __restrict__ ext_b1,
                                              const float* __restrict__ ext_w2, const float* __restrict__ ext_b2,
                                              const float* __restrict__ k_w, float* __restrict__ Km,
                                              float* __restrict__ rot, float* __restrict__ trs,
                                              float* __restrict__ dout){
  int bm = blockIdx.x; int b = bm >> 4, m = bm & 15; int t = threadIdx.x;
  __shared__ __align__(16) float xc[192];
  __shared__ __align__(16) float h1[256];
  __shared__ __align__(16) float xcu[128];
  __shared__ float qv[4]; __shared__ float ev[30];
  if (t < 192) xc[t] = (t < 128) ? zv[b*128 + t] : lrelu(enc_w[(t-128)*16 + m]);
  __syncthreads();
  {
    float s = 0.f; const float* wr = w1 + (size_t)t*192;
    for (int c = 0; c < 192; c += 4){
      float4 w4 = *(const float4*)&wr[c]; float4 x4 = *(const float4*)&xc[c];
      s += w4.x*x4.x + w4.y*x4.y + w4.z*x4.z + w4.w*x4.w;
    }
    h1[t] = lrelu(s);
  }
  __syncthreads();
  if (t < 128){
    float s = 0.f; const float* wr = w2 + (size_t)t*256;
    for (int c = 0; c < 256; c += 4){
      float4 w4 = *(const float4*)&wr[c]; float4 x4 = *(const float4*)&h1[c];
      s += w4.x*x4.x + w4.y*x4.y + w4.z*x4.z + w4.w*x4.w;
    }
    xcu[t] = lrelu(s);
  }
  __syncthreads();
  if (t < 64){
    float s = 0.f;
    for (int c = 0; c < 128; ++c) s += xcu[c]*k_w[(size_t)t*128 + c];
    Km[(size_t)(b*16 + m)*64 + t] = s;
  } else if (t < 68){
    int o = t - 64; float s = rot_b[o];
    for (int c = 0; c < 128; ++c) s += xcu[c]*rot_w[(size_t)o*128 + c];
    qv[o] = s;
  } else if (t < 71){
    int o = t - 68; float s = trans_b[o];
    for (int c = 0; c < 128; ++c) s += xcu[c]*trans_w[(size_t)o*128 + c];
    trs[(size_t)(b*16 + m)*3 + o] = tanhf(s);
  } else if (t < 101){
    int o = t - 71; float s = ext_b1[o];
    for (int c = 0; c < 128; ++c) s += xcu[c]*ext_w1[(size_t)o*128 + c];
    ev[o] = lrelu(s);
  }
  __syncthreads();
  if (t == 0){
    float w = qv[0], x = qv[1], y = qv[2], z = qv[3];
    float nrm = sqrtf(w*w + x*x + y*y + z*z);
    float inv = 1.f / fmaxf(nrm, 1e-12f);
    w *= inv; x *= inv; y *= inv; z *= inv;
    float xx2 = x*x, yy = y*y, zz = z*z;
    float* r = rot + (size_t)(b*16 + m)*9;
    r[0] = 1.f - 2.f*(yy + zz); r[1] = 2.f*(x*y - w*z); r[2] = 2.f*(x*z + w*y);
    r[3] = 2.f*(x*y + w*z); r[4] = 1.f - 2.f*(xx2 + zz); r[5] = 2.f*(y*z - w*x);
    r[6] = 2.f*(x*z - w*y); r[7] = 2.f*(y*z + w*x); r[8] = 1.f - 2.f*(xx2 + yy);
  }
  if (t == 1){
    float s = ext_b2[0];
    for (int o = 0; o < 30; ++o) s += ev[o]*ext_w2[o];
    dout[458752 + b*16 + m] = s;
  }
}

// attention epilogue
__global__ __launch_bounds__(256) void attn(const float* __restrict__ Qbuf, const float* __restrict__ Km,
                                            const float* __restrict__ rot, const float* __restrict__ trs,
                                            float* __restrict__ dout){
  __shared__ float kml[16*64];
  __shared__ float rl[144], tl[48];
  __shared__ float Ql[4][64];
  __shared__ float al[4][16];
  int tid = threadIdx.x, wv = tid >> 6, lane = tid & 63;
  int bn0 = blockIdx.x*4; int b = bn0 >> 12;
  for (int e = tid; e < 1024; e += 256){
    int m = e >> 6, d = e & 63;
    kml[m*64 + (d ^ ((m & 15) << 2))] = Km[(size_t)b*1024 + e];
  }
  if (tid < 144) rl[tid] = rot[(size_t)b*144 + tid];
  if (tid < 48)  tl[tid] = trs[(size_t)b*48 + tid];
  __syncthreads();
  int bn = bn0 + wv;
  Ql[wv][lane] = Qbuf[(size_t)bn*64 + lane];
  if (lane < 16){
    float sc = 0.f;
    for (int d = 0; d < 64; ++d) sc += Ql[wv][d] * kml[lane*64 + (d ^ ((lane & 15) << 2))];
    float mx = sc;
    #pragma unroll
    for (int off = 8; off; off >>= 1) mx = fmaxf(mx, __shfl_xor(mx, off));
    float e = expf(sc - mx);
    float sm = e;
    #pragma unroll
    for (int off = 8; off; off >>= 1) sm += __shfl_xor(sm, off);
    float a = e / sm;
    dout[(size_t)bn*16 + lane] = a;
    al[wv][lane] = a;
  }
  if (lane < 9){
    float s = 0.f;
    for (int m = 0; m < 16; ++m) s += al[wv][m] * rl[m*9 + lane];
    dout[262144 + (size_t)bn*9 + lane] = s;
  }
  if (lane >= 16 && lane < 19){
    int d = lane - 16;
    float s = 0.f;
    for (int m = 0; m < 16; ++m) s += al[wv][m] * tl[m*3 + d];
    dout[409600 + (size_t)bn*3 + d] = s;
  }
}

// ---------------------------------------------------------------------------
extern "C" void kernel_launch(void* const* d_in, const int* in_sizes, int n_in,
                              void* d_out, int out_size, void* d_ws, size_t ws_size,
                              hipStream_t stream){
  (void)in_sizes; (void)n_in; (void)out_size; (void)ws_size;
  const float* xyz     = (const float*)d_in[0];
  const float* eps_z   = (const float*)d_in[2];
  const float* w1a     = (const float*)d_in[3];
  const float* w1b     = (const float*)d_in[4];
  const float* w2a     = (const float*)d_in[5];
  const float* w2b     = (const float*)d_in[6];
  const float* w3      = (const float*)d_in[7];
  const float* mu_w    = (const float*)d_in[8];
  const float* mu_b    = (const float*)d_in[9];
  const float* var_w   = (const float*)d_in[10];
  const float* var_b   = (const float*)d_in[11];
  const float* enc_w   = (const float*)d_in[12];
  const float* cw1     = (const float*)d_in[13];
  const float* cw2     = (const float*)d_in[14];
  const float* q_w     = (const float*)d_in[15];
  const float* k_w     = (const float*)d_in[16];
  const float* rot_w   = (const float*)d_in[19];
  const float* rot_b   = (const float*)d_in[20];
  const float* trans_w = (const float*)d_in[21];
  const float* trans_b = (const float*)d_in[22];
  const float* ext_w1  = (const float*)d_in[23];
  const float* ext_b1  = (const float*)d_in[24];
  const float* ext_w2  = (const float*)d_in[25];
  const float* ext_b2  = (const float*)d_in[26];
  float* dout = (float*)d_out;

  char* wsb = (char*)d_ws;
  size_t off = 0;
  float* buf   = (float*)(wsb + off); off += 83886080;      // z2a/z2b [B,N,K,64] f32; reused as key matrix (64MB)
  int*   idx0  = (int*)(wsb + off);   off += 1310720;
  int*   idx1  = (int*)(wsb + off);   off += 1310720;
  float* xper  = (float*)(wsb + off); off += 8388608;       // [B,N,128] = [x1|x2]
  float* xx    = (float*)(wsb + off); off += 65536;
  float* part1 = (float*)(wsb + off); off += 4194304;       // reused as Qbuf
  float* part2 = (float*)(wsb + off); off += 4194304;
  float* st1a  = (float*)(wsb + off); off += 512;
  float* st1b  = (float*)(wsb + off); off += 512;
  float* st2a  = (float*)(wsb + off); off += 512;
  float* st2b  = (float*)(wsb + off); off += 512;
  float* st3   = (float*)(wsb + off); off += 8192;
  unsigned* xglob = (unsigned*)(wsb + off); off += 16384;
  float* zv    = (float*)(wsb + off); off += 2048;
  float* Kmb   = (float*)(wsb + off); off += 16384;
  float* rotb  = (float*)(wsb + off); off += 2304;
  float* trsb  = (float*)(wsb + off); off += 768;
  float4* pts  = (float4*)(wsb + off); off += 262144;       // [B*N] (x,y,z,|x|^2)

  // --- Feature_extract, block 1 (fully fused, exact f32 -> x1/idx1 unchanged) ---
  soa_xyz<<<64, 256, 0, stream>>>(xyz, pts);
  knn_xyz<<<4096, 256, 0, stream>>>(pts, idx0);
  stats1a<<<1024, 256, 0, stream>>>(pts, idx0, w1a, part1, part2);
  stats_reduce<<<64, 256, 0, stream>>>(part1, part2, st1a, 1024, 64, 327680.f);
  fused1<0><<<4096, 128, 0, stream>>>(pts, idx0, w1a, w1b, st1a, nullptr, part1, part2, nullptr);
  stats_reduce<<<64, 256, 0, stream>>>(part1, part2, st1b, 4096, 64, 327680.f);
  fused1<1><<<4096, 128, 0, stream>>>(pts, idx0, w1a, w1b, st1a, st1b, nullptr, nullptr, xper);

  // --- knn on x1 (Gram -> packed keys -> topk), per batch, exact f32 ---
  row_norms<<<4096, 256, 0, stream>>>(xper, xx);
  for (int b = 0; b < 4; ++b){
    gram_dist<<<dim3(32,32), 256, 0, stream>>>(xper + (size_t)b*NN*128, xx + (size_t)b*NN, (unsigned*)buf);
    topk_rows<<<1024, 256, 0, stream>>>((unsigned*)buf, idx1 + (size_t)b*NN*KK);
  }

  // --- Feature_extract, block 2 (bf16 MFMA) ---
  gemm_mfma<128,2,0><<<dim3(2560,1), 256, 0, stream>>>(xper, w2a, buf, 64, part1, part2, nullptr, idx1, 1.f, nullptr, nullptr);
  stats_reduce<<<64, 256, 0, stream>>>(part1, part2, st2a, 2560, 64, 327680.f);
  gemm_mfma<64,1,0><<<dim3(2560,1), 256, 0, stream>>>(buf, w2b, buf, 64, part1, part2, st2a, nullptr, 1.f, nullptr, nullptr);
  stats_reduce<<<64, 256, 0, stream>>>(part1, part2, st2b, 2560, 64, 327680.f);
  colmax<<<4096, 256, 0, stream>>>(buf, st2b, xper, 64);    // x2

  // --- global embedding (bf16 MFMA stats pass + fused BN/lrelu/max pass, no z3) ---
  gemm_mfma<128,0,1><<<dim3(128,16), 256, 0, stream>>>(xper, w3, nullptr, 1024, part1, part2, nullptr, nullptr, 1.f, nullptr, nullptr);
  stats_reduce<<<1024, 256, 0, stream>>>(part1, part2, st3, 128, 1024, 16384.f);
  hipMemsetAsync(xglob, 0, 4096*sizeof(unsigned), stream);
  gemm_mfma<128,0,2><<<dim3(128,16), 256, 0, stream>>>(xper, w3, nullptr, 1024, nullptr, nullptr, nullptr, nullptr, 1.f, st3, xglob);

  // --- heads ---
  head<<<4, 256, 0, stream>>>(xglob, mu_w, mu_b, var_w, var_b, eps_z, dout, zv);
  cuboid<<<64, 256, 0, stream>>>(zv, enc_w, cw1, cw2, rot_w, rot_b, trans_w, trans_b,
                                 ext_w1, ext_b1, ext_w2, ext_b2, k_w, Kmb, rotb, trsb, dout);
  gemm_mfma<128,0,0><<<dim3(128,1), 256, 0, stream>>>(xper, q_w, part1, 64, nullptr, nullptr, nullptr, nullptr, 0.125f, nullptr, nullptr);
  attn<<<4096, 256, 0, stream>>>(part1, Kmb, rotb, trsb, dout);
}

// Round 9
// 529.414 us; speedup vs baseline: 1.7726x; 1.2655x over previous
//
#include <hip/hip_runtime.h>
#include <math.h>

#define BB 4
#define NN 4096
#define KK 20

typedef __bf16 bf16x8 __attribute__((ext_vector_type(8)));
typedef float  f32x4  __attribute__((ext_vector_type(4)));

__device__ __forceinline__ float lrelu(float x){ return x > 0.f ? x : 0.2f*x; }

// order-preserving f32 -> u32 (monotone), and inverse
__device__ __forceinline__ unsigned ordf(float v){
  unsigned u = __float_as_uint(v);
  return u ^ (((unsigned)((int)u >> 31)) | 0x80000000u);
}
__device__ __forceinline__ float iordf(unsigned o){
  unsigned u = (o & 0x80000000u) ? (o ^ 0x80000000u) : ~o;
  return __uint_as_float(u);
}

// ---------------------------------------------------------------------------
// Exact top-20 of 4096 keys per wave, PACKED-KEY variant (see r8 notes).
template<typename GetK>
__device__ __forceinline__ int topk20_v4(int lane, GetK getk){
  unsigned b0 = 0u, b1 = 0u, b2 = 0u;
  for (int s = 0; s < 64; ++s){
    unsigned v = getk(s, lane);
    unsigned nb0 = b0 > v ? b0 : v;
    unsigned m1  = b1 > v ? b1 : v;
    unsigned nb1 = m1 < b0 ? m1 : b0;     // min(b0, max(b1,v))
    unsigned m2  = b2 > v ? b2 : v;
    unsigned nb2 = m2 < b1 ? m2 : b1;     // min(b1, max(b2,v))
    b0 = nb0; b1 = nb1; b2 = nb2;
  }
  unsigned lastk = 0xFFFFFFFFu;
  int myj = 0;
  for (int r = 0; r < 20; ++r){
    unsigned m = b0;
    #pragma unroll
    for (int off = 32; off; off >>= 1){ unsigned o = __shfl_xor(m, off); if (o > m) m = o; }
    unsigned long long msk = __ballot(b0 == m);
    int wl = __ffsll(msk) - 1;
    int ss = 63 - (int)(m & 63u);
    if (lane == r) myj = (ss << 6) | wl;
    bool empty = false;
    if (lane == wl){
      lastk = m;
      b0 = b1; b1 = b2; b2 = 0u;
      empty = (b0 == 0u);
    }
    if (__any(empty)){
      unsigned lk = __shfl(lastk, wl);
      unsigned cv = getk(lane, wl);
      if (cv >= lk) cv = 0u;
      unsigned nv0 = 0u, nv1 = 0u, nv2 = 0u;
      #pragma unroll
      for (int t = 0; t < 3; ++t){
        unsigned mm = cv;
        #pragma unroll
        for (int off = 32; off; off >>= 1){ unsigned o = __shfl_xor(mm, off); if (o > mm) mm = o; }
        unsigned long long mk = __ballot(cv == mm && mm != 0u);
        if (mk){
          int src = __ffsll(mk) - 1;
          if (lane == src) cv = 0u;
        }
        if (t == 0) nv0 = mm; else if (t == 1) nv1 = mm; else nv2 = mm;
      }
      if (lane == wl){ b0 = nv0; b1 = nv1; b2 = nv2; }
    }
  }
  return myj;
}

// ---------------------------------------------------------------------------
// SoA + norm precompute: pts[g] = (x, y, z, x^2+y^2+z^2), g over B*N points.
__global__ __launch_bounds__(256) void soa_xyz(const float* __restrict__ xyz, float4* __restrict__ pts){
  int g = blockIdx.x*256 + threadIdx.x;
  const float* p = xyz + (size_t)g*3;
  float a0 = p[0], a1 = p[1], a2 = p[2];
  float xx = fmaf(a0, a0, fmaf(a1, a1, a2*a2));
  pts[g] = make_float4(a0, a1, a2, xx);
}

// kNN on xyz. One wave per row.
__global__ __launch_bounds__(256) void knn_xyz(const float4* __restrict__ pts, int* __restrict__ idx_out){
  int tid = threadIdx.x, wv = tid >> 6, lane = tid & 63;
  int row = blockIdx.x * 4 + wv;
  int b = row >> 12, i = row & 4095;
  const float4* pb = pts + ((size_t)b << 12);
  float4 pi = pb[i];
  float xi0 = pi.x, xi1 = pi.y, xi2 = pi.z, xxi = pi.w;
  auto getk = [=](int s, int L)->unsigned{
    float4 p = pb[(s << 6) + L];
    float inner = fmaf(xi0, p.x, fmaf(xi1, p.y, xi2*p.z));
    float d = fmaf(2.f, inner, -xxi) - p.w;
    return (ordf(d) & 0xFFFFFFC0u) | (unsigned)(63 - s);
  };
  int myj = topk20_v4(lane, getk);
  if (lane < 20) idx_out[(size_t)row*20 + lane] = myj;
}

// top-20 per row from pre-packed key matrix [4096][4096]
__global__ __launch_bounds__(256) void topk_rows(const unsigned* __restrict__ dg, int* __restrict__ idx_out){
  int tid = threadIdx.x, wv = tid >> 6, lane = tid & 63;
  int i = blockIdx.x * 4 + wv;
  const unsigned* drow = dg + (size_t)i * 4096;
  auto getk = [=](int s, int L)->unsigned{ return drow[(s << 6) + L]; };
  int myj = topk20_v4(lane, getk);
  if (lane < 20) idx_out[(size_t)i*20 + lane] = myj;
}

// ---------------------------------------------------------------------------
// Gram -> packed top-k keys via SPLIT-BF16 MFMA (r9).
// x = hi + lo (hi=bf16(x), lo=bf16(x-hi)); G ~= hi.hi + hi.lo + lo.hi (f32 acc).
// Missing lo.lo term ~4e-6 relative -- same class as the 26-bit key truncation.
// Full 32x32 grid (no symmetric skip): compute is cheap, writes identical.
// Block: 256 thr / 4 waves; tile 128 rows x 128 cols; K=64; 64KB LDS.
__global__ __launch_bounds__(256) void gram_mfma(const float* __restrict__ x1, const float* __restrict__ xx,
                                                 unsigned* __restrict__ dg){
  __shared__ __align__(16) char Ahi[128*128];
  __shared__ __align__(16) char Alo[128*128];
  __shared__ __align__(16) char Bhi[128*128];
  __shared__ __align__(16) char Blo[128*128];
  int tid = threadIdx.x, wv = tid >> 6, lane = tid & 63;
  int it = blockIdx.y, jt = blockIdx.x;
  for (int q = 0; q < 4; ++q){
    int e = q*256 + tid;
    int r = e >> 3, c8 = e & 7;
    int k0 = c8*8;
    int off = r*128 + ((k0*2) ^ ((r & 7) << 4));
    {
      const float* src = &x1[(size_t)(it*128 + r)*128 + k0];
      float4 v1 = *(const float4*)src, v2 = *(const float4*)(src+4);
      float f[8] = {v1.x,v1.y,v1.z,v1.w,v2.x,v2.y,v2.z,v2.w};
      bf16x8 hv, lv;
      #pragma unroll
      for (int i2 = 0; i2 < 8; ++i2){ hv[i2] = (__bf16)f[i2]; lv[i2] = (__bf16)(f[i2] - (float)hv[i2]); }
      *(bf16x8*)&Ahi[off] = hv; *(bf16x8*)&Alo[off] = lv;
    }
    {
      const float* src = &x1[(size_t)(jt*128 + r)*128 + k0];
      float4 v1 = *(const float4*)src, v2 = *(const float4*)(src+4);
      float f[8] = {v1.x,v1.y,v1.z,v1.w,v2.x,v2.y,v2.z,v2.w};
      bf16x8 hv, lv;
      #pragma unroll
      for (int i2 = 0; i2 < 8; ++i2){ hv[i2] = (__bf16)f[i2]; lv[i2] = (__bf16)(f[i2] - (float)hv[i2]); }
      *(bf16x8*)&Bhi[off] = hv; *(bf16x8*)&Blo[off] = lv;
    }
  }
  __syncthreads();
  int lr = lane & 15, hi16 = lane >> 4;
  f32x4 acc[2][8];
  #pragma unroll
  for (int a_ = 0; a_ < 2; ++a_)
    #pragma unroll
    for (int b_ = 0; b_ < 8; ++b_){ acc[a_][b_][0]=0.f; acc[a_][b_][1]=0.f; acc[a_][b_][2]=0.f; acc[a_][b_][3]=0.f; }
  int wrow = wv*32;
  for (int ks = 0; ks < 2; ++ks){
    int kb = ks*64 + hi16*16;
    bf16x8 ah[2], al[2];
    #pragma unroll
    for (int rf = 0; rf < 2; ++rf){
      int row = wrow + rf*16 + lr;
      int off = row*128 + (kb ^ ((row & 7) << 4));
      ah[rf] = *(const bf16x8*)&Ahi[off];
      al[rf] = *(const bf16x8*)&Alo[off];
    }
    #pragma unroll
    for (int cf = 0; cf < 8; ++cf){
      int cr = cf*16 + lr;
      int off = cr*128 + (kb ^ ((cr & 7) << 4));
      bf16x8 bh = *(const bf16x8*)&Bhi[off];
      bf16x8 bl = *(const bf16x8*)&Blo[off];
      #pragma unroll
      for (int rf = 0; rf < 2; ++rf){
        acc[rf][cf] = __builtin_amdgcn_mfma_f32_16x16x32_bf16(ah[rf], bh, acc[rf][cf], 0, 0, 0);
        acc[rf][cf] = __builtin_amdgcn_mfma_f32_16x16x32_bf16(ah[rf], bl, acc[rf][cf], 0, 0, 0);
        acc[rf][cf] = __builtin_amdgcn_mfma_f32_16x16x32_bf16(al[rf], bh, acc[rf][cf], 0, 0, 0);
      }
    }
  }
  // epilogue: d = -xxi + 2*G - xxj -> packed key
  int rowg = it*128 + wrow;
  float xxi[2][4];
  #pragma unroll
  for (int rf = 0; rf < 2; ++rf)
    #pragma unroll
    for (int r4 = 0; r4 < 4; ++r4) xxi[rf][r4] = xx[rowg + rf*16 + hi16*4 + r4];
  #pragma unroll
  for (int cf = 0; cf < 8; ++cf){
    int colg = jt*128 + cf*16 + lr;
    float xxj = xx[colg];
    unsigned tag = 63u - (unsigned)(jt*2 + (cf >> 2));
    #pragma unroll
    for (int rf = 0; rf < 2; ++rf)
      #pragma unroll
      for (int r4 = 0; r4 < 4; ++r4){
        float d = -xxi[rf][r4] + 2.f*acc[rf][cf][r4] - xxj;
        dg[(size_t)(rowg + rf*16 + hi16*4 + r4)*4096 + colg] = (ordf(d) & 0xFFFFFFC0u) | tag;
      }
  }
}

__global__ __launch_bounds__(256) void row_norms(const float* __restrict__ xper, float* __restrict__ xx){
  int wv = threadIdx.x >> 6, lane = threadIdx.x & 63;
  int row = blockIdx.x * 4 + wv;
  float v = xper[(size_t)row*128 + lane];
  float s = v*v;
  #pragma unroll
  for (int off = 32; off; off >>= 1) s += __shfl_xor(s, off);
  if (lane == 0) xx[row] = s;
}

// ---------------------------------------------------------------------------
// stats of z1a = graph_feature(xyz) @ w1a^T, no materialization.
__global__ __launch_bounds__(256) void stats1a(const float4* __restrict__ pts, const int* __restrict__ idx,
                                               const float* __restrict__ w1a,
                                               float* __restrict__ part1, float* __restrict__ part2){
  int tid = threadIdx.x, wv = tid >> 6, lane = tid & 63;
  float w[6];
  #pragma unroll
  for (int c = 0; c < 6; ++c) w[c] = w1a[lane*6 + c];
  float s1 = 0.f, s2 = 0.f;
  int p0 = blockIdx.x*16 + wv*4;
  for (int pp = 0; pp < 4; ++pp){
    int bn = p0 + pp; int b = bn >> 12, i = bn & 4095;
    const float4* pb = pts + ((size_t)b << 12);
    float4 pi = pb[i];
    float i0 = pi.x, i1 = pi.y, i2 = pi.z;
    for (int k = 0; k < 20; ++k){
      int j = idx[bn*20 + k];
      float4 pj = pb[j];
      float z = w[0]*(pj.x-i0) + w[1]*(pj.y-i1) + w[2]*(pj.z-i2) + w[3]*i0 + w[4]*i1 + w[5]*i2;
      s1 += z; s2 += z*z;
    }
  }
  __shared__ float red[2][4][64];
  red[0][wv][lane] = s1; red[1][wv][lane] = s2;
  __syncthreads();
  if (tid < 64)
    part1[(size_t)blockIdx.x*64 + tid] = red[0][0][tid]+red[0][1][tid]+red[0][2][tid]+red[0][3][tid];
  else if (tid < 128){
    int c = tid - 64;
    part2[(size_t)blockIdx.x*64 + c] = red[1][0][c]+red[1][1][c]+red[1][2][c]+red[1][3][c];
  }
}

// ---------------------------------------------------------------------------
// Fused block-1 (r9): recompute z1a, h = lrelu(bn(z1a)) in LDS, gemm w1b,
// channel stats partials + STORE z1b to zout (colmax finishes BN+lrelu+kmax).
// x1 stays bit-identical to r8 (same MAC order). k4 loop NOT unrolled (r3).
__global__ __launch_bounds__(128) void fused1s(const float4* __restrict__ pts, const int* __restrict__ idx,
                                               const float* __restrict__ w1a, const float* __restrict__ w1b,
                                               const float* __restrict__ st_a,
                                               float* __restrict__ part1, float* __restrict__ part2,
                                               float* __restrict__ zout){
  __shared__ __align__(16) float h[80*68];
  __shared__ __align__(16) float wl[64*68];
  __shared__ float pr[2][2][64];
  int tid = threadIdx.x, wv = tid >> 6, lane = tid & 63;
  int p0 = blockIdx.x * 4;
  {
    int c = tid >> 1, kh = tid & 1;
    for (int u = 0; u < 8; ++u)
      *(float4*)&wl[c*68 + kh*32 + u*4] = *(const float4*)&w1b[c*64 + kh*32 + u*4];
  }
  {
    float w[6];
    #pragma unroll
    for (int c = 0; c < 6; ++c) w[c] = w1a[lane*6 + c];
    float ma = st_a[lane], ra = st_a[64 + lane];
    for (int g = 0; g < 2; ++g){
      int pt = wv*2 + g; int bn = p0 + pt; int b = bn >> 12, i = bn & 4095;
      const float4* pb = pts + ((size_t)b << 12);
      float4 pi = pb[i];
      float i0 = pi.x, i1 = pi.y, i2 = pi.z;
      for (int kk = 0; kk < 20; ++kk){
        int j = idx[bn*20 + kk];
        float4 pj = pb[j];
        float z = w[0]*(pj.x-i0) + w[1]*(pj.y-i1) + w[2]*(pj.z-i2) + w[3]*i0 + w[4]*i1 + w[5]*i2;
        h[(pt*20 + kk)*68 + lane] = lrelu((z - ma)*ra);
      }
    }
  }
  __syncthreads();
  int ly = lane >> 3, lx = lane & 7;
  float acc[5][8] = {};
  for (int k4 = 0; k4 < 16; ++k4){          // NOT unrolled
    float a[5][4], bb[8][4];
    #pragma unroll
    for (int p = 0; p < 5; ++p){
      float4 v = *(const float4*)&h[(wv*40 + ly + 8*p)*68 + k4*4];
      a[p][0]=v.x; a[p][1]=v.y; a[p][2]=v.z; a[p][3]=v.w;
    }
    #pragma unroll
    for (int q = 0; q < 8; ++q){
      float4 u = *(const float4*)&wl[(lx + 8*q)*68 + k4*4];
      bb[q][0]=u.x; bb[q][1]=u.y; bb[q][2]=u.z; bb[q][3]=u.w;
    }
    #pragma unroll
    for (int kk = 0; kk < 4; ++kk)
      #pragma unroll
      for (int p = 0; p < 5; ++p)
        #pragma unroll
        for (int q = 0; q < 8; ++q)
          acc[p][q] += a[p][kk] * bb[q][kk];
  }
  // stats partials (shuffle over ly) -- unchanged semantics
  #pragma unroll
  for (int q = 0; q < 8; ++q){
    float s1 = 0.f, s2 = 0.f;
    #pragma unroll
    for (int p = 0; p < 5; ++p){ float v = acc[p][q]; s1 += v; s2 += v*v; }
    #pragma unroll
    for (int off = 8; off < 64; off <<= 1){ s1 += __shfl_xor(s1, off); s2 += __shfl_xor(s2, off); }
    if (ly == 0){ pr[wv][0][lx + 8*q] = s1; pr[wv][1][lx + 8*q] = s2; }
  }
  // park raw z1b in h (own-wave rows; no cross-wave hazard before barrier)
  #pragma unroll
  for (int p = 0; p < 5; ++p)
    #pragma unroll
    for (int q = 0; q < 8; ++q)
      h[(wv*40 + ly + 8*p)*68 + (lx + 8*q)] = acc[p][q];
  __syncthreads();
  if (tid < 64) part1[(size_t)blockIdx.x*64 + tid] = pr[0][0][tid] + pr[1][0][tid];
  else if (tid < 128){ int c = tid - 64; part2[(size_t)blockIdx.x*64 + c] = pr[0][1][c] + pr[1][1][c]; }
  // coalesced store: 80 rows x 64 cols, float4
  for (int it2 = 0; it2 < 10; ++it2){
    int e4 = it2*128 + tid;
    int r = e4 >> 4, c4 = e4 & 15;
    float4 v = *(const float4*)&h[r*68 + c4*4];
    *(float4*)&zout[((size_t)p0*20 + r)*64 + c4*4] = v;
  }
}

// ---------------------------------------------------------------------------
// MFMA rows-GEMM (bf16 inputs, f32 accum). See r5 notes; unchanged.
template<int CIN, int VAR, int OUT>
__global__ __launch_bounds__(256) void gemm_mfma(const float* A, const float* __restrict__ W,
                                                 float* out, int ostride,
                                                 float* __restrict__ part1, float* __restrict__ part2,
                                                 const float* __restrict__ statsIn,
                                                 const int* __restrict__ idx, float oscale,
                                                 const float* __restrict__ statsIn2,
                                                 unsigned* __restrict__ xglob){
  constexpr int ROWB = CIN*2;
  constexpr int CH8  = CIN/8;
  constexpr int SH   = (CIN == 128) ? 4 : 3;
  __shared__ __align__(16) char Al[128*ROWB];
  __shared__ __align__(16) char Bl[64*ROWB];
  __shared__ float pls[4][2][64];
  int tid = threadIdx.x, wv = tid >> 6, lane = tid & 63;
  int rowbase = blockIdx.x*128, chb = blockIdx.y;

  for (int q = 0; q < (128*CH8)/256; ++q){
    int e = q*256 + tid;
    int r = e >> SH, c8 = e & (CH8-1);
    int k0 = c8*8;
    float f[8];
    if (VAR == 2){
      int row = rowbase + r;
      int bn = row / 20; int b = bn >> 12;
      int j = idx[row];
      const float* xi = A + (size_t)bn*128;
      const float* xj = A + ((size_t)(b << 12) + j)*128;
      if (k0 < 64){
        float4 a1 = *(const float4*)&xj[k0];  float4 a2 = *(const float4*)&xj[k0+4];
        float4 b1 = *(const float4*)&xi[k0];  float4 b2 = *(const float4*)&xi[k0+4];
        f[0]=a1.x-b1.x; f[1]=a1.y-b1.y; f[2]=a1.z-b1.z; f[3]=a1.w-b1.w;
        f[4]=a2.x-b2.x; f[5]=a2.y-b2.y; f[6]=a2.z-b2.z; f[7]=a2.w-b2.w;
      } else {
        float4 b1 = *(const float4*)&xi[k0-64]; float4 b2 = *(const float4*)&xi[k0-60];
        f[0]=b1.x; f[1]=b1.y; f[2]=b1.z; f[3]=b1.w;
        f[4]=b2.x; f[5]=b2.y; f[6]=b2.z; f[7]=b2.w;
      }
    } else {
      const float* src = &A[(size_t)(rowbase + r)*CIN + k0];
      float4 v1 = *(const float4*)src; float4 v2 = *(const float4*)(src+4);
      f[0]=v1.x; f[1]=v1.y; f[2]=v1.z; f[3]=v1.w;
      f[4]=v2.x; f[5]=v2.y; f[6]=v2.z; f[7]=v2.w;
      if (VAR == 1){
        float4 m1 = *(const float4*)&statsIn[k0];     float4 m2 = *(const float4*)&statsIn[k0+4];
        float4 r1 = *(const float4*)&statsIn[CIN+k0]; float4 r2 = *(const float4*)&statsIn[CIN+k0+4];
        f[0]=lrelu((f[0]-m1.x)*r1.x); f[1]=lrelu((f[1]-m1.y)*r1.y);
        f[2]=lrelu((f[2]-m1.z)*r1.z); f[3]=lrelu((f[3]-m1.w)*r1.w);
        f[4]=lrelu((f[4]-m2.x)*r2.x); f[5]=lrelu((f[5]-m2.y)*r2.y);
        f[6]=lrelu((f[6]-m2.z)*r2.z); f[7]=lrelu((f[7]-m2.w)*r2.w);
      }
    }
    bf16x8 hv;
    #pragma unroll
    for (int i2 = 0; i2 < 8; ++i2) hv[i2] = (__bf16)f[i2];
    *(bf16x8*)&Al[r*ROWB + ((k0*2) ^ ((r & 7) << 4))] = hv;
  }
  for (int q = 0; q < (64*CH8)/256; ++q){
    int e = q*256 + tid;
    int r = e >> SH, c8 = e & (CH8-1);
    int k0 = c8*8;
    const float* src = &W[(size_t)(chb*64 + r)*CIN + k0];
    float4 v1 = *(const float4*)src; float4 v2 = *(const float4*)(src+4);
    float f[8] = {v1.x,v1.y,v1.z,v1.w,v2.x,v2.y,v2.z,v2.w};
    bf16x8 hv;
    #pragma unroll
    for (int i2 = 0; i2 < 8; ++i2) hv[i2] = (__bf16)f[i2];
    *(bf16x8*)&Bl[r*ROWB + ((k0*2) ^ ((r & 7) << 4))] = hv;
  }
  __syncthreads();

  int lr = lane & 15, hi = lane >> 4;
  f32x4 acc[2][4];
  #pragma unroll
  for (int a_ = 0; a_ < 2; ++a_)
    #pragma unroll
    for (int b_ = 0; b_ < 4; ++b_){ acc[a_][b_][0]=0.f; acc[a_][b_][1]=0.f; acc[a_][b_][2]=0.f; acc[a_][b_][3]=0.f; }
  int wrow = wv*32;
  for (int ks = 0; ks < CIN/32; ++ks){
    int kb = ks*64 + hi*16;
    bf16x8 af[2], bfr[4];
    #pragma unroll
    for (int rf = 0; rf < 2; ++rf){
      int row = wrow + rf*16 + lr;
      af[rf] = *(const bf16x8*)&Al[row*ROWB + (kb ^ ((row & 7) << 4))];
    }
    #pragma unroll
    for (int cf = 0; cf < 4; ++cf){
      int cr = cf*16 + lr;
      bfr[cf] = *(const bf16x8*)&Bl[cr*ROWB + (kb ^ ((cr & 7) << 4))];
    }
    #pragma unroll
    for (int rf = 0; rf < 2; ++rf)
      #pragma unroll
      for (int cf = 0; cf < 4; ++cf)
        acc[rf][cf] = __builtin_amdgcn_mfma_f32_16x16x32_bf16(af[rf], bfr[cf], acc[rf][cf], 0, 0, 0);
  }

  if (OUT == 0){
    #pragma unroll
    for (int rf = 0; rf < 2; ++rf)
      #pragma unroll
      for (int cf = 0; cf < 4; ++cf)
        #pragma unroll
        for (int r4 = 0; r4 < 4; ++r4){
          int row = rowbase + wrow + rf*16 + hi*4 + r4;
          out[(size_t)row*ostride + chb*64 + cf*16 + lr] = acc[rf][cf][r4] * oscale;
        }
  }
  if (OUT != 2 && part1){
    #pragma unroll
    for (int cf = 0; cf < 4; ++cf){
      float s1 = 0.f, s2 = 0.f;
      #pragma unroll
      for (int rf = 0; rf < 2; ++rf)
        #pragma unroll
        for (int r4 = 0; r4 < 4; ++r4){ float v = acc[rf][cf][r4]; s1 += v; s2 += v*v; }
      s1 += __shfl_xor(s1, 16); s1 += __shfl_xor(s1, 32);
      s2 += __shfl_xor(s2, 16); s2 += __shfl_xor(s2, 32);
      if (hi == 0){ pls[wv][0][cf*16 + lr] = s1; pls[wv][1][cf*16 + lr] = s2; }
    }
    __syncthreads();
    int nchTot = gridDim.y * 64;
    if (tid < 64)
      part1[(size_t)blockIdx.x*nchTot + chb*64 + tid] = pls[0][0][tid]+pls[1][0][tid]+pls[2][0][tid]+pls[3][0][tid];
    else if (tid < 128){
      int c = tid - 64;
      part2[(size_t)blockIdx.x*nchTot + chb*64 + c] = pls[0][1][c]+pls[1][1][c]+pls[2][1][c]+pls[3][1][c];
    }
  }
  if (OUT == 2){
    int nchTot = gridDim.y * 64;
    int b = rowbase >> 12;
    #pragma unroll
    for (int cf = 0; cf < 4; ++cf){
      int col = chb*64 + cf*16 + lr;
      float m2 = statsIn2[col], rs2 = statsIn2[nchTot + col];
      float mv = -INFINITY;
      #pragma unroll
      for (int rf = 0; rf < 2; ++rf)
        #pragma unroll
        for (int r4 = 0; r4 < 4; ++r4) mv = fmaxf(mv, lrelu((acc[rf][cf][r4] - m2)*rs2));
      mv = fmaxf(mv, __shfl_xor(mv, 16));
      mv = fmaxf(mv, __shfl_xor(mv, 32));
      if (hi == 0) pls[wv][0][cf*16 + lr] = mv;
    }
    __syncthreads();
    if (tid < 64)
      atomicMax(&xglob[b*nchTot + chb*64 + tid],
                ordf(fmaxf(fmaxf(pls[0][0][tid], pls[1][0][tid]), fmaxf(pls[2][0][tid], pls[3][0][tid]))));
  }
}

// deterministic partial -> (mean, rstd) per channel
__global__ __launch_bounds__(256) void stats_reduce(const float* __restrict__ p1, const float* __restrict__ p2,
                                                    float* __restrict__ statsOut, int nblk, int nch, float count){
  int ch = blockIdx.x, tid = threadIdx.x;
  float s1 = 0.f, s2 = 0.f;
  for (int i = tid; i < nblk; i += 256){ s1 += p1[(size_t)i*nch + ch]; s2 += p2[(size_t)i*nch + ch]; }
  __shared__ float r1[256], r2[256];
  r1[tid] = s1; r2[tid] = s2;
  __syncthreads();
  for (int off = 128; off; off >>= 1){
    if (tid < off){ r1[tid] += r1[tid+off]; r2[tid] += r2[tid+off]; }
    __syncthreads();
  }
  if (tid == 0){
    float m = r1[0] / count;
    float var = r2[0] / count - m*m;
    if (var < 0.f) var = 0.f;
    statsOut[ch] = m;
    statsOut[nch + ch] = rsqrtf(var + 1e-5f);
  }
}

// bn+lrelu then max over k=20 -> xper[:, off..off+63]
__global__ __launch_bounds__(256) void colmax(const float* __restrict__ buf, const float* __restrict__ st,
                                              float* __restrict__ xper, int off){
  int wv = threadIdx.x >> 6, lane = threadIdx.x & 63;
  int bn = blockIdx.x*4 + wv;
  float m = st[lane], rs = st[64 + lane];
  float mx = -INFINITY;
  for (int k = 0; k < 20; ++k){
    float z = buf[((size_t)bn*20 + k)*64 + lane];
    mx = fmaxf(mx, lrelu((z - m)*rs));
  }
  xper[(size_t)bn*128 + off + lane] = mx;
}

__global__ __launch_bounds__(256) void head(const unsigned* __restrict__ xglob,
                                            const float* __restrict__ mu_w, const float* __restrict__ mu_b,
                                            const float* __restrict__ var_w, const float* __restrict__ var_b,
                                            const float* __restrict__ eps_z, float* __restrict__ dout,
                                            float* __restrict__ zv){
  __shared__ __align__(16) float xg[1024];
  int b = blockIdx.x, t = threadIdx.x;
  for (int q = 0; q < 4; ++q) xg[q*256 + t] = iordf(xglob[b*1024 + q*256 + t]);
  __syncthreads();
  if (t < 128){
    float s1 = 0.f, s2 = 0.f;
    for (int c = 0; c < 1024; c += 4){
      float4 xv = *(const float4*)&xg[c];
      float4 wa = *(const float4*)&mu_w[(size_t)t*1024 + c];
      float4 wb = *(const float4*)&var_w[(size_t)t*1024 + c];
      s1 += wa.x*xv.x + wa.y*xv.y + wa.z*xv.z + wa.w*xv.w;
      s2 += wb.x*xv.x + wb.y*xv.y + wb.z*xv.z + wb.w*xv.w;
    }
    float mu = s1 + mu_b[t];
    float lv = s2 + var_b[t];
    dout[458816 + b*128 + t] = mu;
    dout[459328 + b*128 + t] = lv;
    zv[b*128 + t] = eps_z[b*128 + t] * expf(0.5f*lv) + mu;
  }
}

// cuboid MLP + Para_pred per (b,m)
__global__ __launch_bounds__(256) void cuboid(const float* __restrict__ zv, const float* __restrict__ enc_w,
                                              const float* __restrict__ w1, const float* __restrict__ w2,
                                              const float* __restrict__ rot_w, const float* __restrict__ rot_b,
                                              const float* __restrict__ trans_w, const float* __restrict__ trans_b,
                                              const float* __restrict__ ext_w1, const float* __restrict__ ext_b1,
                                              const float* __restrict__ ext_w2, const float* __restrict__ ext_b2,
                                              const float* __restrict__ k_w, float* __restrict__ Km,
                                              float* __restrict__ rot, float* __restrict__ trs,
                                              float* __restrict__ dout){
  int bm = blockIdx.x; int b = bm >> 4, m = bm & 15; int t = threadIdx.x;
  __shared__ __align__(16) float xc[192];
  __shared__ __align__(16) float h1[256];
  __shared__ __align__(16) float xcu[128];
  __shared__ float qv[4]; __shared__ float ev[30];
  if (t < 192) xc[t] = (t < 128) ? zv[b*128 + t] : lrelu(enc_w[(t-128)*16 + m]);
  __syncthreads();
  {
    float s = 0.f; const float* wr = w1 + (size_t)t*192;
    for (int c = 0; c < 192; c += 4){
      float4 w4 = *(const float4*)&wr[c]; float4 x4 = *(const float4*)&xc[c];
      s += w4.x*x4.x + w4.y*x4.y + w4.z*x4.z + w4.w*x4.w;
    }
    h1[t] = lrelu(s);
  }
  __syncthreads();
  if (t < 128){
    float s = 0.f; const float* wr = w2 + (size_t)t*256;
    for (int c = 0; c < 256; c += 4){
      float4 w4 = *(const float4*)&wr[c]; float4 x4 = *(const float4*)&h1[c];
      s += w4.x*x4.x + w4.y*x4.y + w4.z*x4.z + w4.w*x4.w;
    }
    xcu[t] = lrelu(s);
  }
  __syncthreads();
  if (t < 64){
    float s = 0.f;
    for (int c = 0; c < 128; ++c) s += xcu[c]*k_w[(size_t)t*128 + c];
    Km[(size_t)(b*16 + m)*64 + t] = s;
  } else if (t < 68){
    int o = t - 64; float s = rot_b[o];
    for (int c = 0; c < 128; ++c) s += xcu[c]*rot_w[(size_t)o*128 + c];
    qv[o] = s;
  } else if (t < 71){
    int o = t - 68; float s = trans_b[o];
    for (int c = 0; c < 128; ++c) s += xcu[c]*trans_w[(size_t)o*128 + c];
    trs[(size_t)(b*16 + m)*3 + o] = tanhf(s);
  } else if (t < 101){
    int o = t - 71; float s = ext_b1[o];
    for (int c = 0; c < 128; ++c) s += xcu[c]*ext_w1[(size_t)o*128 + c];
    ev[o] = lrelu(s);
  }
  __syncthreads();
  if (t == 0){
    float w = qv[0], x = qv[1], y = qv[2], z = qv[3];
    float nrm = sqrtf(w*w + x*x + y*y + z*z);
    float inv = 1.f / fmaxf(nrm, 1e-12f);
    w *= inv; x *= inv; y *= inv; z *= inv;
    float xx2 = x*x, yy = y*y, zz = z*z;
    float* r = rot + (size_t)(b*16 + m)*9;
    r[0] = 1.f - 2.f*(yy + zz); r[1] = 2.f*(x*y - w*z); r[2] = 2.f*(x*z + w*y);
    r[3] = 2.f*(x*y + w*z); r[4] = 1.f - 2.f*(xx2 + zz); r[5] = 2.f*(y*z - w*x);
    r[6] = 2.f*(x*z - w*y); r[7] = 2.f*(y*z + w*x); r[8] = 1.f - 2.f*(xx2 + yy);
  }
  if (t == 1){
    float s = ext_b2[0];
    for (int o = 0; o < 30; ++o) s += ev[o]*ext_w2[o];
    dout[458752 + b*16 + m] = s;
  }
}

// attention epilogue
__global__ __launch_bounds__(256) void attn(const float* __restrict__ Qbuf, const float* __restrict__ Km,
                                            const float* __restrict__ rot, const float* __restrict__ trs,
                                            float* __restrict__ dout){
  __shared__ float kml[16*64];
  __shared__ float rl[144], tl[48];
  __shared__ float Ql[4][64];
  __shared__ float al[4][16];
  int tid = threadIdx.x, wv = tid >> 6, lane = tid & 63;
  int bn0 = blockIdx.x*4; int b = bn0 >> 12;
  for (int e = tid; e < 1024; e += 256){
    int m = e >> 6, d = e & 63;
    kml[m*64 + (d ^ ((m & 15) << 2))] = Km[(size_t)b*1024 + e];
  }
  if (tid < 144) rl[tid] = rot[(size_t)b*144 + tid];
  if (tid < 48)  tl[tid] = trs[(size_t)b*48 + tid];
  __syncthreads();
  int bn = bn0 + wv;
  Ql[wv][lane] = Qbuf[(size_t)bn*64 + lane];
  if (lane < 16){
    float sc = 0.f;
    for (int d = 0; d < 64; ++d) sc += Ql[wv][d] * kml[lane*64 + (d ^ ((lane & 15) << 2))];
    float mx = sc;
    #pragma unroll
    for (int off = 8; off; off >>= 1) mx = fmaxf(mx, __shfl_xor(mx, off));
    float e = expf(sc - mx);
    float sm = e;
    #pragma unroll
    for (int off = 8; off; off >>= 1) sm += __shfl_xor(sm, off);
    float a = e / sm;
    dout[(size_t)bn*16 + lane] = a;
    al[wv][lane] = a;
  }
  if (lane < 9){
    float s = 0.f;
    for (int m = 0; m < 16; ++m) s += al[wv][m] * rl[m*9 + lane];
    dout[262144 + (size_t)bn*9 + lane] = s;
  }
  if (lane >= 16 && lane < 19){
    int d = lane - 16;
    float s = 0.f;
    for (int m = 0; m < 16; ++m) s += al[wv][m] * tl[m*3 + d];
    dout[409600 + (size_t)bn*3 + d] = s;
  }
}

// ---------------------------------------------------------------------------
extern "C" void kernel_launch(void* const* d_in, const int* in_sizes, int n_in,
                              void* d_out, int out_size, void* d_ws, size_t ws_size,
                              hipStream_t stream){
  (void)in_sizes; (void)n_in; (void)out_size; (void)ws_size;
  const float* xyz     = (const float*)d_in[0];
  const float* eps_z   = (const float*)d_in[2];
  const float* w1a     = (const float*)d_in[3];
  const float* w1b     = (const float*)d_in[4];
  const float* w2a     = (const float*)d_in[5];
  const float* w2b     = (const float*)d_in[6];
  const float* w3      = (const float*)d_in[7];
  const float* mu_w    = (const float*)d_in[8];
  const float* mu_b    = (const float*)d_in[9];
  const float* var_w   = (const float*)d_in[10];
  const float* var_b   = (const float*)d_in[11];
  const float* enc_w   = (const float*)d_in[12];
  const float* cw1     = (const float*)d_in[13];
  const float* cw2     = (const float*)d_in[14];
  const float* q_w     = (const float*)d_in[15];
  const float* k_w     = (const float*)d_in[16];
  const float* rot_w   = (const float*)d_in[19];
  const float* rot_b   = (const float*)d_in[20];
  const float* trans_w = (const float*)d_in[21];
  const float* trans_b = (const float*)d_in[22];
  const float* ext_w1  = (const float*)d_in[23];
  const float* ext_b1  = (const float*)d_in[24];
  const float* ext_w2  = (const float*)d_in[25];
  const float* ext_b2  = (const float*)d_in[26];
  float* dout = (float*)d_out;

  char* wsb = (char*)d_ws;
  size_t off = 0;
  float* buf   = (float*)(wsb + off); off += 83886080;      // z1b/z2a/z2b [B,N,K,64] f32; reused as key matrix (64MB)
  int*   idx0  = (int*)(wsb + off);   off += 1310720;
  int*   idx1  = (int*)(wsb + off);   off += 1310720;
  float* xper  = (float*)(wsb + off); off += 8388608;       // [B,N,128] = [x1|x2]
  float* xx    = (float*)(wsb + off); off += 65536;
  float* part1 = (float*)(wsb + off); off += 4194304;       // reused as Qbuf
  float* part2 = (float*)(wsb + off); off += 4194304;
  float* st1a  = (float*)(wsb + off); off += 512;
  float* st1b  = (float*)(wsb + off); off += 512;
  float* st2a  = (float*)(wsb + off); off += 512;
  float* st2b  = (float*)(wsb + off); off += 512;
  float* st3   = (float*)(wsb + off); off += 8192;
  unsigned* xglob = (unsigned*)(wsb + off); off += 16384;
  float* zv    = (float*)(wsb + off); off += 2048;
  float* Kmb   = (float*)(wsb + off); off += 16384;
  float* rotb  = (float*)(wsb + off); off += 2304;
  float* trsb  = (float*)(wsb + off); off += 768;
  float4* pts  = (float4*)(wsb + off); off += 262144;       // [B*N] (x,y,z,|x|^2)

  // --- Feature_extract, block 1 (x1 bit-identical to r8) ---
  soa_xyz<<<64, 256, 0, stream>>>(xyz, pts);
  knn_xyz<<<4096, 256, 0, stream>>>(pts, idx0);
  stats1a<<<1024, 256, 0, stream>>>(pts, idx0, w1a, part1, part2);
  stats_reduce<<<64, 256, 0, stream>>>(part1, part2, st1a, 1024, 64, 327680.f);
  fused1s<<<4096, 128, 0, stream>>>(pts, idx0, w1a, w1b, st1a, part1, part2, buf);
  stats_reduce<<<64, 256, 0, stream>>>(part1, part2, st1b, 4096, 64, 327680.f);
  colmax<<<4096, 256, 0, stream>>>(buf, st1b, xper, 0);     // x1

  // --- knn on x1 (split-bf16 MFMA Gram -> packed keys -> topk), per batch ---
  row_norms<<<4096, 256, 0, stream>>>(xper, xx);
  for (int b = 0; b < 4; ++b){
    gram_mfma<<<dim3(32,32), 256, 0, stream>>>(xper + (size_t)b*NN*128, xx + (size_t)b*NN, (unsigned*)buf);
    topk_rows<<<1024, 256, 0, stream>>>((unsigned*)buf, idx1 + (size_t)b*NN*KK);
  }

  // --- Feature_extract, block 2 (bf16 MFMA) ---
  gemm_mfma<128,2,0><<<dim3(2560,1), 256, 0, stream>>>(xper, w2a, buf, 64, part1, part2, nullptr, idx1, 1.f, nullptr, nullptr);
  stats_reduce<<<64, 256, 0, stream>>>(part1, part2, st2a, 2560, 64, 327680.f);
  gemm_mfma<64,1,0><<<dim3(2560,1), 256, 0, stream>>>(buf, w2b, buf, 64, part1, part2, st2a, nullptr, 1.f, nullptr, nullptr);
  stats_reduce<<<64, 256, 0, stream>>>(part1, part2, st2b, 2560, 64, 327680.f);
  colmax<<<4096, 256, 0, stream>>>(buf, st2b, xper, 64);    // x2

  // --- global embedding (bf16 MFMA stats pass + fused BN/lrelu/max pass, no z3) ---
  gemm_mfma<128,0,1><<<dim3(128,16), 256, 0, stream>>>(xper, w3, nullptr, 1024, part1, part2, nullptr, nullptr, 1.f, nullptr, nullptr);
  stats_reduce<<<1024, 256, 0, stream>>>(part1, part2, st3, 128, 1024, 16384.f);
  hipMemsetAsync(xglob, 0, 4096*sizeof(unsigned), stream);
  gemm_mfma<128,0,2><<<dim3(128,16), 256, 0, stream>>>(xper, w3, nullptr, 1024, nullptr, nullptr, nullptr, nullptr, 1.f, st3, xglob);

  // --- heads ---
  head<<<4, 256, 0, stream>>>(xglob, mu_w, mu_b, var_w, var_b, eps_z, dout, zv);
  cuboid<<<64, 256, 0, stream>>>(zv, enc_w, cw1, cw2, rot_w, rot_b, trans_w, trans_b,
                                 ext_w1, ext_b1, ext_w2, ext_b2, k_w, Kmb, rotb, trsb, dout);
  gemm_mfma<128,0,0><<<dim3(128,1), 256, 0, stream>>>(xper, q_w, part1, 64, nullptr, nullptr, nullptr, nullptr, 0.125f, nullptr, nullptr);
  attn<<<4096, 256, 0, stream>>>(part1, Kmb, rotb, trsb, dout);
}

// Round 10
// 484.523 us; speedup vs baseline: 1.9368x; 1.0926x over previous
//
#include <hip/hip_runtime.h>
#include <math.h>

#define BB 4
#define NN 4096
#define KK 20

typedef __bf16 bf16x8 __attribute__((ext_vector_type(8)));
typedef float  f32x4  __attribute__((ext_vector_type(4)));

__device__ __forceinline__ float lrelu(float x){ return x > 0.f ? x : 0.2f*x; }

// order-preserving f32 -> u32 (monotone), and inverse
__device__ __forceinline__ unsigned ordf(float v){
  unsigned u = __float_as_uint(v);
  return u ^ (((unsigned)((int)u >> 31)) | 0x80000000u);
}
__device__ __forceinline__ float iordf(unsigned o){
  unsigned u = (o & 0x80000000u) ? (o ^ 0x80000000u) : ~o;
  return __uint_as_float(u);
}

// ---------------------------------------------------------------------------
// Exact top-20 of 4096 keys per wave, PACKED-KEY variant (see r8 notes).
template<typename GetK>
__device__ __forceinline__ int topk20_v4(int lane, GetK getk){
  unsigned b0 = 0u, b1 = 0u, b2 = 0u;
  for (int s = 0; s < 64; ++s){
    unsigned v = getk(s, lane);
    unsigned nb0 = b0 > v ? b0 : v;
    unsigned m1  = b1 > v ? b1 : v;
    unsigned nb1 = m1 < b0 ? m1 : b0;     // min(b0, max(b1,v))
    unsigned m2  = b2 > v ? b2 : v;
    unsigned nb2 = m2 < b1 ? m2 : b1;     // min(b1, max(b2,v))
    b0 = nb0; b1 = nb1; b2 = nb2;
  }
  unsigned lastk = 0xFFFFFFFFu;
  int myj = 0;
  for (int r = 0; r < 20; ++r){
    unsigned m = b0;
    #pragma unroll
    for (int off = 32; off; off >>= 1){ unsigned o = __shfl_xor(m, off); if (o > m) m = o; }
    unsigned long long msk = __ballot(b0 == m);
    int wl = __ffsll(msk) - 1;
    int ss = 63 - (int)(m & 63u);
    if (lane == r) myj = (ss << 6) | wl;
    bool empty = false;
    if (lane == wl){
      lastk = m;
      b0 = b1; b1 = b2; b2 = 0u;
      empty = (b0 == 0u);
    }
    if (__any(empty)){
      unsigned lk = __shfl(lastk, wl);
      unsigned cv = getk(lane, wl);
      if (cv >= lk) cv = 0u;
      unsigned nv0 = 0u, nv1 = 0u, nv2 = 0u;
      #pragma unroll
      for (int t = 0; t < 3; ++t){
        unsigned mm = cv;
        #pragma unroll
        for (int off = 32; off; off >>= 1){ unsigned o = __shfl_xor(mm, off); if (o > mm) mm = o; }
        unsigned long long mk = __ballot(cv == mm && mm != 0u);
        if (mk){
          int src = __ffsll(mk) - 1;
          if (lane == src) cv = 0u;
        }
        if (t == 0) nv0 = mm; else if (t == 1) nv1 = mm; else nv2 = mm;
      }
      if (lane == wl){ b0 = nv0; b1 = nv1; b2 = nv2; }
    }
  }
  return myj;
}

// ---------------------------------------------------------------------------
// SoA + norm precompute: pts[g] = (x, y, z, x^2+y^2+z^2), g over B*N points.
__global__ __launch_bounds__(256) void soa_xyz(const float* __restrict__ xyz, float4* __restrict__ pts){
  int g = blockIdx.x*256 + threadIdx.x;
  const float* p = xyz + (size_t)g*3;
  float a0 = p[0], a1 = p[1], a2 = p[2];
  float xx = fmaf(a0, a0, fmaf(a1, a1, a2*a2));
  pts[g] = make_float4(a0, a1, a2, xx);
}

// kNN on xyz. One wave per row.
__global__ __launch_bounds__(256) void knn_xyz(const float4* __restrict__ pts, int* __restrict__ idx_out){
  int tid = threadIdx.x, wv = tid >> 6, lane = tid & 63;
  int row = blockIdx.x * 4 + wv;
  int b = row >> 12, i = row & 4095;
  const float4* pb = pts + ((size_t)b << 12);
  float4 pi = pb[i];
  float xi0 = pi.x, xi1 = pi.y, xi2 = pi.z, xxi = pi.w;
  auto getk = [=](int s, int L)->unsigned{
    float4 p = pb[(s << 6) + L];
    float inner = fmaf(xi0, p.x, fmaf(xi1, p.y, xi2*p.z));
    float d = fmaf(2.f, inner, -xxi) - p.w;
    return (ordf(d) & 0xFFFFFFC0u) | (unsigned)(63 - s);
  };
  int myj = topk20_v4(lane, getk);
  if (lane < 20) idx_out[(size_t)row*20 + lane] = myj;
}

// top-20 per row from pre-packed key matrix [4096][4096]
__global__ __launch_bounds__(256) void topk_rows(const unsigned* __restrict__ dg, int* __restrict__ idx_out){
  int tid = threadIdx.x, wv = tid >> 6, lane = tid & 63;
  int i = blockIdx.x * 4 + wv;
  const unsigned* drow = dg + (size_t)i * 4096;
  auto getk = [=](int s, int L)->unsigned{ return drow[(s << 6) + L]; };
  int myj = topk20_v4(lane, getk);
  if (lane < 20) idx_out[(size_t)i*20 + lane] = myj;
}

// ---------------------------------------------------------------------------
// Gram -> packed top-k keys via SPLIT-BF16 MFMA (r9). See r9 notes.
__global__ __launch_bounds__(256) void gram_mfma(const float* __restrict__ x1, const float* __restrict__ xx,
                                                 unsigned* __restrict__ dg){
  __shared__ __align__(16) char Ahi[128*128];
  __shared__ __align__(16) char Alo[128*128];
  __shared__ __align__(16) char Bhi[128*128];
  __shared__ __align__(16) char Blo[128*128];
  int tid = threadIdx.x, wv = tid >> 6, lane = tid & 63;
  int it = blockIdx.y, jt = blockIdx.x;
  for (int q = 0; q < 4; ++q){
    int e = q*256 + tid;
    int r = e >> 3, c8 = e & 7;
    int k0 = c8*8;
    int off = r*128 + ((k0*2) ^ ((r & 7) << 4));
    {
      const float* src = &x1[(size_t)(it*128 + r)*128 + k0];
      float4 v1 = *(const float4*)src, v2 = *(const float4*)(src+4);
      float f[8] = {v1.x,v1.y,v1.z,v1.w,v2.x,v2.y,v2.z,v2.w};
      bf16x8 hv, lv;
      #pragma unroll
      for (int i2 = 0; i2 < 8; ++i2){ hv[i2] = (__bf16)f[i2]; lv[i2] = (__bf16)(f[i2] - (float)hv[i2]); }
      *(bf16x8*)&Ahi[off] = hv; *(bf16x8*)&Alo[off] = lv;
    }
    {
      const float* src = &x1[(size_t)(jt*128 + r)*128 + k0];
      float4 v1 = *(const float4*)src, v2 = *(const float4*)(src+4);
      float f[8] = {v1.x,v1.y,v1.z,v1.w,v2.x,v2.y,v2.z,v2.w};
      bf16x8 hv, lv;
      #pragma unroll
      for (int i2 = 0; i2 < 8; ++i2){ hv[i2] = (__bf16)f[i2]; lv[i2] = (__bf16)(f[i2] - (float)hv[i2]); }
      *(bf16x8*)&Bhi[off] = hv; *(bf16x8*)&Blo[off] = lv;
    }
  }
  __syncthreads();
  int lr = lane & 15, hi16 = lane >> 4;
  f32x4 acc[2][8];
  #pragma unroll
  for (int a_ = 0; a_ < 2; ++a_)
    #pragma unroll
    for (int b_ = 0; b_ < 8; ++b_){ acc[a_][b_][0]=0.f; acc[a_][b_][1]=0.f; acc[a_][b_][2]=0.f; acc[a_][b_][3]=0.f; }
  int wrow = wv*32;
  for (int ks = 0; ks < 2; ++ks){
    int kb = ks*64 + hi16*16;
    bf16x8 ah[2], al[2];
    #pragma unroll
    for (int rf = 0; rf < 2; ++rf){
      int row = wrow + rf*16 + lr;
      int off = row*128 + (kb ^ ((row & 7) << 4));
      ah[rf] = *(const bf16x8*)&Ahi[off];
      al[rf] = *(const bf16x8*)&Alo[off];
    }
    #pragma unroll
    for (int cf = 0; cf < 8; ++cf){
      int cr = cf*16 + lr;
      int off = cr*128 + (kb ^ ((cr & 7) << 4));
      bf16x8 bh = *(const bf16x8*)&Bhi[off];
      bf16x8 bl = *(const bf16x8*)&Blo[off];
      #pragma unroll
      for (int rf = 0; rf < 2; ++rf){
        acc[rf][cf] = __builtin_amdgcn_mfma_f32_16x16x32_bf16(ah[rf], bh, acc[rf][cf], 0, 0, 0);
        acc[rf][cf] = __builtin_amdgcn_mfma_f32_16x16x32_bf16(ah[rf], bl, acc[rf][cf], 0, 0, 0);
        acc[rf][cf] = __builtin_amdgcn_mfma_f32_16x16x32_bf16(al[rf], bh, acc[rf][cf], 0, 0, 0);
      }
    }
  }
  int rowg = it*128 + wrow;
  float xxi[2][4];
  #pragma unroll
  for (int rf = 0; rf < 2; ++rf)
    #pragma unroll
    for (int r4 = 0; r4 < 4; ++r4) xxi[rf][r4] = xx[rowg + rf*16 + hi16*4 + r4];
  #pragma unroll
  for (int cf = 0; cf < 8; ++cf){
    int colg = jt*128 + cf*16 + lr;
    float xxj = xx[colg];
    unsigned tag = 63u - (unsigned)(jt*2 + (cf >> 2));
    #pragma unroll
    for (int rf = 0; rf < 2; ++rf)
      #pragma unroll
      for (int r4 = 0; r4 < 4; ++r4){
        float d = -xxi[rf][r4] + 2.f*acc[rf][cf][r4] - xxj;
        dg[(size_t)(rowg + rf*16 + hi16*4 + r4)*4096 + colg] = (ordf(d) & 0xFFFFFFC0u) | tag;
      }
  }
}

__global__ __launch_bounds__(256) void row_norms(const float* __restrict__ xper, float* __restrict__ xx){
  int wv = threadIdx.x >> 6, lane = threadIdx.x & 63;
  int row = blockIdx.x * 4 + wv;
  float v = xper[(size_t)row*128 + lane];
  float s = v*v;
  #pragma unroll
  for (int off = 32; off; off >>= 1) s += __shfl_xor(s, off);
  if (lane == 0) xx[row] = s;
}

// ---------------------------------------------------------------------------
// stats of z1a = graph_feature(xyz) @ w1a^T, no materialization.
__global__ __launch_bounds__(256) void stats1a(const float4* __restrict__ pts, const int* __restrict__ idx,
                                               const float* __restrict__ w1a,
                                               float* __restrict__ part1, float* __restrict__ part2){
  int tid = threadIdx.x, wv = tid >> 6, lane = tid & 63;
  float w[6];
  #pragma unroll
  for (int c = 0; c < 6; ++c) w[c] = w1a[lane*6 + c];
  float s1 = 0.f, s2 = 0.f;
  int p0 = blockIdx.x*16 + wv*4;
  for (int pp = 0; pp < 4; ++pp){
    int bn = p0 + pp; int b = bn >> 12, i = bn & 4095;
    const float4* pb = pts + ((size_t)b << 12);
    float4 pi = pb[i];
    float i0 = pi.x, i1 = pi.y, i2 = pi.z;
    for (int k = 0; k < 20; ++k){
      int j = idx[bn*20 + k];
      float4 pj = pb[j];
      float z = w[0]*(pj.x-i0) + w[1]*(pj.y-i1) + w[2]*(pj.z-i2) + w[3]*i0 + w[4]*i1 + w[5]*i2;
      s1 += z; s2 += z*z;
    }
  }
  __shared__ float red[2][4][64];
  red[0][wv][lane] = s1; red[1][wv][lane] = s2;
  __syncthreads();
  if (tid < 64)
    part1[(size_t)blockIdx.x*64 + tid] = red[0][0][tid]+red[0][1][tid]+red[0][2][tid]+red[0][3][tid];
  else if (tid < 128){
    int c = tid - 64;
    part2[(size_t)blockIdx.x*64 + c] = red[1][0][c]+red[1][1][c]+red[1][2][c]+red[1][3][c];
  }
}

// ---------------------------------------------------------------------------
// Fused block-1 via SPLIT-BF16 MFMA (r10): recompute z1a (exact f32, same MAC
// order as r9), BN(st1a)+lrelu -> h, split h and w1b into hi/lo bf16, MFMA
// (hh + hl + lh, f32 acc) -> z1b store + channel stats partials.
// Tile: 128 rows x 64 ch per block (256 thr / 4 waves), K=64.
__global__ __launch_bounds__(256) void fused1m(const float4* __restrict__ pts, const int* __restrict__ idx,
                                               const float* __restrict__ w1a, const float* __restrict__ w1b,
                                               const float* __restrict__ st_a,
                                               float* __restrict__ part1, float* __restrict__ part2,
                                               float* __restrict__ zout){
  __shared__ __align__(16) char Ahi[128*128];
  __shared__ __align__(16) char Alo[128*128];
  __shared__ __align__(16) char Bhi[64*128];
  __shared__ __align__(16) char Blo[64*128];
  __shared__ float w1al[64*6];
  __shared__ float pls[4][2][64];
  int tid = threadIdx.x, wv = tid >> 6, lane = tid & 63;
  int rowbase = blockIdx.x*128;
  // stage w1a (384 floats) for broadcast reads
  if (tid < 192){ ((float2*)w1al)[tid] = ((const float2*)w1a)[tid]; }
  __syncthreads();
  // ---- stage A: 128 rows x 64 ch; recompute z1a -> BN -> lrelu -> split ----
  for (int q = 0; q < 4; ++q){
    int e = q*256 + tid;
    int r = e >> 3, c8 = e & 7;          // row r, channel chunk c8 (8 ch)
    int row = rowbase + r;
    int bn = row / 20; int b = bn >> 12;
    int j = idx[row];
    const float4* pb = pts + ((size_t)b << 12);
    float4 pi = pb[(size_t)(bn & 4095)];
    float4 pj = pb[j];
    float d0 = pj.x - pi.x, d1 = pj.y - pi.y, d2 = pj.z - pi.z;
    bf16x8 hv, lv;
    #pragma unroll
    for (int u = 0; u < 8; ++u){
      int c = c8*8 + u;
      const float* w = &w1al[c*6];
      float z = w[0]*d0 + w[1]*d1 + w[2]*d2 + w[3]*pi.x + w[4]*pi.y + w[5]*pi.z;
      float h = lrelu((z - st_a[c]) * st_a[64 + c]);
      hv[u] = (__bf16)h; lv[u] = (__bf16)(h - (float)hv[u]);
    }
    int off = r*128 + ((c8*16) ^ ((r & 7) << 4));
    *(bf16x8*)&Ahi[off] = hv; *(bf16x8*)&Alo[off] = lv;
  }
  // ---- stage B: w1b [64][64] split ----
  for (int q = 0; q < 2; ++q){
    int e = q*256 + tid;
    int r = e >> 3, c8 = e & 7;
    int k0 = c8*8;
    const float* src = &w1b[(size_t)r*64 + k0];
    float4 v1 = *(const float4*)src, v2 = *(const float4*)(src+4);
    float f[8] = {v1.x,v1.y,v1.z,v1.w,v2.x,v2.y,v2.z,v2.w};
    bf16x8 hv, lv;
    #pragma unroll
    for (int i2 = 0; i2 < 8; ++i2){ hv[i2] = (__bf16)f[i2]; lv[i2] = (__bf16)(f[i2] - (float)hv[i2]); }
    int off = r*128 + ((k0*2) ^ ((r & 7) << 4));
    *(bf16x8*)&Bhi[off] = hv; *(bf16x8*)&Blo[off] = lv;
  }
  __syncthreads();
  // ---- MFMA: wave wv rows [wv*32, +32), cols [0,64); K=64 ----
  int lr = lane & 15, hi = lane >> 4;
  f32x4 acc[2][4];
  #pragma unroll
  for (int a_ = 0; a_ < 2; ++a_)
    #pragma unroll
    for (int b_ = 0; b_ < 4; ++b_){ acc[a_][b_][0]=0.f; acc[a_][b_][1]=0.f; acc[a_][b_][2]=0.f; acc[a_][b_][3]=0.f; }
  int wrow = wv*32;
  for (int ks = 0; ks < 2; ++ks){
    int kb = ks*64 + hi*16;
    bf16x8 ah[2], al[2];
    #pragma unroll
    for (int rf = 0; rf < 2; ++rf){
      int row = wrow + rf*16 + lr;
      int off = row*128 + (kb ^ ((row & 7) << 4));
      ah[rf] = *(const bf16x8*)&Ahi[off];
      al[rf] = *(const bf16x8*)&Alo[off];
    }
    #pragma unroll
    for (int cf = 0; cf < 4; ++cf){
      int cr = cf*16 + lr;
      int off = cr*128 + (kb ^ ((cr & 7) << 4));
      bf16x8 bh = *(const bf16x8*)&Bhi[off];
      bf16x8 bl = *(const bf16x8*)&Blo[off];
      #pragma unroll
      for (int rf = 0; rf < 2; ++rf){
        acc[rf][cf] = __builtin_amdgcn_mfma_f32_16x16x32_bf16(ah[rf], bh, acc[rf][cf], 0, 0, 0);
        acc[rf][cf] = __builtin_amdgcn_mfma_f32_16x16x32_bf16(ah[rf], bl, acc[rf][cf], 0, 0, 0);
        acc[rf][cf] = __builtin_amdgcn_mfma_f32_16x16x32_bf16(al[rf], bh, acc[rf][cf], 0, 0, 0);
      }
    }
  }
  // ---- write z1b + stats partials ----
  #pragma unroll
  for (int rf = 0; rf < 2; ++rf)
    #pragma unroll
    for (int cf = 0; cf < 4; ++cf)
      #pragma unroll
      for (int r4 = 0; r4 < 4; ++r4){
        int row = rowbase + wrow + rf*16 + hi*4 + r4;
        zout[(size_t)row*64 + cf*16 + lr] = acc[rf][cf][r4];
      }
  #pragma unroll
  for (int cf = 0; cf < 4; ++cf){
    float s1 = 0.f, s2 = 0.f;
    #pragma unroll
    for (int rf = 0; rf < 2; ++rf)
      #pragma unroll
      for (int r4 = 0; r4 < 4; ++r4){ float v = acc[rf][cf][r4]; s1 += v; s2 += v*v; }
    s1 += __shfl_xor(s1, 16); s1 += __shfl_xor(s1, 32);
    s2 += __shfl_xor(s2, 16); s2 += __shfl_xor(s2, 32);
    if (hi == 0){ pls[wv][0][cf*16 + lr] = s1; pls[wv][1][cf*16 + lr] = s2; }
  }
  __syncthreads();
  if (tid < 64)
    part1[(size_t)blockIdx.x*64 + tid] = pls[0][0][tid]+pls[1][0][tid]+pls[2][0][tid]+pls[3][0][tid];
  else if (tid < 128){
    int c = tid - 64;
    part2[(size_t)blockIdx.x*64 + c] = pls[0][1][c]+pls[1][1][c]+pls[2][1][c]+pls[3][1][c];
  }
}

// ---------------------------------------------------------------------------
// MFMA rows-GEMM (bf16 inputs, f32 accum). See r5 notes; unchanged.
template<int CIN, int VAR, int OUT>
__global__ __launch_bounds__(256) void gemm_mfma(const float* A, const float* __restrict__ W,
                                                 float* out, int ostride,
                                                 float* __restrict__ part1, float* __restrict__ part2,
                                                 const float* __restrict__ statsIn,
                                                 const int* __restrict__ idx, float oscale,
                                                 const float* __restrict__ statsIn2,
                                                 unsigned* __restrict__ xglob){
  constexpr int ROWB = CIN*2;
  constexpr int CH8  = CIN/8;
  constexpr int SH   = (CIN == 128) ? 4 : 3;
  __shared__ __align__(16) char Al[128*ROWB];
  __shared__ __align__(16) char Bl[64*ROWB];
  __shared__ float pls[4][2][64];
  int tid = threadIdx.x, wv = tid >> 6, lane = tid & 63;
  int rowbase = blockIdx.x*128, chb = blockIdx.y;

  for (int q = 0; q < (128*CH8)/256; ++q){
    int e = q*256 + tid;
    int r = e >> SH, c8 = e & (CH8-1);
    int k0 = c8*8;
    float f[8];
    if (VAR == 2){
      int row = rowbase + r;
      int bn = row / 20; int b = bn >> 12;
      int j = idx[row];
      const float* xi = A + (size_t)bn*128;
      const float* xj = A + ((size_t)(b << 12) + j)*128;
      if (k0 < 64){
        float4 a1 = *(const float4*)&xj[k0];  float4 a2 = *(const float4*)&xj[k0+4];
        float4 b1 = *(const float4*)&xi[k0];  float4 b2 = *(const float4*)&xi[k0+4];
        f[0]=a1.x-b1.x; f[1]=a1.y-b1.y; f[2]=a1.z-b1.z; f[3]=a1.w-b1.w;
        f[4]=a2.x-b2.x; f[5]=a2.y-b2.y; f[6]=a2.z-b2.z; f[7]=a2.w-b2.w;
      } else {
        float4 b1 = *(const float4*)&xi[k0-64]; float4 b2 = *(const float4*)&xi[k0-60];
        f[0]=b1.x; f[1]=b1.y; f[2]=b1.z; f[3]=b1.w;
        f[4]=b2.x; f[5]=b2.y; f[6]=b2.z; f[7]=b2.w;
      }
    } else {
      const float* src = &A[(size_t)(rowbase + r)*CIN + k0];
      float4 v1 = *(const float4*)src; float4 v2 = *(const float4*)(src+4);
      f[0]=v1.x; f[1]=v1.y; f[2]=v1.z; f[3]=v1.w;
      f[4]=v2.x; f[5]=v2.y; f[6]=v2.z; f[7]=v2.w;
      if (VAR == 1){
        float4 m1 = *(const float4*)&statsIn[k0];     float4 m2 = *(const float4*)&statsIn[k0+4];
        float4 r1 = *(const float4*)&statsIn[CIN+k0]; float4 r2 = *(const float4*)&statsIn[CIN+k0+4];
        f[0]=lrelu((f[0]-m1.x)*r1.x); f[1]=lrelu((f[1]-m1.y)*r1.y);
        f[2]=lrelu((f[2]-m1.z)*r1.z); f[3]=lrelu((f[3]-m1.w)*r1.w);
        f[4]=lrelu((f[4]-m2.x)*r2.x); f[5]=lrelu((f[5]-m2.y)*r2.y);
        f[6]=lrelu((f[6]-m2.z)*r2.z); f[7]=lrelu((f[7]-m2.w)*r2.w);
      }
    }
    bf16x8 hv;
    #pragma unroll
    for (int i2 = 0; i2 < 8; ++i2) hv[i2] = (__bf16)f[i2];
    *(bf16x8*)&Al[r*ROWB + ((k0*2) ^ ((r & 7) << 4))] = hv;
  }
  for (int q = 0; q < (64*CH8)/256; ++q){
    int e = q*256 + tid;
    int r = e >> SH, c8 = e & (CH8-1);
    int k0 = c8*8;
    const float* src = &W[(size_t)(chb*64 + r)*CIN + k0];
    float4 v1 = *(const float4*)src; float4 v2 = *(const float4*)(src+4);
    float f[8] = {v1.x,v1.y,v1.z,v1.w,v2.x,v2.y,v2.z,v2.w};
    bf16x8 hv;
    #pragma unroll
    for (int i2 = 0; i2 < 8; ++i2) hv[i2] = (__bf16)f[i2];
    *(bf16x8*)&Bl[r*ROWB + ((k0*2) ^ ((r & 7) << 4))] = hv;
  }
  __syncthreads();

  int lr = lane & 15, hi = lane >> 4;
  f32x4 acc[2][4];
  #pragma unroll
  for (int a_ = 0; a_ < 2; ++a_)
    #pragma unroll
    for (int b_ = 0; b_ < 4; ++b_){ acc[a_][b_][0]=0.f; acc[a_][b_][1]=0.f; acc[a_][b_][2]=0.f; acc[a_][b_][3]=0.f; }
  int wrow = wv*32;
  for (int ks = 0; ks < CIN/32; ++ks){
    int kb = ks*64 + hi*16;
    bf16x8 af[2], bfr[4];
    #pragma unroll
    for (int rf = 0; rf < 2; ++rf){
      int row = wrow + rf*16 + lr;
      af[rf] = *(const bf16x8*)&Al[row*ROWB + (kb ^ ((row & 7) << 4))];
    }
    #pragma unroll
    for (int cf = 0; cf < 4; ++cf){
      int cr = cf*16 + lr;
      bfr[cf] = *(const bf16x8*)&Bl[cr*ROWB + (kb ^ ((cr & 7) << 4))];
    }
    #pragma unroll
    for (int rf = 0; rf < 2; ++rf)
      #pragma unroll
      for (int cf = 0; cf < 4; ++cf)
        acc[rf][cf] = __builtin_amdgcn_mfma_f32_16x16x32_bf16(af[rf], bfr[cf], acc[rf][cf], 0, 0, 0);
  }

  if (OUT == 0){
    #pragma unroll
    for (int rf = 0; rf < 2; ++rf)
      #pragma unroll
      for (int cf = 0; cf < 4; ++cf)
        #pragma unroll
        for (int r4 = 0; r4 < 4; ++r4){
          int row = rowbase + wrow + rf*16 + hi*4 + r4;
          out[(size_t)row*ostride + chb*64 + cf*16 + lr] = acc[rf][cf][r4] * oscale;
        }
  }
  if (OUT != 2 && part1){
    #pragma unroll
    for (int cf = 0; cf < 4; ++cf){
      float s1 = 0.f, s2 = 0.f;
      #pragma unroll
      for (int rf = 0; rf < 2; ++rf)
        #pragma unroll
        for (int r4 = 0; r4 < 4; ++r4){ float v = acc[rf][cf][r4]; s1 += v; s2 += v*v; }
      s1 += __shfl_xor(s1, 16); s1 += __shfl_xor(s1, 32);
      s2 += __shfl_xor(s2, 16); s2 += __shfl_xor(s2, 32);
      if (hi == 0){ pls[wv][0][cf*16 + lr] = s1; pls[wv][1][cf*16 + lr] = s2; }
    }
    __syncthreads();
    int nchTot = gridDim.y * 64;
    if (tid < 64)
      part1[(size_t)blockIdx.x*nchTot + chb*64 + tid] = pls[0][0][tid]+pls[1][0][tid]+pls[2][0][tid]+pls[3][0][tid];
    else if (tid < 128){
      int c = tid - 64;
      part2[(size_t)blockIdx.x*nchTot + chb*64 + c] = pls[0][1][c]+pls[1][1][c]+pls[2][1][c]+pls[3][1][c];
    }
  }
  if (OUT == 2){
    int nchTot = gridDim.y * 64;
    int b = rowbase >> 12;
    #pragma unroll
    for (int cf = 0; cf < 4; ++cf){
      int col = chb*64 + cf*16 + lr;
      float m2 = statsIn2[col], rs2 = statsIn2[nchTot + col];
      float mv = -INFINITY;
      #pragma unroll
      for (int rf = 0; rf < 2; ++rf)
        #pragma unroll
        for (int r4 = 0; r4 < 4; ++r4) mv = fmaxf(mv, lrelu((acc[rf][cf][r4] - m2)*rs2));
      mv = fmaxf(mv, __shfl_xor(mv, 16));
      mv = fmaxf(mv, __shfl_xor(mv, 32));
      if (hi == 0) pls[wv][0][cf*16 + lr] = mv;
    }
    __syncthreads();
    if (tid < 64)
      atomicMax(&xglob[b*nchTot + chb*64 + tid],
                ordf(fmaxf(fmaxf(pls[0][0][tid], pls[1][0][tid]), fmaxf(pls[2][0][tid], pls[3][0][tid]))));
  }
}

// deterministic partial -> (mean, rstd) per channel
__global__ __launch_bounds__(256) void stats_reduce(const float* __restrict__ p1, const float* __restrict__ p2,
                                                    float* __restrict__ statsOut, int nblk, int nch, float count){
  int ch = blockIdx.x, tid = threadIdx.x;
  float s1 = 0.f, s2 = 0.f;
  for (int i = tid; i < nblk; i += 256){ s1 += p1[(size_t)i*nch + ch]; s2 += p2[(size_t)i*nch + ch]; }
  __shared__ float r1[256], r2[256];
  r1[tid] = s1; r2[tid] = s2;
  __syncthreads();
  for (int off = 128; off; off >>= 1){
    if (tid < off){ r1[tid] += r1[tid+off]; r2[tid] += r2[tid+off]; }
    __syncthreads();
  }
  if (tid == 0){
    float m = r1[0] / count;
    float var = r2[0] / count - m*m;
    if (var < 0.f) var = 0.f;
    statsOut[ch] = m;
    statsOut[nch + ch] = rsqrtf(var + 1e-5f);
  }
}

// bn+lrelu then max over k=20 -> xper[:, off..off+63]
__global__ __launch_bounds__(256) void colmax(const float* __restrict__ buf, const float* __restrict__ st,
                                              float* __restrict__ xper, int off){
  int wv = threadIdx.x >> 6, lane = threadIdx.x & 63;
  int bn = blockIdx.x*4 + wv;
  float m = st[lane], rs = st[64 + lane];
  float mx = -INFINITY;
  for (int k = 0; k < 20; ++k){
    float z = buf[((size_t)bn*20 + k)*64 + lane];
    mx = fmaxf(mx, lrelu((z - m)*rs));
  }
  xper[(size_t)bn*128 + off + lane] = mx;
}

__global__ __launch_bounds__(256) void head(const unsigned* __restrict__ xglob,
                                            const float* __restrict__ mu_w, const float* __restrict__ mu_b,
                                            const float* __restrict__ var_w, const float* __restrict__ var_b,
                                            const float* __restrict__ eps_z, float* __restrict__ dout,
                                            float* __restrict__ zv){
  __shared__ __align__(16) float xg[1024];
  int b = blockIdx.x, t = threadIdx.x;
  for (int q = 0; q < 4; ++q) xg[q*256 + t] = iordf(xglob[b*1024 + q*256 + t]);
  __syncthreads();
  if (t < 128){
    float s1 = 0.f, s2 = 0.f;
    for (int c = 0; c < 1024; c += 4){
      float4 xv = *(const float4*)&xg[c];
      float4 wa = *(const float4*)&mu_w[(size_t)t*1024 + c];
      float4 wb = *(const float4*)&var_w[(size_t)t*1024 + c];
      s1 += wa.x*xv.x + wa.y*xv.y + wa.z*xv.z + wa.w*xv.w;
      s2 += wb.x*xv.x + wb.y*xv.y + wb.z*xv.z + wb.w*xv.w;
    }
    float mu = s1 + mu_b[t];
    float lv = s2 + var_b[t];
    dout[458816 + b*128 + t] = mu;
    dout[459328 + b*128 + t] = lv;
    zv[b*128 + t] = eps_z[b*128 + t] * expf(0.5f*lv) + mu;
  }
}

// cuboid MLP + Para_pred per (b,m)
__global__ __launch_bounds__(256) void cuboid(const float* __restrict__ zv, const float* __restrict__ enc_w,
                                              const float* __restrict__ w1, const float* __restrict__ w2,
                                              const float* __restrict__ rot_w, const float* __restrict__ rot_b,
                                              const float* __restrict__ trans_w, const float* __restrict__ trans_b,
                                              const float* __restrict__ ext_w1, const float* __restrict__ ext_b1,
                                              const float* __restrict__ ext_w2, const float* __restrict__ ext_b2,
                                              const float* __restrict__ k_w, float* __restrict__ Km,
                                              float* __restrict__ rot, float* __restrict__ trs,
                                              float* __restrict__ dout){
  int bm = blockIdx.x; int b = bm >> 4, m = bm & 15; int t = threadIdx.x;
  __shared__ __align__(16) float xc[192];
  __shared__ __align__(16) float h1[256];
  __shared__ __align__(16) float xcu[128];
  __shared__ float qv[4]; __shared__ float ev[30];
  if (t < 192) xc[t] = (t < 128) ? zv[b*128 + t] : lrelu(enc_w[(t-128)*16 + m]);
  __syncthreads();
  {
    float s = 0.f; const float* wr = w1 + (size_t)t*192;
    for (int c = 0; c < 192; c += 4){
      float4 w4 = *(const float4*)&wr[c]; float4 x4 = *(const float4*)&xc[c];
      s += w4.x*x4.x + w4.y*x4.y + w4.z*x4.z + w4.w*x4.w;
    }
    h1[t] = lrelu(s);
  }
  __syncthreads();
  if (t < 128){
    float s = 0.f; const float* wr = w2 + (size_t)t*256;
    for (int c = 0; c < 256; c += 4){
      float4 w4 = *(const float4*)&wr[c]; float4 x4 = *(const float4*)&h1[c];
      s += w4.x*x4.x + w4.y*x4.y + w4.z*x4.z + w4.w*x4.w;
    }
    xcu[t] = lrelu(s);
  }
  __syncthreads();
  if (t < 64){
    float s = 0.f;
    for (int c = 0; c < 128; ++c) s += xcu[c]*k_w[(size_t)t*128 + c];
    Km[(size_t)(b*16 + m)*64 + t] = s;
  } else if (t < 68){
    int o = t - 64; float s = rot_b[o];
    for (int c = 0; c < 128; ++c) s += xcu[c]*rot_w[(size_t)o*128 + c];
    qv[o] = s;
  } else if (t < 71){
    int o = t - 68; float s = trans_b[o];
    for (int c = 0; c < 128; ++c) s += xcu[c]*trans_w[(size_t)o*128 + c];
    trs[(size_t)(b*16 + m)*3 + o] = tanhf(s);
  } else if (t < 101){
    int o = t - 71; float s = ext_b1[o];
    for (int c = 0; c < 128; ++c) s += xcu[c]*ext_w1[(size_t)o*128 + c];
    ev[o] = lrelu(s);
  }
  __syncthreads();
  if (t == 0){
    float w = qv[0], x = qv[1], y = qv[2], z = qv[3];
    float nrm = sqrtf(w*w + x*x + y*y + z*z);
    float inv = 1.f / fmaxf(nrm, 1e-12f);
    w *= inv; x *= inv; y *= inv; z *= inv;
    float xx2 = x*x, yy = y*y, zz = z*z;
    float* r = rot + (size_t)(b*16 + m)*9;
    r[0] = 1.f - 2.f*(yy + zz); r[1] = 2.f*(x*y - w*z); r[2] = 2.f*(x*z + w*y);
    r[3] = 2.f*(x*y + w*z); r[4] = 1.f - 2.f*(xx2 + zz); r[5] = 2.f*(y*z - w*x);
    r[6] = 2.f*(x*z - w*y); r[7] = 2.f*(y*z + w*x); r[8] = 1.f - 2.f*(xx2 + yy);
  }
  if (t == 1){
    float s = ext_b2[0];
    for (int o = 0; o < 30; ++o) s += ev[o]*ext_w2[o];
    dout[458752 + b*16 + m] = s;
  }
}

// attention epilogue
__global__ __launch_bounds__(256) void attn(const float* __restrict__ Qbuf, const float* __restrict__ Km,
                                            const float* __restrict__ rot, const float* __restrict__ trs,
                                            float* __restrict__ dout){
  __shared__ float kml[16*64];
  __shared__ float rl[144], tl[48];
  __shared__ float Ql[4][64];
  __shared__ float al[4][16];
  int tid = threadIdx.x, wv = tid >> 6, lane = tid & 63;
  int bn0 = blockIdx.x*4; int b = bn0 >> 12;
  for (int e = tid; e < 1024; e += 256){
    int m = e >> 6, d = e & 63;
    kml[m*64 + (d ^ ((m & 15) << 2))] = Km[(size_t)b*1024 + e];
  }
  if (tid < 144) rl[tid] = rot[(size_t)b*144 + tid];
  if (tid < 48)  tl[tid] = trs[(size_t)b*48 + tid];
  __syncthreads();
  int bn = bn0 + wv;
  Ql[wv][lane] = Qbuf[(size_t)bn*64 + lane];
  if (lane < 16){
    float sc = 0.f;
    for (int d = 0; d < 64; ++d) sc += Ql[wv][d] * kml[lane*64 + (d ^ ((lane & 15) << 2))];
    float mx = sc;
    #pragma unroll
    for (int off = 8; off; off >>= 1) mx = fmaxf(mx, __shfl_xor(mx, off));
    float e = expf(sc - mx);
    float sm = e;
    #pragma unroll
    for (int off = 8; off; off >>= 1) sm += __shfl_xor(sm, off);
    float a = e / sm;
    dout[(size_t)bn*16 + lane] = a;
    al[wv][lane] = a;
  }
  if (lane < 9){
    float s = 0.f;
    for (int m = 0; m < 16; ++m) s += al[wv][m] * rl[m*9 + lane];
    dout[262144 + (size_t)bn*9 + lane] = s;
  }
  if (lane >= 16 && lane < 19){
    int d = lane - 16;
    float s = 0.f;
    for (int m = 0; m < 16; ++m) s += al[wv][m] * tl[m*3 + d];
    dout[409600 + (size_t)bn*3 + d] = s;
  }
}

// ---------------------------------------------------------------------------
extern "C" void kernel_launch(void* const* d_in, const int* in_sizes, int n_in,
                              void* d_out, int out_size, void* d_ws, size_t ws_size,
                              hipStream_t stream){
  (void)in_sizes; (void)n_in; (void)out_size; (void)ws_size;
  const float* xyz     = (const float*)d_in[0];
  const float* eps_z   = (const float*)d_in[2];
  const float* w1a     = (const float*)d_in[3];
  const float* w1b     = (const float*)d_in[4];
  const float* w2a     = (const float*)d_in[5];
  const float* w2b     = (const float*)d_in[6];
  const float* w3      = (const float*)d_in[7];
  const float* mu_w    = (const float*)d_in[8];
  const float* mu_b    = (const float*)d_in[9];
  const float* var_w   = (const float*)d_in[10];
  const float* var_b   = (const float*)d_in[11];
  const float* enc_w   = (const float*)d_in[12];
  const float* cw1     = (const float*)d_in[13];
  const float* cw2     = (const float*)d_in[14];
  const float* q_w     = (const float*)d_in[15];
  const float* k_w     = (const float*)d_in[16];
  const float* rot_w   = (const float*)d_in[19];
  const float* rot_b   = (const float*)d_in[20];
  const float* trans_w = (const float*)d_in[21];
  const float* trans_b = (const float*)d_in[22];
  const float* ext_w1  = (const float*)d_in[23];
  const float* ext_b1  = (const float*)d_in[24];
  const float* ext_w2  = (const float*)d_in[25];
  const float* ext_b2  = (const float*)d_in[26];
  float* dout = (float*)d_out;

  char* wsb = (char*)d_ws;
  size_t off = 0;
  float* buf   = (float*)(wsb + off); off += 83886080;      // z1b/z2a/z2b [B,N,K,64] f32; reused as key matrix (64MB)
  int*   idx0  = (int*)(wsb + off);   off += 1310720;
  int*   idx1  = (int*)(wsb + off);   off += 1310720;
  float* xper  = (float*)(wsb + off); off += 8388608;       // [B,N,128] = [x1|x2]
  float* xx    = (float*)(wsb + off); off += 65536;
  float* part1 = (float*)(wsb + off); off += 4194304;       // reused as Qbuf
  float* part2 = (float*)(wsb + off); off += 4194304;
  float* st1a  = (float*)(wsb + off); off += 512;
  float* st1b  = (float*)(wsb + off); off += 512;
  float* st2a  = (float*)(wsb + off); off += 512;
  float* st2b  = (float*)(wsb + off); off += 512;
  float* st3   = (float*)(wsb + off); off += 8192;
  unsigned* xglob = (unsigned*)(wsb + off); off += 16384;
  float* zv    = (float*)(wsb + off); off += 2048;
  float* Kmb   = (float*)(wsb + off); off += 16384;
  float* rotb  = (float*)(wsb + off); off += 2304;
  float* trsb  = (float*)(wsb + off); off += 768;
  float4* pts  = (float4*)(wsb + off); off += 262144;       // [B*N] (x,y,z,|x|^2)

  // --- Feature_extract, block 1 (w1b via split-bf16 MFMA) ---
  soa_xyz<<<64, 256, 0, stream>>>(xyz, pts);
  knn_xyz<<<4096, 256, 0, stream>>>(pts, idx0);
  stats1a<<<1024, 256, 0, stream>>>(pts, idx0, w1a, part1, part2);
  stats_reduce<<<64, 256, 0, stream>>>(part1, part2, st1a, 1024, 64, 327680.f);
  fused1m<<<2560, 256, 0, stream>>>(pts, idx0, w1a, w1b, st1a, part1, part2, buf);
  stats_reduce<<<64, 256, 0, stream>>>(part1, part2, st1b, 2560, 64, 327680.f);
  colmax<<<4096, 256, 0, stream>>>(buf, st1b, xper, 0);     // x1

  // --- knn on x1 (split-bf16 MFMA Gram -> packed keys -> topk), per batch ---
  row_norms<<<4096, 256, 0, stream>>>(xper, xx);
  for (int b = 0; b < 4; ++b){
    gram_mfma<<<dim3(32,32), 256, 0, stream>>>(xper + (size_t)b*NN*128, xx + (size_t)b*NN, (unsigned*)buf);
    topk_rows<<<1024, 256, 0, stream>>>((unsigned*)buf, idx1 + (size_t)b*NN*KK);
  }

  // --- Feature_extract, block 2 (bf16 MFMA) ---
  gemm_mfma<128,2,0><<<dim3(2560,1), 256, 0, stream>>>(xper, w2a, buf, 64, part1, part2, nullptr, idx1, 1.f, nullptr, nullptr);
  stats_reduce<<<64, 256, 0, stream>>>(part1, part2, st2a, 2560, 64, 327680.f);
  gemm_mfma<64,1,0><<<dim3(2560,1), 256, 0, stream>>>(buf, w2b, buf, 64, part1, part2, st2a, nullptr, 1.f, nullptr, nullptr);
  stats_reduce<<<64, 256, 0, stream>>>(part1, part2, st2b, 2560, 64, 327680.f);
  colmax<<<4096, 256, 0, stream>>>(buf, st2b, xper, 64);    // x2

  // --- global embedding (bf16 MFMA stats pass + fused BN/lrelu/max pass, no z3) ---
  gemm_mfma<128,0,1><<<dim3(128,16), 256, 0, stream>>>(xper, w3, nullptr, 1024, part1, part2, nullptr, nullptr, 1.f, nullptr, nullptr);
  stats_reduce<<<1024, 256, 0, stream>>>(part1, part2, st3, 128, 1024, 16384.f);
  hipMemsetAsync(xglob, 0, 4096*sizeof(unsigned), stream);
  gemm_mfma<128,0,2><<<dim3(128,16), 256, 0, stream>>>(xper, w3, nullptr, 1024, nullptr, nullptr, nullptr, nullptr, 1.f, st3, xglob);

  // --- heads ---
  head<<<4, 256, 0, stream>>>(xglob, mu_w, mu_b, var_w, var_b, eps_z, dout, zv);
  cuboid<<<64, 256, 0, stream>>>(zv, enc_w, cw1, cw2, rot_w, rot_b, trans_w, trans_b,
                                 ext_w1, ext_b1, ext_w2, ext_b2, k_w, Kmb, rotb, trsb, dout);
  gemm_mfma<128,0,0><<<dim3(128,1), 256, 0, stream>>>(xper, q_w, part1, 64, nullptr, nullptr, nullptr, nullptr, 0.125f, nullptr, nullptr);
  attn<<<4096, 256, 0, stream>>>(part1, Kmb, rotb, trsb, dout);
}

// Round 11
// 439.054 us; speedup vs baseline: 2.1374x; 1.1036x over previous
//
#include <hip/hip_runtime.h>
#include <math.h>

#define BB 4
#define NN 4096
#define KK 20

typedef __bf16 bf16x8 __attribute__((ext_vector_type(8)));
typedef float  f32x4  __attribute__((ext_vector_type(4)));

__device__ __forceinline__ float lrelu(float x){ return x > 0.f ? x : 0.2f*x; }

// order-preserving f32 -> u32 (monotone), and inverse
__device__ __forceinline__ unsigned ordf(float v){
  unsigned u = __float_as_uint(v);
  return u ^ (((unsigned)((int)u >> 31)) | 0x80000000u);
}
__device__ __forceinline__ float iordf(unsigned o){
  unsigned u = (o & 0x80000000u) ? (o ^ 0x80000000u) : ~o;
  return __uint_as_float(u);
}

// ---------------------------------------------------------------------------
// Exact top-20 of 4096 keys per wave, PACKED-KEY variant (see r8 notes).
template<typename GetK>
__device__ __forceinline__ int topk20_v4(int lane, GetK getk){
  unsigned b0 = 0u, b1 = 0u, b2 = 0u;
  for (int s = 0; s < 64; ++s){
    unsigned v = getk(s, lane);
    unsigned nb0 = b0 > v ? b0 : v;
    unsigned m1  = b1 > v ? b1 : v;
    unsigned nb1 = m1 < b0 ? m1 : b0;     // min(b0, max(b1,v))
    unsigned m2  = b2 > v ? b2 : v;
    unsigned nb2 = m2 < b1 ? m2 : b1;     // min(b1, max(b2,v))
    b0 = nb0; b1 = nb1; b2 = nb2;
  }
  unsigned lastk = 0xFFFFFFFFu;
  int myj = 0;
  for (int r = 0; r < 20; ++r){
    unsigned m = b0;
    #pragma unroll
    for (int off = 32; off; off >>= 1){ unsigned o = __shfl_xor(m, off); if (o > m) m = o; }
    unsigned long long msk = __ballot(b0 == m);
    int wl = __ffsll(msk) - 1;
    int ss = 63 - (int)(m & 63u);
    if (lane == r) myj = (ss << 6) | wl;
    bool empty = false;
    if (lane == wl){
      lastk = m;
      b0 = b1; b1 = b2; b2 = 0u;
      empty = (b0 == 0u);
    }
    if (__any(empty)){
      unsigned lk = __shfl(lastk, wl);
      unsigned cv = getk(lane, wl);
      if (cv >= lk) cv = 0u;
      unsigned nv0 = 0u, nv1 = 0u, nv2 = 0u;
      #pragma unroll
      for (int t = 0; t < 3; ++t){
        unsigned mm = cv;
        #pragma unroll
        for (int off = 32; off; off >>= 1){ unsigned o = __shfl_xor(mm, off); if (o > mm) mm = o; }
        unsigned long long mk = __ballot(cv == mm && mm != 0u);
        if (mk){
          int src = __ffsll(mk) - 1;
          if (lane == src) cv = 0u;
        }
        if (t == 0) nv0 = mm; else if (t == 1) nv1 = mm; else nv2 = mm;
      }
      if (lane == wl){ b0 = nv0; b1 = nv1; b2 = nv2; }
    }
  }
  return myj;
}

// ---------------------------------------------------------------------------
// SoA + norm precompute: pts[g] = (x, y, z, x^2+y^2+z^2), g over B*N points.
__global__ __launch_bounds__(256) void soa_xyz(const float* __restrict__ xyz, float4* __restrict__ pts){
  int g = blockIdx.x*256 + threadIdx.x;
  const float* p = xyz + (size_t)g*3;
  float a0 = p[0], a1 = p[1], a2 = p[2];
  float xx = fmaf(a0, a0, fmaf(a1, a1, a2*a2));
  pts[g] = make_float4(a0, a1, a2, xx);
}

// kNN on xyz. One wave per row.
__global__ __launch_bounds__(256) void knn_xyz(const float4* __restrict__ pts, int* __restrict__ idx_out){
  int tid = threadIdx.x, wv = tid >> 6, lane = tid & 63;
  int row = blockIdx.x * 4 + wv;
  int b = row >> 12, i = row & 4095;
  const float4* pb = pts + ((size_t)b << 12);
  float4 pi = pb[i];
  float xi0 = pi.x, xi1 = pi.y, xi2 = pi.z, xxi = pi.w;
  auto getk = [=](int s, int L)->unsigned{
    float4 p = pb[(s << 6) + L];
    float inner = fmaf(xi0, p.x, fmaf(xi1, p.y, xi2*p.z));
    float d = fmaf(2.f, inner, -xxi) - p.w;
    return (ordf(d) & 0xFFFFFFC0u) | (unsigned)(63 - s);
  };
  int myj = topk20_v4(lane, getk);
  if (lane < 20) idx_out[(size_t)row*20 + lane] = myj;
}

// top-20 per row from pre-packed key matrix [4096][4096]
__global__ __launch_bounds__(256) void topk_rows(const unsigned* __restrict__ dg, int* __restrict__ idx_out){
  int tid = threadIdx.x, wv = tid >> 6, lane = tid & 63;
  int i = blockIdx.x * 4 + wv;
  const unsigned* drow = dg + (size_t)i * 4096;
  auto getk = [=](int s, int L)->unsigned{ return drow[(s << 6) + L]; };
  int myj = topk20_v4(lane, getk);
  if (lane < 20) idx_out[(size_t)i*20 + lane] = myj;
}

// ---------------------------------------------------------------------------
// Gram -> packed top-k keys via SPLIT-BF16 MFMA (r9). See r9 notes.
__global__ __launch_bounds__(256) void gram_mfma(const float* __restrict__ x1, const float* __restrict__ xx,
                                                 unsigned* __restrict__ dg){
  __shared__ __align__(16) char Ahi[128*128];
  __shared__ __align__(16) char Alo[128*128];
  __shared__ __align__(16) char Bhi[128*128];
  __shared__ __align__(16) char Blo[128*128];
  int tid = threadIdx.x, wv = tid >> 6, lane = tid & 63;
  int it = blockIdx.y, jt = blockIdx.x;
  for (int q = 0; q < 4; ++q){
    int e = q*256 + tid;
    int r = e >> 3, c8 = e & 7;
    int k0 = c8*8;
    int off = r*128 + ((k0*2) ^ ((r & 7) << 4));
    {
      const float* src = &x1[(size_t)(it*128 + r)*128 + k0];
      float4 v1 = *(const float4*)src, v2 = *(const float4*)(src+4);
      float f[8] = {v1.x,v1.y,v1.z,v1.w,v2.x,v2.y,v2.z,v2.w};
      bf16x8 hv, lv;
      #pragma unroll
      for (int i2 = 0; i2 < 8; ++i2){ hv[i2] = (__bf16)f[i2]; lv[i2] = (__bf16)(f[i2] - (float)hv[i2]); }
      *(bf16x8*)&Ahi[off] = hv; *(bf16x8*)&Alo[off] = lv;
    }
    {
      const float* src = &x1[(size_t)(jt*128 + r)*128 + k0];
      float4 v1 = *(const float4*)src, v2 = *(const float4*)(src+4);
      float f[8] = {v1.x,v1.y,v1.z,v1.w,v2.x,v2.y,v2.z,v2.w};
      bf16x8 hv, lv;
      #pragma unroll
      for (int i2 = 0; i2 < 8; ++i2){ hv[i2] = (__bf16)f[i2]; lv[i2] = (__bf16)(f[i2] - (float)hv[i2]); }
      *(bf16x8*)&Bhi[off] = hv; *(bf16x8*)&Blo[off] = lv;
    }
  }
  __syncthreads();
  int lr = lane & 15, hi16 = lane >> 4;
  f32x4 acc[2][8];
  #pragma unroll
  for (int a_ = 0; a_ < 2; ++a_)
    #pragma unroll
    for (int b_ = 0; b_ < 8; ++b_){ acc[a_][b_][0]=0.f; acc[a_][b_][1]=0.f; acc[a_][b_][2]=0.f; acc[a_][b_][3]=0.f; }
  int wrow = wv*32;
  for (int ks = 0; ks < 2; ++ks){
    int kb = ks*64 + hi16*16;
    bf16x8 ah[2], al[2];
    #pragma unroll
    for (int rf = 0; rf < 2; ++rf){
      int row = wrow + rf*16 + lr;
      int off = row*128 + (kb ^ ((row & 7) << 4));
      ah[rf] = *(const bf16x8*)&Ahi[off];
      al[rf] = *(const bf16x8*)&Alo[off];
    }
    #pragma unroll
    for (int cf = 0; cf < 8; ++cf){
      int cr = cf*16 + lr;
      int off = cr*128 + (kb ^ ((cr & 7) << 4));
      bf16x8 bh = *(const bf16x8*)&Bhi[off];
      bf16x8 bl = *(const bf16x8*)&Blo[off];
      #pragma unroll
      for (int rf = 0; rf < 2; ++rf){
        acc[rf][cf] = __builtin_amdgcn_mfma_f32_16x16x32_bf16(ah[rf], bh, acc[rf][cf], 0, 0, 0);
        acc[rf][cf] = __builtin_amdgcn_mfma_f32_16x16x32_bf16(ah[rf], bl, acc[rf][cf], 0, 0, 0);
        acc[rf][cf] = __builtin_amdgcn_mfma_f32_16x16x32_bf16(al[rf], bh, acc[rf][cf], 0, 0, 0);
      }
    }
  }
  int rowg = it*128 + wrow;
  float xxi[2][4];
  #pragma unroll
  for (int rf = 0; rf < 2; ++rf)
    #pragma unroll
    for (int r4 = 0; r4 < 4; ++r4) xxi[rf][r4] = xx[rowg + rf*16 + hi16*4 + r4];
  #pragma unroll
  for (int cf = 0; cf < 8; ++cf){
    int colg = jt*128 + cf*16 + lr;
    float xxj = xx[colg];
    unsigned tag = 63u - (unsigned)(jt*2 + (cf >> 2));
    #pragma unroll
    for (int rf = 0; rf < 2; ++rf)
      #pragma unroll
      for (int r4 = 0; r4 < 4; ++r4){
        float d = -xxi[rf][r4] + 2.f*acc[rf][cf][r4] - xxj;
        dg[(size_t)(rowg + rf*16 + hi16*4 + r4)*4096 + colg] = (ordf(d) & 0xFFFFFFC0u) | tag;
      }
  }
}

__global__ __launch_bounds__(256) void row_norms(const float* __restrict__ xper, float* __restrict__ xx){
  int wv = threadIdx.x >> 6, lane = threadIdx.x & 63;
  int row = blockIdx.x * 4 + wv;
  float v = xper[(size_t)row*128 + lane];
  float s = v*v;
  #pragma unroll
  for (int off = 32; off; off >>= 1) s += __shfl_xor(s, off);
  if (lane == 0) xx[row] = s;
}

// ---------------------------------------------------------------------------
// stats of z1a = graph_feature(xyz) @ w1a^T, no materialization.
__global__ __launch_bounds__(256) void stats1a(const float4* __restrict__ pts, const int* __restrict__ idx,
                                               const float* __restrict__ w1a,
                                               float* __restrict__ part1, float* __restrict__ part2){
  int tid = threadIdx.x, wv = tid >> 6, lane = tid & 63;
  float w[6];
  #pragma unroll
  for (int c = 0; c < 6; ++c) w[c] = w1a[lane*6 + c];
  float s1 = 0.f, s2 = 0.f;
  int p0 = blockIdx.x*16 + wv*4;
  for (int pp = 0; pp < 4; ++pp){
    int bn = p0 + pp; int b = bn >> 12, i = bn & 4095;
    const float4* pb = pts + ((size_t)b << 12);
    float4 pi = pb[i];
    float i0 = pi.x, i1 = pi.y, i2 = pi.z;
    for (int k = 0; k < 20; ++k){
      int j = idx[bn*20 + k];
      float4 pj = pb[j];
      float z = w[0]*(pj.x-i0) + w[1]*(pj.y-i1) + w[2]*(pj.z-i2) + w[3]*i0 + w[4]*i1 + w[5]*i2;
      s1 += z; s2 += z*z;
    }
  }
  __shared__ float red[2][4][64];
  red[0][wv][lane] = s1; red[1][wv][lane] = s2;
  __syncthreads();
  if (tid < 64)
    part1[(size_t)blockIdx.x*64 + tid] = red[0][0][tid]+red[0][1][tid]+red[0][2][tid]+red[0][3][tid];
  else if (tid < 128){
    int c = tid - 64;
    part2[(size_t)blockIdx.x*64 + c] = red[1][0][c]+red[1][1][c]+red[1][2][c]+red[1][3][c];
  }
}

// ---------------------------------------------------------------------------
// Fused block-1 via SPLIT-BF16 MFMA (r10). See r10 notes; unchanged.
__global__ __launch_bounds__(256) void fused1m(const float4* __restrict__ pts, const int* __restrict__ idx,
                                               const float* __restrict__ w1a, const float* __restrict__ w1b,
                                               const float* __restrict__ st_a,
                                               float* __restrict__ part1, float* __restrict__ part2,
                                               float* __restrict__ zout){
  __shared__ __align__(16) char Ahi[128*128];
  __shared__ __align__(16) char Alo[128*128];
  __shared__ __align__(16) char Bhi[64*128];
  __shared__ __align__(16) char Blo[64*128];
  __shared__ float w1al[64*6];
  __shared__ float pls[4][2][64];
  int tid = threadIdx.x, wv = tid >> 6, lane = tid & 63;
  int rowbase = blockIdx.x*128;
  if (tid < 192){ ((float2*)w1al)[tid] = ((const float2*)w1a)[tid]; }
  __syncthreads();
  for (int q = 0; q < 4; ++q){
    int e = q*256 + tid;
    int r = e >> 3, c8 = e & 7;
    int row = rowbase + r;
    int bn = row / 20; int b = bn >> 12;
    int j = idx[row];
    const float4* pb = pts + ((size_t)b << 12);
    float4 pi = pb[(size_t)(bn & 4095)];
    float4 pj = pb[j];
    float d0 = pj.x - pi.x, d1 = pj.y - pi.y, d2 = pj.z - pi.z;
    bf16x8 hv, lv;
    #pragma unroll
    for (int u = 0; u < 8; ++u){
      int c = c8*8 + u;
      const float* w = &w1al[c*6];
      float z = w[0]*d0 + w[1]*d1 + w[2]*d2 + w[3]*pi.x + w[4]*pi.y + w[5]*pi.z;
      float h = lrelu((z - st_a[c]) * st_a[64 + c]);
      hv[u] = (__bf16)h; lv[u] = (__bf16)(h - (float)hv[u]);
    }
    int off = r*128 + ((c8*16) ^ ((r & 7) << 4));
    *(bf16x8*)&Ahi[off] = hv; *(bf16x8*)&Alo[off] = lv;
  }
  for (int q = 0; q < 2; ++q){
    int e = q*256 + tid;
    int r = e >> 3, c8 = e & 7;
    int k0 = c8*8;
    const float* src = &w1b[(size_t)r*64 + k0];
    float4 v1 = *(const float4*)src, v2 = *(const float4*)(src+4);
    float f[8] = {v1.x,v1.y,v1.z,v1.w,v2.x,v2.y,v2.z,v2.w};
    bf16x8 hv, lv;
    #pragma unroll
    for (int i2 = 0; i2 < 8; ++i2){ hv[i2] = (__bf16)f[i2]; lv[i2] = (__bf16)(f[i2] - (float)hv[i2]); }
    int off = r*128 + ((k0*2) ^ ((r & 7) << 4));
    *(bf16x8*)&Bhi[off] = hv; *(bf16x8*)&Blo[off] = lv;
  }
  __syncthreads();
  int lr = lane & 15, hi = lane >> 4;
  f32x4 acc[2][4];
  #pragma unroll
  for (int a_ = 0; a_ < 2; ++a_)
    #pragma unroll
    for (int b_ = 0; b_ < 4; ++b_){ acc[a_][b_][0]=0.f; acc[a_][b_][1]=0.f; acc[a_][b_][2]=0.f; acc[a_][b_][3]=0.f; }
  int wrow = wv*32;
  for (int ks = 0; ks < 2; ++ks){
    int kb = ks*64 + hi*16;
    bf16x8 ah[2], al[2];
    #pragma unroll
    for (int rf = 0; rf < 2; ++rf){
      int row = wrow + rf*16 + lr;
      int off = row*128 + (kb ^ ((row & 7) << 4));
      ah[rf] = *(const bf16x8*)&Ahi[off];
      al[rf] = *(const bf16x8*)&Alo[off];
    }
    #pragma unroll
    for (int cf = 0; cf < 4; ++cf){
      int cr = cf*16 + lr;
      int off = cr*128 + (kb ^ ((cr & 7) << 4));
      bf16x8 bh = *(const bf16x8*)&Bhi[off];
      bf16x8 bl = *(const bf16x8*)&Blo[off];
      #pragma unroll
      for (int rf = 0; rf < 2; ++rf){
        acc[rf][cf] = __builtin_amdgcn_mfma_f32_16x16x32_bf16(ah[rf], bh, acc[rf][cf], 0, 0, 0);
        acc[rf][cf] = __builtin_amdgcn_mfma_f32_16x16x32_bf16(ah[rf], bl, acc[rf][cf], 0, 0, 0);
        acc[rf][cf] = __builtin_amdgcn_mfma_f32_16x16x32_bf16(al[rf], bh, acc[rf][cf], 0, 0, 0);
      }
    }
  }
  #pragma unroll
  for (int rf = 0; rf < 2; ++rf)
    #pragma unroll
    for (int cf = 0; cf < 4; ++cf)
      #pragma unroll
      for (int r4 = 0; r4 < 4; ++r4){
        int row = rowbase + wrow + rf*16 + hi*4 + r4;
        zout[(size_t)row*64 + cf*16 + lr] = acc[rf][cf][r4];
      }
  #pragma unroll
  for (int cf = 0; cf < 4; ++cf){
    float s1 = 0.f, s2 = 0.f;
    #pragma unroll
    for (int rf = 0; rf < 2; ++rf)
      #pragma unroll
      for (int r4 = 0; r4 < 4; ++r4){ float v = acc[rf][cf][r4]; s1 += v; s2 += v*v; }
    s1 += __shfl_xor(s1, 16); s1 += __shfl_xor(s1, 32);
    s2 += __shfl_xor(s2, 16); s2 += __shfl_xor(s2, 32);
    if (hi == 0){ pls[wv][0][cf*16 + lr] = s1; pls[wv][1][cf*16 + lr] = s2; }
  }
  __syncthreads();
  if (tid < 64)
    part1[(size_t)blockIdx.x*64 + tid] = pls[0][0][tid]+pls[1][0][tid]+pls[2][0][tid]+pls[3][0][tid];
  else if (tid < 128){
    int c = tid - 64;
    part2[(size_t)blockIdx.x*64 + c] = pls[0][1][c]+pls[1][1][c]+pls[2][1][c]+pls[3][1][c];
  }
}

// ---------------------------------------------------------------------------
// MFMA rows-GEMM (bf16 inputs, f32 accum). See r5 notes; unchanged.
template<int CIN, int VAR, int OUT>
__global__ __launch_bounds__(256) void gemm_mfma(const float* A, const float* __restrict__ W,
                                                 float* out, int ostride,
                                                 float* __restrict__ part1, float* __restrict__ part2,
                                                 const float* __restrict__ statsIn,
                                                 const int* __restrict__ idx, float oscale,
                                                 const float* __restrict__ statsIn2,
                                                 unsigned* __restrict__ xglob){
  constexpr int ROWB = CIN*2;
  constexpr int CH8  = CIN/8;
  constexpr int SH   = (CIN == 128) ? 4 : 3;
  __shared__ __align__(16) char Al[128*ROWB];
  __shared__ __align__(16) char Bl[64*ROWB];
  __shared__ float pls[4][2][64];
  int tid = threadIdx.x, wv = tid >> 6, lane = tid & 63;
  int rowbase = blockIdx.x*128, chb = blockIdx.y;

  for (int q = 0; q < (128*CH8)/256; ++q){
    int e = q*256 + tid;
    int r = e >> SH, c8 = e & (CH8-1);
    int k0 = c8*8;
    float f[8];
    if (VAR == 2){
      int row = rowbase + r;
      int bn = row / 20; int b = bn >> 12;
      int j = idx[row];
      const float* xi = A + (size_t)bn*128;
      const float* xj = A + ((size_t)(b << 12) + j)*128;
      if (k0 < 64){
        float4 a1 = *(const float4*)&xj[k0];  float4 a2 = *(const float4*)&xj[k0+4];
        float4 b1 = *(const float4*)&xi[k0];  float4 b2 = *(const float4*)&xi[k0+4];
        f[0]=a1.x-b1.x; f[1]=a1.y-b1.y; f[2]=a1.z-b1.z; f[3]=a1.w-b1.w;
        f[4]=a2.x-b2.x; f[5]=a2.y-b2.y; f[6]=a2.z-b2.z; f[7]=a2.w-b2.w;
      } else {
        float4 b1 = *(const float4*)&xi[k0-64]; float4 b2 = *(const float4*)&xi[k0-60];
        f[0]=b1.x; f[1]=b1.y; f[2]=b1.z; f[3]=b1.w;
        f[4]=b2.x; f[5]=b2.y; f[6]=b2.z; f[7]=b2.w;
      }
    } else {
      const float* src = &A[(size_t)(rowbase + r)*CIN + k0];
      float4 v1 = *(const float4*)src; float4 v2 = *(const float4*)(src+4);
      f[0]=v1.x; f[1]=v1.y; f[2]=v1.z; f[3]=v1.w;
      f[4]=v2.x; f[5]=v2.y; f[6]=v2.z; f[7]=v2.w;
      if (VAR == 1){
        float4 m1 = *(const float4*)&statsIn[k0];     float4 m2 = *(const float4*)&statsIn[k0+4];
        float4 r1 = *(const float4*)&statsIn[CIN+k0]; float4 r2 = *(const float4*)&statsIn[CIN+k0+4];
        f[0]=lrelu((f[0]-m1.x)*r1.x); f[1]=lrelu((f[1]-m1.y)*r1.y);
        f[2]=lrelu((f[2]-m1.z)*r1.z); f[3]=lrelu((f[3]-m1.w)*r1.w);
        f[4]=lrelu((f[4]-m2.x)*r2.x); f[5]=lrelu((f[5]-m2.y)*r2.y);
        f[6]=lrelu((f[6]-m2.z)*r2.z); f[7]=lrelu((f[7]-m2.w)*r2.w);
      }
    }
    bf16x8 hv;
    #pragma unroll
    for (int i2 = 0; i2 < 8; ++i2) hv[i2] = (__bf16)f[i2];
    *(bf16x8*)&Al[r*ROWB + ((k0*2) ^ ((r & 7) << 4))] = hv;
  }
  for (int q = 0; q < (64*CH8)/256; ++q){
    int e = q*256 + tid;
    int r = e >> SH, c8 = e & (CH8-1);
    int k0 = c8*8;
    const float* src = &W[(size_t)(chb*64 + r)*CIN + k0];
    float4 v1 = *(const float4*)src; float4 v2 = *(const float4*)(src+4);
    float f[8] = {v1.x,v1.y,v1.z,v1.w,v2.x,v2.y,v2.z,v2.w};
    bf16x8 hv;
    #pragma unroll
    for (int i2 = 0; i2 < 8; ++i2) hv[i2] = (__bf16)f[i2];
    *(bf16x8*)&Bl[r*ROWB + ((k0*2) ^ ((r & 7) << 4))] = hv;
  }
  __syncthreads();

  int lr = lane & 15, hi = lane >> 4;
  f32x4 acc[2][4];
  #pragma unroll
  for (int a_ = 0; a_ < 2; ++a_)
    #pragma unroll
    for (int b_ = 0; b_ < 4; ++b_){ acc[a_][b_][0]=0.f; acc[a_][b_][1]=0.f; acc[a_][b_][2]=0.f; acc[a_][b_][3]=0.f; }
  int wrow = wv*32;
  for (int ks = 0; ks < CIN/32; ++ks){
    int kb = ks*64 + hi*16;
    bf16x8 af[2], bfr[4];
    #pragma unroll
    for (int rf = 0; rf < 2; ++rf){
      int row = wrow + rf*16 + lr;
      af[rf] = *(const bf16x8*)&Al[row*ROWB + (kb ^ ((row & 7) << 4))];
    }
    #pragma unroll
    for (int cf = 0; cf < 4; ++cf){
      int cr = cf*16 + lr;
      bfr[cf] = *(const bf16x8*)&Bl[cr*ROWB + (kb ^ ((cr & 7) << 4))];
    }
    #pragma unroll
    for (int rf = 0; rf < 2; ++rf)
      #pragma unroll
      for (int cf = 0; cf < 4; ++cf)
        acc[rf][cf] = __builtin_amdgcn_mfma_f32_16x16x32_bf16(af[rf], bfr[cf], acc[rf][cf], 0, 0, 0);
  }

  if (OUT == 0){
    #pragma unroll
    for (int rf = 0; rf < 2; ++rf)
      #pragma unroll
      for (int cf = 0; cf < 4; ++cf)
        #pragma unroll
        for (int r4 = 0; r4 < 4; ++r4){
          int row = rowbase + wrow + rf*16 + hi*4 + r4;
          out[(size_t)row*ostride + chb*64 + cf*16 + lr] = acc[rf][cf][r4] * oscale;
        }
  }
  if (OUT != 2 && part1){
    #pragma unroll
    for (int cf = 0; cf < 4; ++cf){
      float s1 = 0.f, s2 = 0.f;
      #pragma unroll
      for (int rf = 0; rf < 2; ++rf)
        #pragma unroll
        for (int r4 = 0; r4 < 4; ++r4){ float v = acc[rf][cf][r4]; s1 += v; s2 += v*v; }
      s1 += __shfl_xor(s1, 16); s1 += __shfl_xor(s1, 32);
      s2 += __shfl_xor(s2, 16); s2 += __shfl_xor(s2, 32);
      if (hi == 0){ pls[wv][0][cf*16 + lr] = s1; pls[wv][1][cf*16 + lr] = s2; }
    }
    __syncthreads();
    int nchTot = gridDim.y * 64;
    if (tid < 64)
      part1[(size_t)blockIdx.x*nchTot + chb*64 + tid] = pls[0][0][tid]+pls[1][0][tid]+pls[2][0][tid]+pls[3][0][tid];
    else if (tid < 128){
      int c = tid - 64;
      part2[(size_t)blockIdx.x*nchTot + chb*64 + c] = pls[0][1][c]+pls[1][1][c]+pls[2][1][c]+pls[3][1][c];
    }
  }
  if (OUT == 2){
    int nchTot = gridDim.y * 64;
    int b = rowbase >> 12;
    #pragma unroll
    for (int cf = 0; cf < 4; ++cf){
      int col = chb*64 + cf*16 + lr;
      float m2 = statsIn2[col], rs2 = statsIn2[nchTot + col];
      float mv = -INFINITY;
      #pragma unroll
      for (int rf = 0; rf < 2; ++rf)
        #pragma unroll
        for (int r4 = 0; r4 < 4; ++r4) mv = fmaxf(mv, lrelu((acc[rf][cf][r4] - m2)*rs2));
      mv = fmaxf(mv, __shfl_xor(mv, 16));
      mv = fmaxf(mv, __shfl_xor(mv, 32));
      if (hi == 0) pls[wv][0][cf*16 + lr] = mv;
    }
    __syncthreads();
    if (tid < 64)
      atomicMax(&xglob[b*nchTot + chb*64 + tid],
                ordf(fmaxf(fmaxf(pls[0][0][tid], pls[1][0][tid]), fmaxf(pls[2][0][tid], pls[3][0][tid]))));
  }
}

// deterministic partial -> (mean, rstd) per channel
__global__ __launch_bounds__(256) void stats_reduce(const float* __restrict__ p1, const float* __restrict__ p2,
                                                    float* __restrict__ statsOut, int nblk, int nch, float count){
  int ch = blockIdx.x, tid = threadIdx.x;
  float s1 = 0.f, s2 = 0.f;
  for (int i = tid; i < nblk; i += 256){ s1 += p1[(size_t)i*nch + ch]; s2 += p2[(size_t)i*nch + ch]; }
  __shared__ float r1[256], r2[256];
  r1[tid] = s1; r2[tid] = s2;
  __syncthreads();
  for (int off = 128; off; off >>= 1){
    if (tid < off){ r1[tid] += r1[tid+off]; r2[tid] += r2[tid+off]; }
    __syncthreads();
  }
  if (tid == 0){
    float m = r1[0] / count;
    float var = r2[0] / count - m*m;
    if (var < 0.f) var = 0.f;
    statsOut[ch] = m;
    statsOut[nch + ch] = rsqrtf(var + 1e-5f);
  }
}

// bn+lrelu then max over k=20 -> xper[:, off..off+63]
__global__ __launch_bounds__(256) void colmax(const float* __restrict__ buf, const float* __restrict__ st,
                                              float* __restrict__ xper, int off){
  int wv = threadIdx.x >> 6, lane = threadIdx.x & 63;
  int bn = blockIdx.x*4 + wv;
  float m = st[lane], rs = st[64 + lane];
  float mx = -INFINITY;
  for (int k = 0; k < 20; ++k){
    float z = buf[((size_t)bn*20 + k)*64 + lane];
    mx = fmaxf(mx, lrelu((z - m)*rs));
  }
  xper[(size_t)bn*128 + off + lane] = mx;
}

// head (r11): one wave per output scalar t. grid = 4 b x 32 groups; 4 waves.
// Wave (b, t=group*4+wv): lanes cover 16 of 1024 channels each, shfl reduce.
__global__ __launch_bounds__(256) void head(const unsigned* __restrict__ xglob,
                                            const float* __restrict__ mu_w, const float* __restrict__ mu_b,
                                            const float* __restrict__ var_w, const float* __restrict__ var_b,
                                            const float* __restrict__ eps_z, float* __restrict__ dout,
                                            float* __restrict__ zv){
  __shared__ __align__(16) float xg[1024];
  int b = blockIdx.x >> 5, grp = blockIdx.x & 31;
  int tid = threadIdx.x, wv = tid >> 6, lane = tid & 63;
  for (int q = 0; q < 4; ++q) xg[q*256 + tid] = iordf(xglob[b*1024 + q*256 + tid]);
  __syncthreads();
  int t = grp*4 + wv;
  const float* wa = &mu_w[(size_t)t*1024];
  const float* wb = &var_w[(size_t)t*1024];
  float s1 = 0.f, s2 = 0.f;
  #pragma unroll
  for (int u = 0; u < 4; ++u){
    int c = lane*16 + ((u + (lane & 3)) & 3)*4;     // rotate to spread LDS banks
    float4 xv = *(const float4*)&xg[c];
    float4 a4 = *(const float4*)&wa[c];
    float4 b4 = *(const float4*)&wb[c];
    s1 += a4.x*xv.x + a4.y*xv.y + a4.z*xv.z + a4.w*xv.w;
    s2 += b4.x*xv.x + b4.y*xv.y + b4.z*xv.z + b4.w*xv.w;
  }
  #pragma unroll
  for (int off = 32; off; off >>= 1){ s1 += __shfl_xor(s1, off); s2 += __shfl_xor(s2, off); }
  if (lane == 0){
    float mu = s1 + mu_b[t];
    float lv = s2 + var_b[t];
    dout[458816 + b*128 + t] = mu;
    dout[459328 + b*128 + t] = lv;
    zv[b*128 + t] = eps_z[b*128 + t] * expf(0.5f*lv) + mu;
  }
}

// cuboid MLP + Para_pred per (b,m)
__global__ __launch_bounds__(256) void cuboid(const float* __restrict__ zv, const float* __restrict__ enc_w,
                                              const float* __restrict__ w1, const float* __restrict__ w2,
                                              const float* __restrict__ rot_w, const float* __restrict__ rot_b,
                                              const float* __restrict__ trans_w, const float* __restrict__ trans_b,
                                              const float* __restrict__ ext_w1, const float* __restrict__ ext_b1,
                                              const float* __restrict__ ext_w2, const float* __restrict__ ext_b2,
                                              const float* __restrict__ k_w, float* __restrict__ Km,
                                              float* __restrict__ rot, float* __restrict__ trs,
                                              float* __restrict__ dout){
  int bm = blockIdx.x; int b = bm >> 4, m = bm & 15; int t = threadIdx.x;
  __shared__ __align__(16) float xc[192];
  __shared__ __align__(16) float h1[256];
  __shared__ __align__(16) float xcu[128];
  __shared__ float qv[4]; __shared__ float ev[30];
  if (t < 192) xc[t] = (t < 128) ? zv[b*128 + t] : lrelu(enc_w[(t-128)*16 + m]);
  __syncthreads();
  {
    float s = 0.f; const float* wr = w1 + (size_t)t*192;
    for (int c = 0; c < 192; c += 4){
      float4 w4 = *(const float4*)&wr[c]; float4 x4 = *(const float4*)&xc[c];
      s += w4.x*x4.x + w4.y*x4.y + w4.z*x4.z + w4.w*x4.w;
    }
    h1[t] = lrelu(s);
  }
  __syncthreads();
  if (t < 128){
    float s = 0.f; const float* wr = w2 + (size_t)t*256;
    for (int c = 0; c < 256; c += 4){
      float4 w4 = *(const float4*)&wr[c]; float4 x4 = *(const float4*)&h1[c];
      s += w4.x*x4.x + w4.y*x4.y + w4.z*x4.z + w4.w*x4.w;
    }
    xcu[t] = lrelu(s);
  }
  __syncthreads();
  if (t < 64){
    float s = 0.f;
    for (int c = 0; c < 128; ++c) s += xcu[c]*k_w[(size_t)t*128 + c];
    Km[(size_t)(b*16 + m)*64 + t] = s;
  } else if (t < 68){
    int o = t - 64; float s = rot_b[o];
    for (int c = 0; c < 128; ++c) s += xcu[c]*rot_w[(size_t)o*128 + c];
    qv[o] = s;
  } else if (t < 71){
    int o = t - 68; float s = trans_b[o];
    for (int c = 0; c < 128; ++c) s += xcu[c]*trans_w[(size_t)o*128 + c];
    trs[(size_t)(b*16 + m)*3 + o] = tanhf(s);
  } else if (t < 101){
    int o = t - 71; float s = ext_b1[o];
    for (int c = 0; c < 128; ++c) s += xcu[c]*ext_w1[(size_t)o*128 + c];
    ev[o] = lrelu(s);
  }
  __syncthreads();
  if (t == 0){
    float w = qv[0], x = qv[1], y = qv[2], z = qv[3];
    float nrm = sqrtf(w*w + x*x + y*y + z*z);
    float inv = 1.f / fmaxf(nrm, 1e-12f);
    w *= inv; x *= inv; y *= inv; z *= inv;
    float xx2 = x*x, yy = y*y, zz = z*z;
    float* r = rot + (size_t)(b*16 + m)*9;
    r[0] = 1.f - 2.f*(yy + zz); r[1] = 2.f*(x*y - w*z); r[2] = 2.f*(x*z + w*y);
    r[3] = 2.f*(x*y + w*z); r[4] = 1.f - 2.f*(xx2 + zz); r[5] = 2.f*(y*z - w*x);
    r[6] = 2.f*(x*z - w*y); r[7] = 2.f*(y*z + w*x); r[8] = 1.f - 2.f*(xx2 + yy);
  }
  if (t == 1){
    float s = ext_b2[0];
    for (int o = 0; o < 30; ++o) s += ev[o]*ext_w2[o];
    dout[458752 + b*16 + m] = s;
  }
}

// attention epilogue
__global__ __launch_bounds__(256) void attn(const float* __restrict__ Qbuf, const float* __restrict__ Km,
                                            const float* __restrict__ rot, const float* __restrict__ trs,
                                            float* __restrict__ dout){
  __shared__ float kml[16*64];
  __shared__ float rl[144], tl[48];
  __shared__ float Ql[4][64];
  __shared__ float al[4][16];
  int tid = threadIdx.x, wv = tid >> 6, lane = tid & 63;
  int bn0 = blockIdx.x*4; int b = bn0 >> 12;
  for (int e = tid; e < 1024; e += 256){
    int m = e >> 6, d = e & 63;
    kml[m*64 + (d ^ ((m & 15) << 2))] = Km[(size_t)b*1024 + e];
  }
  if (tid < 144) rl[tid] = rot[(size_t)b*144 + tid];
  if (tid < 48)  tl[tid] = trs[(size_t)b*48 + tid];
  __syncthreads();
  int bn = bn0 + wv;
  Ql[wv][lane] = Qbuf[(size_t)bn*64 + lane];
  if (lane < 16){
    float sc = 0.f;
    for (int d = 0; d < 64; ++d) sc += Ql[wv][d] * kml[lane*64 + (d ^ ((lane & 15) << 2))];
    float mx = sc;
    #pragma unroll
    for (int off = 8; off; off >>= 1) mx = fmaxf(mx, __shfl_xor(mx, off));
    float e = expf(sc - mx);
    float sm = e;
    #pragma unroll
    for (int off = 8; off; off >>= 1) sm += __shfl_xor(sm, off);
    float a = e / sm;
    dout[(size_t)bn*16 + lane] = a;
    al[wv][lane] = a;
  }
  if (lane < 9){
    float s = 0.f;
    for (int m = 0; m < 16; ++m) s += al[wv][m] * rl[m*9 + lane];
    dout[262144 + (size_t)bn*9 + lane] = s;
  }
  if (lane >= 16 && lane < 19){
    int d = lane - 16;
    float s = 0.f;
    for (int m = 0; m < 16; ++m) s += al[wv][m] * tl[m*3 + d];
    dout[409600 + (size_t)bn*3 + d] = s;
  }
}

// ---------------------------------------------------------------------------
extern "C" void kernel_launch(void* const* d_in, const int* in_sizes, int n_in,
                              void* d_out, int out_size, void* d_ws, size_t ws_size,
                              hipStream_t stream){
  (void)in_sizes; (void)n_in; (void)out_size; (void)ws_size;
  const float* xyz     = (const float*)d_in[0];
  const float* eps_z   = (const float*)d_in[2];
  const float* w1a     = (const float*)d_in[3];
  const float* w1b     = (const float*)d_in[4];
  const float* w2a     = (const float*)d_in[5];
  const float* w2b     = (const float*)d_in[6];
  const float* w3      = (const float*)d_in[7];
  const float* mu_w    = (const float*)d_in[8];
  const float* mu_b    = (const float*)d_in[9];
  const float* var_w   = (const float*)d_in[10];
  const float* var_b   = (const float*)d_in[11];
  const float* enc_w   = (const float*)d_in[12];
  const float* cw1     = (const float*)d_in[13];
  const float* cw2     = (const float*)d_in[14];
  const float* q_w     = (const float*)d_in[15];
  const float* k_w     = (const float*)d_in[16];
  const float* rot_w   = (const float*)d_in[19];
  const float* rot_b   = (const float*)d_in[20];
  const float* trans_w = (const float*)d_in[21];
  const float* trans_b = (const float*)d_in[22];
  const float* ext_w1  = (const float*)d_in[23];
  const float* ext_b1  = (const float*)d_in[24];
  const float* ext_w2  = (const float*)d_in[25];
  const float* ext_b2  = (const float*)d_in[26];
  float* dout = (float*)d_out;

  char* wsb = (char*)d_ws;
  size_t off = 0;
  float* buf   = (float*)(wsb + off); off += 83886080;      // z1b/z2a/z2b [B,N,K,64] f32; reused as key matrix (64MB)
  int*   idx0  = (int*)(wsb + off);   off += 1310720;
  int*   idx1  = (int*)(wsb + off);   off += 1310720;
  float* xper  = (float*)(wsb + off); off += 8388608;       // [B,N,128] = [x1|x2]
  float* xx    = (float*)(wsb + off); off += 65536;
  float* part1 = (float*)(wsb + off); off += 4194304;       // reused as Qbuf
  float* part2 = (float*)(wsb + off); off += 4194304;
  float* st1a  = (float*)(wsb + off); off += 512;
  float* st1b  = (float*)(wsb + off); off += 512;
  float* st2a  = (float*)(wsb + off); off += 512;
  float* st2b  = (float*)(wsb + off); off += 512;
  float* st3   = (float*)(wsb + off); off += 8192;
  unsigned* xglob = (unsigned*)(wsb + off); off += 16384;
  float* zv    = (float*)(wsb + off); off += 2048;
  float* Kmb   = (float*)(wsb + off); off += 16384;
  float* rotb  = (float*)(wsb + off); off += 2304;
  float* trsb  = (float*)(wsb + off); off += 768;
  float4* pts  = (float4*)(wsb + off); off += 262144;       // [B*N] (x,y,z,|x|^2)

  // --- Feature_extract, block 1 (w1b via split-bf16 MFMA) ---
  soa_xyz<<<64, 256, 0, stream>>>(xyz, pts);
  knn_xyz<<<4096, 256, 0, stream>>>(pts, idx0);
  stats1a<<<1024, 256, 0, stream>>>(pts, idx0, w1a, part1, part2);
  stats_reduce<<<64, 256, 0, stream>>>(part1, part2, st1a, 1024, 64, 327680.f);
  fused1m<<<2560, 256, 0, stream>>>(pts, idx0, w1a, w1b, st1a, part1, part2, buf);
  stats_reduce<<<64, 256, 0, stream>>>(part1, part2, st1b, 2560, 64, 327680.f);
  colmax<<<4096, 256, 0, stream>>>(buf, st1b, xper, 0);     // x1

  // --- knn on x1 (split-bf16 MFMA Gram -> packed keys -> topk), per batch ---
  row_norms<<<4096, 256, 0, stream>>>(xper, xx);
  for (int b = 0; b < 4; ++b){
    gram_mfma<<<dim3(32,32), 256, 0, stream>>>(xper + (size_t)b*NN*128, xx + (size_t)b*NN, (unsigned*)buf);
    topk_rows<<<1024, 256, 0, stream>>>((unsigned*)buf, idx1 + (size_t)b*NN*KK);
  }

  // --- Feature_extract, block 2 (bf16 MFMA) ---
  gemm_mfma<128,2,0><<<dim3(2560,1), 256, 0, stream>>>(xper, w2a, buf, 64, part1, part2, nullptr, idx1, 1.f, nullptr, nullptr);
  stats_reduce<<<64, 256, 0, stream>>>(part1, part2, st2a, 2560, 64, 327680.f);
  gemm_mfma<64,1,0><<<dim3(2560,1), 256, 0, stream>>>(buf, w2b, buf, 64, part1, part2, st2a, nullptr, 1.f, nullptr, nullptr);
  stats_reduce<<<64, 256, 0, stream>>>(part1, part2, st2b, 2560, 64, 327680.f);
  colmax<<<4096, 256, 0, stream>>>(buf, st2b, xper, 64);    // x2

  // --- global embedding (bf16 MFMA stats pass + fused BN/lrelu/max pass, no z3) ---
  gemm_mfma<128,0,1><<<dim3(128,16), 256, 0, stream>>>(xper, w3, nullptr, 1024, part1, part2, nullptr, nullptr, 1.f, nullptr, nullptr);
  stats_reduce<<<1024, 256, 0, stream>>>(part1, part2, st3, 128, 1024, 16384.f);
  hipMemsetAsync(xglob, 0, 4096*sizeof(unsigned), stream);
  gemm_mfma<128,0,2><<<dim3(128,16), 256, 0, stream>>>(xper, w3, nullptr, 1024, nullptr, nullptr, nullptr, nullptr, 1.f, st3, xglob);

  // --- heads ---
  head<<<128, 256, 0, stream>>>(xglob, mu_w, mu_b, var_w, var_b, eps_z, dout, zv);
  cuboid<<<64, 256, 0, stream>>>(zv, enc_w, cw1, cw2, rot_w, rot_b, trans_w, trans_b,
                                 ext_w1, ext_b1, ext_w2, ext_b2, k_w, Kmb, rotb, trsb, dout);
  gemm_mfma<128,0,0><<<dim3(128,1), 256, 0, stream>>>(xper, q_w, part1, 64, nullptr, nullptr, nullptr, nullptr, 0.125f, nullptr, nullptr);
  attn<<<4096, 256, 0, stream>>>(part1, Kmb, rotb, trsb, dout);
}